// Round 12
// baseline (1152.082 us; speedup 1.0000x reference)
//
#include <hip/hip_runtime.h>
#include <hip/hip_bf16.h>
#include <math.h>

#define B_ 4
#define T_ 2048
#define M_ 1024
#define H_ 16
#define E_ 8
#define S_ (B_*T_)      // 8192
#define C_ (S_/E_)      // 1024
#define D_ (M_/H_)      // 64
#define F_ (4*M_)       // 4096

typedef unsigned short ushort_t;
typedef __attribute__((ext_vector_type(8))) short bf16x8;
typedef __attribute__((ext_vector_type(4))) float f32x4;

__device__ __forceinline__ float gelu_exact(float x) {
    return 0.5f * x * (1.0f + erff(x * 0.70710678118654752440f));
}

__device__ __forceinline__ unsigned short f2bf(float f) {
    unsigned int u = __float_as_uint(f);
    u = (u + 0x7FFFu + ((u >> 16) & 1u)) >> 16;   // RNE
    return (unsigned short)u;
}

__device__ __forceinline__ float bf2f(unsigned short h) {
    return __uint_as_float(((unsigned)h) << 16);
}

__device__ __forceinline__ void gload_lds16(const void* g, void* l) {
    __builtin_amdgcn_global_load_lds(
        (const __attribute__((address_space(1))) unsigned int*)g,
        (__attribute__((address_space(3))) unsigned int*)l,
        16, 0, 0);
}

__device__ __forceinline__ void lgkm0() {
    asm volatile("s_waitcnt lgkmcnt(0)" ::: "memory");
}

// ---------------------------------------------------------------------------
// LayerNorm (f32 out).
// ---------------------------------------------------------------------------
__global__ __launch_bounds__(256) void ln_kernel(const float* __restrict__ x,
                                                 const float* __restrict__ g,
                                                 const float* __restrict__ bta,
                                                 float* __restrict__ out)
{
    const int row = blockIdx.x;
    const int tid = threadIdx.x;
    const float4 v = reinterpret_cast<const float4*>(x + (size_t)row * M_)[tid];
    float s = v.x + v.y + v.z + v.w;
    __shared__ float red[4];
    #pragma unroll
    for (int off = 32; off > 0; off >>= 1) s += __shfl_down(s, off);
    if ((tid & 63) == 0) red[tid >> 6] = s;
    __syncthreads();
    const float mu = (red[0] + red[1] + red[2] + red[3]) * (1.0f / (float)M_);
    __syncthreads();
    float4 d;
    d.x = v.x - mu; d.y = v.y - mu; d.z = v.z - mu; d.w = v.w - mu;
    float q = d.x*d.x + d.y*d.y + d.z*d.z + d.w*d.w;
    #pragma unroll
    for (int off = 32; off > 0; off >>= 1) q += __shfl_down(q, off);
    if ((tid & 63) == 0) red[tid >> 6] = q;
    __syncthreads();
    const float var  = (red[0] + red[1] + red[2] + red[3]) * (1.0f / (float)M_);
    const float rstd = 1.0f / sqrtf(var + 1e-5f);
    const float4 gv = reinterpret_cast<const float4*>(g)[tid];
    const float4 bv = reinterpret_cast<const float4*>(bta)[tid];
    float4 o;
    o.x = d.x * rstd * gv.x + bv.x;
    o.y = d.y * rstd * gv.y + bv.y;
    o.z = d.z * rstd * gv.z + bv.z;
    o.w = d.w * rstd * gv.w + bv.w;
    reinterpret_cast<float4*>(out + (size_t)row * M_)[tid] = o;
}

// LayerNorm fused with hi/lo bf16 split output.
__global__ __launch_bounds__(256) void ln_split_kernel(const float* __restrict__ x,
                                                       const float* __restrict__ g,
                                                       const float* __restrict__ bta,
                                                       ushort_t* __restrict__ hi,
                                                       ushort_t* __restrict__ lo)
{
    const int row = blockIdx.x;
    const int tid = threadIdx.x;
    const float4 v = reinterpret_cast<const float4*>(x + (size_t)row * M_)[tid];
    float s = v.x + v.y + v.z + v.w;
    __shared__ float red[4];
    #pragma unroll
    for (int off = 32; off > 0; off >>= 1) s += __shfl_down(s, off);
    if ((tid & 63) == 0) red[tid >> 6] = s;
    __syncthreads();
    const float mu = (red[0] + red[1] + red[2] + red[3]) * (1.0f / (float)M_);
    __syncthreads();
    float4 d;
    d.x = v.x - mu; d.y = v.y - mu; d.z = v.z - mu; d.w = v.w - mu;
    float q = d.x*d.x + d.y*d.y + d.z*d.z + d.w*d.w;
    #pragma unroll
    for (int off = 32; off > 0; off >>= 1) q += __shfl_down(q, off);
    if ((tid & 63) == 0) red[tid >> 6] = q;
    __syncthreads();
    const float var  = (red[0] + red[1] + red[2] + red[3]) * (1.0f / (float)M_);
    const float rstd = 1.0f / sqrtf(var + 1e-5f);
    const float4 gv = reinterpret_cast<const float4*>(g)[tid];
    const float4 bv = reinterpret_cast<const float4*>(bta)[tid];
    float o[4];
    o[0] = d.x * rstd * gv.x + bv.x;
    o[1] = d.y * rstd * gv.y + bv.y;
    o[2] = d.z * rstd * gv.z + bv.z;
    o[3] = d.w * rstd * gv.w + bv.w;
    ushort4 hh, ll;
    hh.x = f2bf(o[0]); ll.x = f2bf(o[0] - bf2f(hh.x));
    hh.y = f2bf(o[1]); ll.y = f2bf(o[1] - bf2f(hh.y));
    hh.z = f2bf(o[2]); ll.z = f2bf(o[2] - bf2f(hh.z));
    hh.w = f2bf(o[3]); ll.w = f2bf(o[3] - bf2f(hh.w));
    reinterpret_cast<ushort4*>(hi + (size_t)row * M_)[tid] = hh;
    reinterpret_cast<ushort4*>(lo + (size_t)row * M_)[tid] = ll;
}

// Elementwise f32 -> hi/lo bf16 split (weights).
__global__ __launch_bounds__(256) void split_kernel(const float* __restrict__ in,
                                                    ushort_t* __restrict__ hi,
                                                    ushort_t* __restrict__ lo,
                                                    int n4)
{
    const int i = blockIdx.x * 256 + threadIdx.x;
    if (i >= n4) return;
    const float4 v = reinterpret_cast<const float4*>(in)[i];
    ushort4 hh, ll;
    hh.x = f2bf(v.x); ll.x = f2bf(v.x - bf2f(hh.x));
    hh.y = f2bf(v.y); ll.y = f2bf(v.y - bf2f(hh.y));
    hh.z = f2bf(v.z); ll.z = f2bf(v.z - bf2f(hh.z));
    hh.w = f2bf(v.w); ll.w = f2bf(v.w - bf2f(hh.w));
    reinterpret_cast<ushort4*>(hi)[i] = hh;
    reinterpret_cast<ushort4*>(lo)[i] = ll;
}

// V^T pre-transpose: qkv hi/lo [s][3M] (V slice) -> vt hi/lo [(b*H+h)*64+d][T].
__global__ __launch_bounds__(256) void vtrans_kernel(const ushort_t* __restrict__ qkvh,
                                                     const ushort_t* __restrict__ qkvl,
                                                     ushort_t* __restrict__ vth,
                                                     ushort_t* __restrict__ vtl)
{
    __shared__ ushort_t tile[64][72];
    const int t0 = blockIdx.x * 64, h = blockIdx.y, b = blockIdx.z;
    const int tid = threadIdx.x;
    const int tr = tid & 63, dc = (tid >> 6) * 16;
    const size_t src = ((size_t)(b*T_ + t0 + tr)) * (3*M_) + 2*M_ + h*64 + dc;
    const int dr = tid & 63, tc = (tid >> 6) * 16;
    const size_t dst = ((size_t)((b*H_ + h)*64 + dr)) * T_ + t0 + tc;

    #pragma unroll
    for (int pass = 0; pass < 2; ++pass) {
        const ushort_t* in = pass ? qkvl : qkvh;
        ushort_t* outp     = pass ? vtl  : vth;
        *reinterpret_cast<bf16x8*>(&tile[tr][dc])     = *reinterpret_cast<const bf16x8*>(in + src);
        *reinterpret_cast<bf16x8*>(&tile[tr][dc + 8]) = *reinterpret_cast<const bf16x8*>(in + src + 8);
        __syncthreads();
        bf16x8 o0, o1;
        #pragma unroll
        for (int j = 0; j < 8; ++j) {
            o0[j] = (short)tile[tc + j][dr];
            o1[j] = (short)tile[tc + 8 + j][dr];
        }
        *reinterpret_cast<bf16x8*>(outp + dst)     = o0;
        *reinterpret_cast<bf16x8*>(outp + dst + 8) = o1;
        __syncthreads();
    }
}

// ---------------------------------------------------------------------------
// bf16x3 MFMA GEMM (f32-grade, pre-router). m97 structure, 4 LDS buffers.
// EPI 1: f32 out = acc + bias + res.   EPI 2: hi/lo bf16 out = split(acc+bias).
// ---------------------------------------------------------------------------
template<int EPI>
__global__ __launch_bounds__(256) void gemm_bf16x3(
    const ushort_t* __restrict__ Ahi, const ushort_t* __restrict__ Alo,
    const ushort_t* __restrict__ Bhi, const ushort_t* __restrict__ Blo,
    const float* __restrict__ bias, const float* __restrict__ res,
    void* __restrict__ C0, ushort_t* __restrict__ C1, int N, int K)
{
    __shared__ ushort_t AsH[128*32], AsL[128*32];
    __shared__ ushort_t BsH[128*32], BsL[128*32];

    const int t  = threadIdx.x;
    const int l  = t & 63;
    const int wv = t >> 6;
    const int wm = (wv & 1) * 64, wn = (wv >> 1) * 64;
    const int fr = l & 15, fk = (l >> 4) * 8;
    const int m0 = blockIdx.y * 128, n0 = blockIdx.x * 128;

    const size_t arow = (size_t)(m0 + (t >> 2)) * K + (t & 3) * 8;
    const size_t brow = (size_t)(n0 + (t >> 2)) * K + (t & 3) * 8;
    ushort_t* lAH = AsH + wv * 512;
    ushort_t* lAL = AsL + wv * 512;
    ushort_t* lBH = BsH + wv * 512;
    ushort_t* lBL = BsL + wv * 512;

    f32x4 acc[4][4] = {};

    for (int k0 = 0; k0 < K; k0 += 32) {
        __syncthreads();
        gload_lds16(Ahi + arow + k0, lAH);
        gload_lds16(Ahi + arow + k0 + (size_t)64 * K, lAH + 2048);
        gload_lds16(Alo + arow + k0, lAL);
        gload_lds16(Alo + arow + k0 + (size_t)64 * K, lAL + 2048);
        gload_lds16(Bhi + brow + k0, lBH);
        gload_lds16(Bhi + brow + k0 + (size_t)64 * K, lBH + 2048);
        gload_lds16(Blo + brow + k0, lBL);
        gload_lds16(Blo + brow + k0 + (size_t)64 * K, lBL + 2048);
        __syncthreads();
        bf16x8 ah[4], al[4], bh[4], bl[4];
        #pragma unroll
        for (int i = 0; i < 4; ++i) {
            ah[i] = *reinterpret_cast<const bf16x8*>(&AsH[(wm + i*16 + fr) * 32 + fk]);
            al[i] = *reinterpret_cast<const bf16x8*>(&AsL[(wm + i*16 + fr) * 32 + fk]);
            bh[i] = *reinterpret_cast<const bf16x8*>(&BsH[(wn + i*16 + fr) * 32 + fk]);
            bl[i] = *reinterpret_cast<const bf16x8*>(&BsL[(wn + i*16 + fr) * 32 + fk]);
        }
        #pragma unroll
        for (int mi = 0; mi < 4; ++mi) {
            #pragma unroll
            for (int ni = 0; ni < 4; ++ni) {
                acc[mi][ni] = __builtin_amdgcn_mfma_f32_16x16x32_bf16(ah[mi], bh[ni], acc[mi][ni], 0, 0, 0);
                acc[mi][ni] = __builtin_amdgcn_mfma_f32_16x16x32_bf16(al[mi], bh[ni], acc[mi][ni], 0, 0, 0);
                acc[mi][ni] = __builtin_amdgcn_mfma_f32_16x16x32_bf16(ah[mi], bl[ni], acc[mi][ni], 0, 0, 0);
            }
        }
    }

    // C/D: col = lane&15, row = (lane>>4)*4 + reg
    const int l4 = (l >> 4) * 4;
    #pragma unroll
    for (int mi = 0; mi < 4; ++mi) {
        #pragma unroll
        for (int i = 0; i < 4; ++i) {
            const int row = m0 + wm + mi*16 + l4 + i;
            #pragma unroll
            for (int ni = 0; ni < 4; ++ni) {
                const int col = n0 + wn + ni*16 + fr;
                float v = acc[mi][ni][i] + bias[col];
                if (EPI == 1) {
                    v += res[(size_t)row * N + col];
                    ((float*)C0)[(size_t)row * N + col] = v;
                } else {
                    const ushort_t hb = f2bf(v);
                    ((ushort_t*)C0)[(size_t)row * N + col] = hb;
                    C1[(size_t)row * N + col] = f2bf(v - bf2f(hb));
                }
            }
        }
    }
}

// ---------------------------------------------------------------------------
// bf16x3 MFMA flash attention — PERSISTENT, 1024 blocks (4/CU), 2 snake-paired
// items each (j, 2047-j => 33 tiles/block, perfectly balanced). LDS diet:
// P buffers ALIAS the K buffers (K fully consumed by QK^T before P is
// produced; T14 commit overwrites after PV when P is dead). P stored [16][64]
// per wave with the same ((q&7)<<3) XOR element swizzle as K (verified
// round-trip; 2-way-bank reads). One added barrier between QK^T and P-write.
// LDS 50 KB -> 32 KB -> 4 blocks/CU.
// ---------------------------------------------------------------------------
__global__ __launch_bounds__(256, 4) void attn_mfma_kernel(
    const ushort_t* __restrict__ qkvh, const ushort_t* __restrict__ qkvl,
    const ushort_t* __restrict__ vth,  const ushort_t* __restrict__ vtl,
    ushort_t* __restrict__ ohi, ushort_t* __restrict__ olo)
{
    const int j = (int)blockIdx.x;                 // 0..1023
    const int t = threadIdx.x;
    const int w = t >> 6, l = t & 63;
    const int r = l & 15, g = l >> 4;

    __shared__ ushort_t Khi[64*64], Klo[64*64];    // [kv][64] swizzled; P alias
    __shared__ ushort_t Vhi[64*64], Vlo[64*64];    // V^T [d][64 kv] swizzled

    ushort_t* Pwh = Khi + w * 1024;                // per-wave P [16 q][64 kv]
    ushort_t* Pwl = Klo + w * 1024;

    const int items[2] = { j, 2047 - j };

    // staging lane geometry (item-independent)
    const int srow = w*8 + (l >> 3);
    const int scol = ((l & 7) ^ (l >> 3)) * 8;
    const int d0 = w * 512 + l * 8;                // ushort index; +2048 = rows+32

    for (int ii = 0; ii < 2; ++ii) {
        const int item = items[ii];
        const int qt  = 31 - (item >> 6);          // rank -> qt (descending)
        const int rem = item & 63;
        const int h = rem >> 2, b = rem & 3;
        const int q0 = qt * 64;
        const size_t rowbase = (size_t)b * T_;
        const int hoff = h * D_;

        // Q fragments (A-frag: row = l&15, k = 32ks + 8g + j)
        bf16x8 qh[2], ql[2];
        {
            const size_t qrow = (rowbase + q0 + 16*w + r) * (size_t)(3*M_) + hoff;
            #pragma unroll
            for (int ks = 0; ks < 2; ++ks) {
                qh[ks] = *reinterpret_cast<const bf16x8*>(qkvh + qrow + 32*ks + 8*g);
                ql[ks] = *reinterpret_cast<const bf16x8*>(qkvl + qrow + 32*ks + 8*g);
            }
        }

        const size_t ksrc0 = (rowbase + srow) * (size_t)(3*M_) + hoff + M_ + scol;
        const size_t vsrc0 = ((size_t)((b*H_ + h)*64 + srow)) * T_ + scol;

        bf16x8 stg[8];
        __syncthreads();   // previous item's LDS readers done
        // prologue: stage tile 0
        {
            const size_t kb = ksrc0, vb = vsrc0;
            const size_t kstep = (size_t)32 * (3*M_);
            stg[0] = *reinterpret_cast<const bf16x8*>(qkvh + kb);
            stg[1] = *reinterpret_cast<const bf16x8*>(qkvh + kb + kstep);
            stg[2] = *reinterpret_cast<const bf16x8*>(qkvl + kb);
            stg[3] = *reinterpret_cast<const bf16x8*>(qkvl + kb + kstep);
            stg[4] = *reinterpret_cast<const bf16x8*>(vth + vb);
            stg[5] = *reinterpret_cast<const bf16x8*>(vth + vb + 32*T_);
            stg[6] = *reinterpret_cast<const bf16x8*>(vtl + vb);
            stg[7] = *reinterpret_cast<const bf16x8*>(vtl + vb + 32*T_);
            *reinterpret_cast<bf16x8*>(&Khi[d0])        = stg[0];
            *reinterpret_cast<bf16x8*>(&Khi[d0 + 2048]) = stg[1];
            *reinterpret_cast<bf16x8*>(&Klo[d0])        = stg[2];
            *reinterpret_cast<bf16x8*>(&Klo[d0 + 2048]) = stg[3];
            *reinterpret_cast<bf16x8*>(&Vhi[d0])        = stg[4];
            *reinterpret_cast<bf16x8*>(&Vhi[d0 + 2048]) = stg[5];
            *reinterpret_cast<bf16x8*>(&Vlo[d0])        = stg[6];
            *reinterpret_cast<bf16x8*>(&Vlo[d0 + 2048]) = stg[7];
        }
        __syncthreads();

        f32x4 oa[4] = {};
        float mrow[4] = {-__builtin_inff(), -__builtin_inff(), -__builtin_inff(), -__builtin_inff()};
        float lrow[4] = {};

        for (int kt = 0; kt <= qt; ++kt) {
            // ---- QK^T: S[16 q][64 kv], bf16x3, K frags from LDS ----
            f32x4 sa[4] = {};
            #pragma unroll
            for (int ks = 0; ks < 2; ++ks) {
                bf16x8 kh[4], kl[4];
                #pragma unroll
                for (int nf = 0; nf < 4; ++nf) {
                    const int row = 16*nf + r;
                    const unsigned boff = (unsigned)(row * 128)
                        + (((unsigned)(ks*64 + g*16)) ^ ((unsigned)((row & 7) << 4)));
                    kh[nf] = *reinterpret_cast<const bf16x8*>((const char*)Khi + boff);
                    kl[nf] = *reinterpret_cast<const bf16x8*>((const char*)Klo + boff);
                }
                #pragma unroll
                for (int nf = 0; nf < 4; ++nf) {
                    sa[nf] = __builtin_amdgcn_mfma_f32_16x16x32_bf16(qh[ks], kh[nf], sa[nf], 0, 0, 0);
                    sa[nf] = __builtin_amdgcn_mfma_f32_16x16x32_bf16(ql[ks], kh[nf], sa[nf], 0, 0, 0);
                    sa[nf] = __builtin_amdgcn_mfma_f32_16x16x32_bf16(qh[ks], kl[nf], sa[nf], 0, 0, 0);
                }
            }

            // ---- issue next tile's staging loads into registers (T14) ----
            if (kt < qt) {
                const size_t kb = ksrc0 + (size_t)((kt+1)*64) * (3*M_);
                const size_t vb = vsrc0 + (size_t)((kt+1)*64);
                const size_t kstep = (size_t)32 * (3*M_);
                stg[0] = *reinterpret_cast<const bf16x8*>(qkvh + kb);
                stg[1] = *reinterpret_cast<const bf16x8*>(qkvh + kb + kstep);
                stg[2] = *reinterpret_cast<const bf16x8*>(qkvl + kb);
                stg[3] = *reinterpret_cast<const bf16x8*>(qkvl + kb + kstep);
                stg[4] = *reinterpret_cast<const bf16x8*>(vth + vb);
                stg[5] = *reinterpret_cast<const bf16x8*>(vth + vb + 32*T_);
                stg[6] = *reinterpret_cast<const bf16x8*>(vtl + vb);
                stg[7] = *reinterpret_cast<const bf16x8*>(vtl + vb + 32*T_);
            }

            // ---- scale + causal mask ----
            float sv[4][4];
            #pragma unroll
            for (int nf = 0; nf < 4; ++nf)
                #pragma unroll
                for (int i = 0; i < 4; ++i)
                    sv[nf][i] = sa[nf][i] * 0.125f;
            if (kt == qt) {
                #pragma unroll
                for (int nf = 0; nf < 4; ++nf) {
                    const int kvg = kt*64 + 16*nf + r;
                    #pragma unroll
                    for (int i = 0; i < 4; ++i) {
                        const int qg = q0 + 16*w + 4*g + i;
                        if (kvg > qg) sv[nf][i] = -3.0e38f;
                    }
                }
            }

            // ---- online softmax (native exp) ----
            float tmax[4];
            #pragma unroll
            for (int i = 0; i < 4; ++i)
                tmax[i] = fmaxf(fmaxf(sv[0][i], sv[1][i]), fmaxf(sv[2][i], sv[3][i]));
            #pragma unroll
            for (int off = 1; off < 16; off <<= 1)
                #pragma unroll
                for (int i = 0; i < 4; ++i)
                    tmax[i] = fmaxf(tmax[i], __shfl_xor(tmax[i], off));
            float mnew[4], corr[4];
            #pragma unroll
            for (int i = 0; i < 4; ++i) {
                mnew[i] = fmaxf(mrow[i], tmax[i]);
                corr[i] = __expf(mrow[i] - mnew[i]);
            }
            float p[4][4];
            float rsum[4] = {};
            #pragma unroll
            for (int nf = 0; nf < 4; ++nf)
                #pragma unroll
                for (int i = 0; i < 4; ++i) {
                    p[nf][i] = __expf(sv[nf][i] - mnew[i]);
                    rsum[i] += p[nf][i];
                }
            #pragma unroll
            for (int off = 1; off < 16; off <<= 1)
                #pragma unroll
                for (int i = 0; i < 4; ++i)
                    rsum[i] += __shfl_xor(rsum[i], off);
            #pragma unroll
            for (int i = 0; i < 4; ++i) {
                lrow[i] = lrow[i] * corr[i] + rsum[i];
                mrow[i] = mnew[i];
            }
            #pragma unroll
            for (int df = 0; df < 4; ++df)
                #pragma unroll
                for (int i = 0; i < 4; ++i)
                    oa[df][i] *= corr[i];

            __syncthreads();   // all waves done reading K -> safe to alias P

            // ---- write P into K region (per-wave [16][64], XOR-swizzled) ----
            #pragma unroll
            for (int nf = 0; nf < 4; ++nf) {
                #pragma unroll
                for (int i = 0; i < 4; ++i) {
                    const int q = 4*g + i;
                    const int kv = (16*nf + r) ^ ((q & 7) << 3);
                    const ushort_t phb = f2bf(p[nf][i]);
                    Pwh[q * 64 + kv] = phb;
                    Pwl[q * 64 + kv] = f2bf(p[nf][i] - bf2f(phb));
                }
            }
            lgkm0();   // P writes visible to this wave's reads (per-wave slice)

            // ---- PV: O += P·V, bf16x3 ----
            #pragma unroll
            for (int ks = 0; ks < 2; ++ks) {
                const unsigned poff = (unsigned)(r * 64 + ((32*ks + 8*g) ^ ((r & 7) << 3)));
                const bf16x8 ph = *reinterpret_cast<const bf16x8*>(&Pwh[poff]);
                const bf16x8 pl = *reinterpret_cast<const bf16x8*>(&Pwl[poff]);
                #pragma unroll
                for (int df = 0; df < 4; ++df) {
                    const int vrow = 16*df + r;
                    const unsigned voff = (unsigned)(vrow * 128)
                        + (((unsigned)(ks*64 + g*16)) ^ ((unsigned)((vrow & 7) << 4)));
                    const bf16x8 vhf = *reinterpret_cast<const bf16x8*>((const char*)Vhi + voff);
                    const bf16x8 vlf = *reinterpret_cast<const bf16x8*>((const char*)Vlo + voff);
                    oa[df] = __builtin_amdgcn_mfma_f32_16x16x32_bf16(ph, vhf, oa[df], 0, 0, 0);
                    oa[df] = __builtin_amdgcn_mfma_f32_16x16x32_bf16(pl, vhf, oa[df], 0, 0, 0);
                    oa[df] = __builtin_amdgcn_mfma_f32_16x16x32_bf16(ph, vlf, oa[df], 0, 0, 0);
                }
            }

            // ---- commit staged registers to LDS for next tile ----
            if (kt < qt) {
                __syncthreads();                   // V readers done; P dead
                *reinterpret_cast<bf16x8*>(&Khi[d0])        = stg[0];
                *reinterpret_cast<bf16x8*>(&Khi[d0 + 2048]) = stg[1];
                *reinterpret_cast<bf16x8*>(&Klo[d0])        = stg[2];
                *reinterpret_cast<bf16x8*>(&Klo[d0 + 2048]) = stg[3];
                *reinterpret_cast<bf16x8*>(&Vhi[d0])        = stg[4];
                *reinterpret_cast<bf16x8*>(&Vhi[d0 + 2048]) = stg[5];
                *reinterpret_cast<bf16x8*>(&Vlo[d0])        = stg[6];
                *reinterpret_cast<bf16x8*>(&Vlo[d0 + 2048]) = stg[7];
                __syncthreads();                   // writes visible
            }
        }

        // ---- epilogue: hi/lo split of O / l ----
        #pragma unroll
        for (int i = 0; i < 4; ++i) {
            const float inv = 1.0f / lrow[i];
            const size_t row = (rowbase + q0 + 16*w + 4*g + i) * (size_t)M_ + hoff;
            #pragma unroll
            for (int df = 0; df < 4; ++df) {
                const float v = oa[df][i] * inv;
                const ushort_t hb = f2bf(v);
                ohi[row + 16*df + r] = hb;
                olo[row + 16*df + r] = f2bf(v - bf2f(hb));
            }
        }
    }
}

// ---------------------------------------------------------------------------
// Router + deepspeed dispatch bookkeeping (exact, f32).
// ---------------------------------------------------------------------------
__global__ __launch_bounds__(256) void gate_kernel(const float* __restrict__ h2,
                                                   const float* __restrict__ wg,
                                                   int* __restrict__ gidx,
                                                   float* __restrict__ gtop)
{
    const int s = blockIdx.x;
    const int e = threadIdx.x >> 5;
    const int l = threadIdx.x & 31;
    const float* row = h2 + (size_t)s * M_;
    float acc = 0.0f;
    for (int m = l; m < M_; m += 32) acc = fmaf(row[m], wg[m * E_ + e], acc);
    #pragma unroll
    for (int off = 16; off > 0; off >>= 1) acc += __shfl_down(acc, off, 32);
    __shared__ float lg[E_];
    if (l == 0) lg[e] = acc;
    __syncthreads();
    if (threadIdx.x == 0) {
        float mx = lg[0]; int bi = 0;
        #pragma unroll
        for (int i = 1; i < E_; ++i) { if (lg[i] > mx) { mx = lg[i]; bi = i; } }
        float den = 0.0f;
        #pragma unroll
        for (int i = 0; i < E_; ++i) den += expf(lg[i] - mx);
        gidx[s] = bi;
        gtop[s] = 1.0f / den;
    }
}

__global__ __launch_bounds__(1024) void scan_kernel(const int* __restrict__ gidx,
                                                    const float* __restrict__ gtop,
                                                    float* __restrict__ gate_val,
                                                    int* __restrict__ token_at)
{
    __shared__ int hist[1024][E_];
    const int tid = threadIdx.x;
    for (int i = tid; i < E_ * C_; i += 1024) token_at[i] = -1;
    int my[8];
    #pragma unroll
    for (int t = 0; t < 8; ++t) my[t] = gidx[tid * 8 + t];
    #pragma unroll
    for (int e = 0; e < E_; ++e) {
        int c = 0;
        #pragma unroll
        for (int t = 0; t < 8; ++t) c += (my[t] == e) ? 1 : 0;
        hist[tid][e] = c;
    }
    __syncthreads();
    if (tid < E_) {
        int run = 0;
        for (int t = 0; t < 1024; ++t) {
            const int v = hist[t][tid];
            hist[t][tid] = run;
            run += v;
        }
    }
    __syncthreads();
    #pragma unroll
    for (int t = 0; t < 8; ++t) {
        const int s = tid * 8 + t;
        const int e = my[t];
        const int p = hist[tid][e];
        hist[tid][e] = p + 1;
        const bool keep = (p < C_);
        gate_val[s] = keep ? gtop[s] : 0.0f;
        if (keep) token_at[e * C_ + p] = s;
    }
}

__global__ __launch_bounds__(256) void dispatch_bf16_kernel(const float* __restrict__ h2,
                                                            const int* __restrict__ token_at,
                                                            ushort_t* __restrict__ disp)
{
    const int ec = blockIdx.x;
    const int s = token_at[ec];
    ushort4* dst = reinterpret_cast<ushort4*>(disp + (size_t)ec * M_);
    if (s >= 0) {
        const float4 v = reinterpret_cast<const float4*>(h2 + (size_t)s * M_)[threadIdx.x];
        dst[threadIdx.x] = make_ushort4(f2bf(v.x), f2bf(v.y), f2bf(v.z), f2bf(v.w));
    } else {
        dst[threadIdx.x] = make_ushort4(0, 0, 0, 0);
    }
}

// Transpose+convert: in[e][R][Cc] f32 -> out[e][Cc][R] bf16.
__global__ __launch_bounds__(256) void transpose_bf16_kernel(const float* __restrict__ in,
                                                             ushort_t* __restrict__ outp,
                                                             int R, int Cc)
{
    __shared__ float tile[32][33];
    const int e = blockIdx.z;
    in   += (size_t)e * R * Cc;
    outp += (size_t)e * R * Cc;
    const int tx = threadIdx.x & 31, ty0 = threadIdx.x >> 5;
    const int c0 = blockIdx.x * 32, r0 = blockIdx.y * 32;
    #pragma unroll
    for (int i = 0; i < 4; ++i)
        tile[ty0 + 8*i][tx] = in[(size_t)(r0 + ty0 + 8*i) * Cc + c0 + tx];
    __syncthreads();
    #pragma unroll
    for (int i = 0; i < 4; ++i)
        outp[(size_t)(c0 + ty0 + 8*i) * R + r0 + tx] = f2bf(tile[tx][ty0 + 8*i]);
}

// ---------------------------------------------------------------------------
// bf16 MFMA GEMM (MoE FFN, post-router) — unchanged, verified.
// ---------------------------------------------------------------------------
template<int EPI>
__global__ __launch_bounds__(256) void gemm_mfma(
    const ushort_t* __restrict__ A, const ushort_t* __restrict__ Bt,
    const float* __restrict__ bias,
    const int* __restrict__ token_at, const float* __restrict__ gate_val,
    void* __restrict__ Cout, int N, int K,
    long strA, long strB, long strBias, long strC)
{
    const int e = blockIdx.z;
    A    += (size_t)e * (size_t)strA;
    Bt   += (size_t)e * (size_t)strB;
    bias += (size_t)e * (size_t)strBias;

    __shared__ ushort_t As[128 * 32];
    __shared__ ushort_t Bs[128 * 32];

    const int t  = threadIdx.x;
    const int l  = t & 63;
    const int wv = t >> 6;
    const int wm = (wv & 1) * 64, wn = (wv >> 1) * 64;
    const int fr = l & 15, fk = (l >> 4) * 8;
    const int m0 = blockIdx.y * 128, n0 = blockIdx.x * 128;

    const ushort_t* gA = A + (size_t)(m0 + (t >> 2)) * K + (t & 3) * 8;
    const ushort_t* gB = Bt + (size_t)(n0 + (t >> 2)) * K + (t & 3) * 8;
    ushort_t* lA = As + wv * 512;
    ushort_t* lB = Bs + wv * 512;

    f32x4 acc[4][4] = {};

    for (int k0 = 0; k0 < K; k0 += 32) {
        __syncthreads();
        gload_lds16(gA + k0, lA);
        gload_lds16(gA + k0 + (size_t)64 * K, lA + 2048);
        gload_lds16(gB + k0, lB);
        gload_lds16(gB + k0 + (size_t)64 * K, lB + 2048);
        __syncthreads();
        bf16x8 af[4], bfr[4];
        #pragma unroll
        for (int i = 0; i < 4; ++i)
            af[i] = *reinterpret_cast<const bf16x8*>(&As[(wm + i*16 + fr) * 32 + fk]);
        #pragma unroll
        for (int i = 0; i < 4; ++i)
            bfr[i] = *reinterpret_cast<const bf16x8*>(&Bs[(wn + i*16 + fr) * 32 + fk]);
        #pragma unroll
        for (int mi = 0; mi < 4; ++mi) {
            #pragma unroll
            for (int ni = 0; ni < 4; ++ni)
                acc[mi][ni] = __builtin_amdgcn_mfma_f32_16x16x32_bf16(
                    af[mi], bfr[ni], acc[mi][ni], 0, 0, 0);
        }
    }

    const int l4 = (l >> 4) * 4;
    if (EPI == 0) {
        ushort_t* Cc = (ushort_t*)Cout + (size_t)e * (size_t)strC;
        #pragma unroll
        for (int ni = 0; ni < 4; ++ni) {
            const int cl = n0 + wn + ni*16 + fr;
            const float bb = bias[cl];
            #pragma unroll
            for (int mi = 0; mi < 4; ++mi) {
                #pragma unroll
                for (int i = 0; i < 4; ++i) {
                    const int rr = m0 + wm + mi*16 + l4 + i;
                    Cc[(size_t)rr * N + cl] = f2bf(gelu_exact(acc[mi][ni][i] + bb));
                }
            }
        }
    } else {
        float* Co = (float*)Cout;
        const int* ta = token_at + e * C_;
        #pragma unroll
        for (int mi = 0; mi < 4; ++mi) {
            #pragma unroll
            for (int i = 0; i < 4; ++i) {
                const int rr = m0 + wm + mi*16 + l4 + i;
                const int s = ta[rr];
                if (s >= 0) {
                    const float gvl = gate_val[s];
                    #pragma unroll
                    for (int ni = 0; ni < 4; ++ni) {
                        const int cl = n0 + wn + ni*16 + fr;
                        Co[(size_t)s * N + cl] += gvl * (acc[mi][ni][i] + bias[cl]);
                    }
                }
            }
        }
    }
}

// ---------------------------------------------------------------------------
extern "C" void kernel_launch(void* const* d_in, const int* in_sizes, int n_in,
                              void* d_out, int out_size, void* d_ws, size_t ws_size,
                              hipStream_t stream)
{
    const float* x    = (const float*)d_in[0];
    const float* ln1g = (const float*)d_in[1];
    const float* ln1b = (const float*)d_in[2];
    const float* Wqkv = (const float*)d_in[3];
    const float* bqkv = (const float*)d_in[4];
    const float* Wout = (const float*)d_in[5];
    const float* bout = (const float*)d_in[6];
    const float* ln2g = (const float*)d_in[7];
    const float* ln2b = (const float*)d_in[8];
    const float* wg   = (const float*)d_in[9];
    const float* w1   = (const float*)d_in[10];
    const float* b1   = (const float*)d_in[11];
    const float* w2   = (const float*)d_in[12];
    const float* b2   = (const float*)d_in[13];
    float* out = (float*)d_out;

    // Workspace (MiB offsets), lifetime-scheduled. Peak ~196 MiB.
    char* ws = (char*)d_ws;
    ushort_t* ahi   = (ushort_t*)ws;
    ushort_t* alo   = (ushort_t*)(ws + ((size_t)16  << 20));
    float*    buf_h = (float*)ws;
    ushort_t* qkvh  = (ushort_t*)(ws + ((size_t)32  << 20));
    ushort_t* qkvl  = (ushort_t*)(ws + ((size_t)80  << 20));
    ushort_t* vth   = (ushort_t*)(ws + ((size_t)128 << 20));
    ushort_t* vtl   = (ushort_t*)(ws + ((size_t)144 << 20));
    ushort_t* ohi   = (ushort_t*)(ws + ((size_t)160 << 20));
    ushort_t* olo   = (ushort_t*)(ws + ((size_t)176 << 20));
    ushort_t* wqh   = (ushort_t*)(ws + ((size_t)128 << 20));   // ph1 only
    ushort_t* wql   = (ushort_t*)(ws + ((size_t)134 << 20));   // ph1 only
    ushort_t* woh   = (ushort_t*)(ws + ((size_t)192 << 20));
    ushort_t* wol   = (ushort_t*)(ws + ((size_t)194 << 20));
    ushort_t* w1t   = (ushort_t*)(ws + ((size_t)32  << 20));
    ushort_t* w2t   = (ushort_t*)(ws + ((size_t)32  << 20));
    ushort_t* dispb = (ushort_t*)(ws + ((size_t)96  << 20));
    ushort_t* h1b   = (ushort_t*)(ws + ((size_t)112 << 20));
    float*    buf_gtop = (float*)(ws + ((size_t)196 << 20));
    float*    buf_gv   = buf_gtop + S_;
    int*      buf_idx  = (int*)(buf_gv + S_);
    int*      buf_ta   = buf_idx + S_;

    // --- pre-router path (f32-grade via bf16x3 MFMA) ---
    split_kernel<<<(3*M_*M_/4 + 255)/256, 256, 0, stream>>>(Wqkv, wqh, wql, 3*M_*M_/4);
    split_kernel<<<(M_*M_/4 + 255)/256, 256, 0, stream>>>(Wout, woh, wol, M_*M_/4);
    ln_split_kernel<<<S_, 256, 0, stream>>>(x, ln1g, ln1b, ahi, alo);
    gemm_bf16x3<2><<<dim3(3*M_/128, S_/128, 1), 256, 0, stream>>>(
        ahi, alo, wqh, wql, bqkv, nullptr, qkvh, qkvl, 3*M_, M_);
    vtrans_kernel<<<dim3(T_/64, H_, B_), 256, 0, stream>>>(qkvh, qkvl, vth, vtl);
    attn_mfma_kernel<<<dim3(1024, 1, 1), 256, 0, stream>>>(qkvh, qkvl, vth, vtl, ohi, olo);
    gemm_bf16x3<1><<<dim3(M_/128, S_/128, 1), 256, 0, stream>>>(
        ohi, olo, woh, wol, bout, x, out, nullptr, M_, M_);

    // --- router (exact f32) ---
    ln_kernel<<<S_, 256, 0, stream>>>(out, ln2g, ln2b, buf_h);
    gate_kernel<<<S_, 256, 0, stream>>>(buf_h, wg, buf_idx, buf_gtop);
    scan_kernel<<<1, 1024, 0, stream>>>(buf_idx, buf_gtop, buf_gv, buf_ta);
    dispatch_bf16_kernel<<<E_*C_, 256, 0, stream>>>(buf_h, buf_ta, dispb);

    // --- MoE FFN (bf16 MFMA, post-router) ---
    transpose_bf16_kernel<<<dim3(F_/32, M_/32, E_), 256, 0, stream>>>(w1, w1t, M_, F_);
    gemm_mfma<0><<<dim3(F_/128, C_/128, E_), 256, 0, stream>>>(
        dispb, w1t, b1, nullptr, nullptr, h1b, F_, M_,
        (long)C_*M_, (long)F_*M_, (long)F_, (long)C_*F_);
    transpose_bf16_kernel<<<dim3(M_/32, F_/32, E_), 256, 0, stream>>>(w2, w2t, F_, M_);
    gemm_mfma<1><<<dim3(M_/128, C_/128, E_), 256, 0, stream>>>(
        h1b, w2t, b2, buf_ta, buf_gv, out, M_, F_,
        (long)C_*F_, (long)M_*F_, (long)M_, 0);
}

// Round 13
// 981.757 us; speedup vs baseline: 1.1735x; 1.1735x over previous
//
#include <hip/hip_runtime.h>
#include <hip/hip_bf16.h>
#include <math.h>

#define B_ 4
#define T_ 2048
#define M_ 1024
#define H_ 16
#define E_ 8
#define S_ (B_*T_)      // 8192
#define C_ (S_/E_)      // 1024
#define D_ (M_/H_)      // 64
#define F_ (4*M_)       // 4096

typedef unsigned short ushort_t;
typedef __attribute__((ext_vector_type(8))) short bf16x8;
typedef __attribute__((ext_vector_type(4))) float f32x4;

__device__ __forceinline__ float gelu_exact(float x) {
    return 0.5f * x * (1.0f + erff(x * 0.70710678118654752440f));
}

__device__ __forceinline__ unsigned short f2bf(float f) {
    unsigned int u = __float_as_uint(f);
    u = (u + 0x7FFFu + ((u >> 16) & 1u)) >> 16;   // RNE
    return (unsigned short)u;
}

__device__ __forceinline__ float bf2f(unsigned short h) {
    return __uint_as_float(((unsigned)h) << 16);
}

__device__ __forceinline__ void gload_lds16(const void* g, void* l) {
    __builtin_amdgcn_global_load_lds(
        (const __attribute__((address_space(1))) unsigned int*)g,
        (__attribute__((address_space(3))) unsigned int*)l,
        16, 0, 0);
}

__device__ __forceinline__ void lgkm0() {
    asm volatile("s_waitcnt lgkmcnt(0)" ::: "memory");
}

// ---------------------------------------------------------------------------
// LayerNorm (f32 out).
// ---------------------------------------------------------------------------
__global__ __launch_bounds__(256) void ln_kernel(const float* __restrict__ x,
                                                 const float* __restrict__ g,
                                                 const float* __restrict__ bta,
                                                 float* __restrict__ out)
{
    const int row = blockIdx.x;
    const int tid = threadIdx.x;
    const float4 v = reinterpret_cast<const float4*>(x + (size_t)row * M_)[tid];
    float s = v.x + v.y + v.z + v.w;
    __shared__ float red[4];
    #pragma unroll
    for (int off = 32; off > 0; off >>= 1) s += __shfl_down(s, off);
    if ((tid & 63) == 0) red[tid >> 6] = s;
    __syncthreads();
    const float mu = (red[0] + red[1] + red[2] + red[3]) * (1.0f / (float)M_);
    __syncthreads();
    float4 d;
    d.x = v.x - mu; d.y = v.y - mu; d.z = v.z - mu; d.w = v.w - mu;
    float q = d.x*d.x + d.y*d.y + d.z*d.z + d.w*d.w;
    #pragma unroll
    for (int off = 32; off > 0; off >>= 1) q += __shfl_down(q, off);
    if ((tid & 63) == 0) red[tid >> 6] = q;
    __syncthreads();
    const float var  = (red[0] + red[1] + red[2] + red[3]) * (1.0f / (float)M_);
    const float rstd = 1.0f / sqrtf(var + 1e-5f);
    const float4 gv = reinterpret_cast<const float4*>(g)[tid];
    const float4 bv = reinterpret_cast<const float4*>(bta)[tid];
    float4 o;
    o.x = d.x * rstd * gv.x + bv.x;
    o.y = d.y * rstd * gv.y + bv.y;
    o.z = d.z * rstd * gv.z + bv.z;
    o.w = d.w * rstd * gv.w + bv.w;
    reinterpret_cast<float4*>(out + (size_t)row * M_)[tid] = o;
}

// LayerNorm fused with hi/lo bf16 split output.
__global__ __launch_bounds__(256) void ln_split_kernel(const float* __restrict__ x,
                                                       const float* __restrict__ g,
                                                       const float* __restrict__ bta,
                                                       ushort_t* __restrict__ hi,
                                                       ushort_t* __restrict__ lo)
{
    const int row = blockIdx.x;
    const int tid = threadIdx.x;
    const float4 v = reinterpret_cast<const float4*>(x + (size_t)row * M_)[tid];
    float s = v.x + v.y + v.z + v.w;
    __shared__ float red[4];
    #pragma unroll
    for (int off = 32; off > 0; off >>= 1) s += __shfl_down(s, off);
    if ((tid & 63) == 0) red[tid >> 6] = s;
    __syncthreads();
    const float mu = (red[0] + red[1] + red[2] + red[3]) * (1.0f / (float)M_);
    __syncthreads();
    float4 d;
    d.x = v.x - mu; d.y = v.y - mu; d.z = v.z - mu; d.w = v.w - mu;
    float q = d.x*d.x + d.y*d.y + d.z*d.z + d.w*d.w;
    #pragma unroll
    for (int off = 32; off > 0; off >>= 1) q += __shfl_down(q, off);
    if ((tid & 63) == 0) red[tid >> 6] = q;
    __syncthreads();
    const float var  = (red[0] + red[1] + red[2] + red[3]) * (1.0f / (float)M_);
    const float rstd = 1.0f / sqrtf(var + 1e-5f);
    const float4 gv = reinterpret_cast<const float4*>(g)[tid];
    const float4 bv = reinterpret_cast<const float4*>(bta)[tid];
    float o[4];
    o[0] = d.x * rstd * gv.x + bv.x;
    o[1] = d.y * rstd * gv.y + bv.y;
    o[2] = d.z * rstd * gv.z + bv.z;
    o[3] = d.w * rstd * gv.w + bv.w;
    ushort4 hh, ll;
    hh.x = f2bf(o[0]); ll.x = f2bf(o[0] - bf2f(hh.x));
    hh.y = f2bf(o[1]); ll.y = f2bf(o[1] - bf2f(hh.y));
    hh.z = f2bf(o[2]); ll.z = f2bf(o[2] - bf2f(hh.z));
    hh.w = f2bf(o[3]); ll.w = f2bf(o[3] - bf2f(hh.w));
    reinterpret_cast<ushort4*>(hi + (size_t)row * M_)[tid] = hh;
    reinterpret_cast<ushort4*>(lo + (size_t)row * M_)[tid] = ll;
}

// Elementwise f32 -> hi/lo bf16 split (weights).
__global__ __launch_bounds__(256) void split_kernel(const float* __restrict__ in,
                                                    ushort_t* __restrict__ hi,
                                                    ushort_t* __restrict__ lo,
                                                    int n4)
{
    const int i = blockIdx.x * 256 + threadIdx.x;
    if (i >= n4) return;
    const float4 v = reinterpret_cast<const float4*>(in)[i];
    ushort4 hh, ll;
    hh.x = f2bf(v.x); ll.x = f2bf(v.x - bf2f(hh.x));
    hh.y = f2bf(v.y); ll.y = f2bf(v.y - bf2f(hh.y));
    hh.z = f2bf(v.z); ll.z = f2bf(v.z - bf2f(hh.z));
    hh.w = f2bf(v.w); ll.w = f2bf(v.w - bf2f(hh.w));
    reinterpret_cast<ushort4*>(hi)[i] = hh;
    reinterpret_cast<ushort4*>(lo)[i] = ll;
}

// V^T pre-transpose: qkv hi/lo [s][3M] (V slice) -> vt hi/lo [(b*H+h)*64+d][T].
__global__ __launch_bounds__(256) void vtrans_kernel(const ushort_t* __restrict__ qkvh,
                                                     const ushort_t* __restrict__ qkvl,
                                                     ushort_t* __restrict__ vth,
                                                     ushort_t* __restrict__ vtl)
{
    __shared__ ushort_t tile[64][72];
    const int t0 = blockIdx.x * 64, h = blockIdx.y, b = blockIdx.z;
    const int tid = threadIdx.x;
    const int tr = tid & 63, dc = (tid >> 6) * 16;
    const size_t src = ((size_t)(b*T_ + t0 + tr)) * (3*M_) + 2*M_ + h*64 + dc;
    const int dr = tid & 63, tc = (tid >> 6) * 16;
    const size_t dst = ((size_t)((b*H_ + h)*64 + dr)) * T_ + t0 + tc;

    #pragma unroll
    for (int pass = 0; pass < 2; ++pass) {
        const ushort_t* in = pass ? qkvl : qkvh;
        ushort_t* outp     = pass ? vtl  : vth;
        *reinterpret_cast<bf16x8*>(&tile[tr][dc])     = *reinterpret_cast<const bf16x8*>(in + src);
        *reinterpret_cast<bf16x8*>(&tile[tr][dc + 8]) = *reinterpret_cast<const bf16x8*>(in + src + 8);
        __syncthreads();
        bf16x8 o0, o1;
        #pragma unroll
        for (int j = 0; j < 8; ++j) {
            o0[j] = (short)tile[tc + j][dr];
            o1[j] = (short)tile[tc + 8 + j][dr];
        }
        *reinterpret_cast<bf16x8*>(outp + dst)     = o0;
        *reinterpret_cast<bf16x8*>(outp + dst + 8) = o1;
        __syncthreads();
    }
}

// ---------------------------------------------------------------------------
// bf16x3 MFMA GEMM (f32-grade, pre-router). m97 structure, 4 LDS buffers.
// EPI 1: f32 out = acc + bias + res.   EPI 2: hi/lo bf16 out = split(acc+bias).
// ---------------------------------------------------------------------------
template<int EPI>
__global__ __launch_bounds__(256) void gemm_bf16x3(
    const ushort_t* __restrict__ Ahi, const ushort_t* __restrict__ Alo,
    const ushort_t* __restrict__ Bhi, const ushort_t* __restrict__ Blo,
    const float* __restrict__ bias, const float* __restrict__ res,
    void* __restrict__ C0, ushort_t* __restrict__ C1, int N, int K)
{
    __shared__ ushort_t AsH[128*32], AsL[128*32];
    __shared__ ushort_t BsH[128*32], BsL[128*32];

    const int t  = threadIdx.x;
    const int l  = t & 63;
    const int wv = t >> 6;
    const int wm = (wv & 1) * 64, wn = (wv >> 1) * 64;
    const int fr = l & 15, fk = (l >> 4) * 8;
    const int m0 = blockIdx.y * 128, n0 = blockIdx.x * 128;

    const size_t arow = (size_t)(m0 + (t >> 2)) * K + (t & 3) * 8;
    const size_t brow = (size_t)(n0 + (t >> 2)) * K + (t & 3) * 8;
    ushort_t* lAH = AsH + wv * 512;
    ushort_t* lAL = AsL + wv * 512;
    ushort_t* lBH = BsH + wv * 512;
    ushort_t* lBL = BsL + wv * 512;

    f32x4 acc[4][4] = {};

    for (int k0 = 0; k0 < K; k0 += 32) {
        __syncthreads();
        gload_lds16(Ahi + arow + k0, lAH);
        gload_lds16(Ahi + arow + k0 + (size_t)64 * K, lAH + 2048);
        gload_lds16(Alo + arow + k0, lAL);
        gload_lds16(Alo + arow + k0 + (size_t)64 * K, lAL + 2048);
        gload_lds16(Bhi + brow + k0, lBH);
        gload_lds16(Bhi + brow + k0 + (size_t)64 * K, lBH + 2048);
        gload_lds16(Blo + brow + k0, lBL);
        gload_lds16(Blo + brow + k0 + (size_t)64 * K, lBL + 2048);
        __syncthreads();
        bf16x8 ah[4], al[4], bh[4], bl[4];
        #pragma unroll
        for (int i = 0; i < 4; ++i) {
            ah[i] = *reinterpret_cast<const bf16x8*>(&AsH[(wm + i*16 + fr) * 32 + fk]);
            al[i] = *reinterpret_cast<const bf16x8*>(&AsL[(wm + i*16 + fr) * 32 + fk]);
            bh[i] = *reinterpret_cast<const bf16x8*>(&BsH[(wn + i*16 + fr) * 32 + fk]);
            bl[i] = *reinterpret_cast<const bf16x8*>(&BsL[(wn + i*16 + fr) * 32 + fk]);
        }
        #pragma unroll
        for (int mi = 0; mi < 4; ++mi) {
            #pragma unroll
            for (int ni = 0; ni < 4; ++ni) {
                acc[mi][ni] = __builtin_amdgcn_mfma_f32_16x16x32_bf16(ah[mi], bh[ni], acc[mi][ni], 0, 0, 0);
                acc[mi][ni] = __builtin_amdgcn_mfma_f32_16x16x32_bf16(al[mi], bh[ni], acc[mi][ni], 0, 0, 0);
                acc[mi][ni] = __builtin_amdgcn_mfma_f32_16x16x32_bf16(ah[mi], bl[ni], acc[mi][ni], 0, 0, 0);
            }
        }
    }

    // C/D: col = lane&15, row = (lane>>4)*4 + reg
    const int l4 = (l >> 4) * 4;
    #pragma unroll
    for (int mi = 0; mi < 4; ++mi) {
        #pragma unroll
        for (int i = 0; i < 4; ++i) {
            const int row = m0 + wm + mi*16 + l4 + i;
            #pragma unroll
            for (int ni = 0; ni < 4; ++ni) {
                const int col = n0 + wn + ni*16 + fr;
                float v = acc[mi][ni][i] + bias[col];
                if (EPI == 1) {
                    v += res[(size_t)row * N + col];
                    ((float*)C0)[(size_t)row * N + col] = v;
                } else {
                    const ushort_t hb = f2bf(v);
                    ((ushort_t*)C0)[(size_t)row * N + col] = hb;
                    C1[(size_t)row * N + col] = f2bf(v - bf2f(hb));
                }
            }
        }
    }
}

// ---------------------------------------------------------------------------
// bf16x3 MFMA flash attention — PERSISTENT, 1024 blocks, 2 snake-paired items
// each (j, 2047-j => 33 tiles/block). LDS diet kept from round 12 (P aliases
// K, 32 KB total, zero bank conflicts verified) but WITHOUT the register
// clamp: plain launch_bounds(256) => compiler picks ~92 VGPR (no spill), and
// 4 blocks/CU come naturally (92<=128 => 4 waves/SIMD; LDS 32KB <= 160/5).
// ---------------------------------------------------------------------------
__global__ __launch_bounds__(256) void attn_mfma_kernel(
    const ushort_t* __restrict__ qkvh, const ushort_t* __restrict__ qkvl,
    const ushort_t* __restrict__ vth,  const ushort_t* __restrict__ vtl,
    ushort_t* __restrict__ ohi, ushort_t* __restrict__ olo)
{
    const int j = (int)blockIdx.x;                 // 0..1023
    const int t = threadIdx.x;
    const int w = t >> 6, l = t & 63;
    const int r = l & 15, g = l >> 4;

    __shared__ ushort_t Khi[64*64], Klo[64*64];    // [kv][64] swizzled; P alias
    __shared__ ushort_t Vhi[64*64], Vlo[64*64];    // V^T [d][64 kv] swizzled

    ushort_t* Pwh = Khi + w * 1024;                // per-wave P [16 q][64 kv]
    ushort_t* Pwl = Klo + w * 1024;

    const int items[2] = { j, 2047 - j };

    // staging lane geometry (item-independent)
    const int srow = w*8 + (l >> 3);
    const int scol = ((l & 7) ^ (l >> 3)) * 8;
    const int d0 = w * 512 + l * 8;                // ushort index; +2048 = rows+32

    for (int ii = 0; ii < 2; ++ii) {
        const int item = items[ii];
        const int qt  = 31 - (item >> 6);          // rank -> qt (descending)
        const int rem = item & 63;
        const int h = rem >> 2, b = rem & 3;
        const int q0 = qt * 64;
        const size_t rowbase = (size_t)b * T_;
        const int hoff = h * D_;

        // Q fragments (A-frag: row = l&15, k = 32ks + 8g + j)
        bf16x8 qh[2], ql[2];
        {
            const size_t qrow = (rowbase + q0 + 16*w + r) * (size_t)(3*M_) + hoff;
            #pragma unroll
            for (int ks = 0; ks < 2; ++ks) {
                qh[ks] = *reinterpret_cast<const bf16x8*>(qkvh + qrow + 32*ks + 8*g);
                ql[ks] = *reinterpret_cast<const bf16x8*>(qkvl + qrow + 32*ks + 8*g);
            }
        }

        const size_t ksrc0 = (rowbase + srow) * (size_t)(3*M_) + hoff + M_ + scol;
        const size_t vsrc0 = ((size_t)((b*H_ + h)*64 + srow)) * T_ + scol;

        bf16x8 stg[8];
        __syncthreads();   // previous item's LDS readers done
        // prologue: stage tile 0
        {
            const size_t kb = ksrc0, vb = vsrc0;
            const size_t kstep = (size_t)32 * (3*M_);
            stg[0] = *reinterpret_cast<const bf16x8*>(qkvh + kb);
            stg[1] = *reinterpret_cast<const bf16x8*>(qkvh + kb + kstep);
            stg[2] = *reinterpret_cast<const bf16x8*>(qkvl + kb);
            stg[3] = *reinterpret_cast<const bf16x8*>(qkvl + kb + kstep);
            stg[4] = *reinterpret_cast<const bf16x8*>(vth + vb);
            stg[5] = *reinterpret_cast<const bf16x8*>(vth + vb + 32*T_);
            stg[6] = *reinterpret_cast<const bf16x8*>(vtl + vb);
            stg[7] = *reinterpret_cast<const bf16x8*>(vtl + vb + 32*T_);
            *reinterpret_cast<bf16x8*>(&Khi[d0])        = stg[0];
            *reinterpret_cast<bf16x8*>(&Khi[d0 + 2048]) = stg[1];
            *reinterpret_cast<bf16x8*>(&Klo[d0])        = stg[2];
            *reinterpret_cast<bf16x8*>(&Klo[d0 + 2048]) = stg[3];
            *reinterpret_cast<bf16x8*>(&Vhi[d0])        = stg[4];
            *reinterpret_cast<bf16x8*>(&Vhi[d0 + 2048]) = stg[5];
            *reinterpret_cast<bf16x8*>(&Vlo[d0])        = stg[6];
            *reinterpret_cast<bf16x8*>(&Vlo[d0 + 2048]) = stg[7];
        }
        __syncthreads();

        f32x4 oa[4] = {};
        float mrow[4] = {-__builtin_inff(), -__builtin_inff(), -__builtin_inff(), -__builtin_inff()};
        float lrow[4] = {};

        for (int kt = 0; kt <= qt; ++kt) {
            // ---- QK^T: S[16 q][64 kv], bf16x3, K frags from LDS ----
            f32x4 sa[4] = {};
            #pragma unroll
            for (int ks = 0; ks < 2; ++ks) {
                bf16x8 kh[4], kl[4];
                #pragma unroll
                for (int nf = 0; nf < 4; ++nf) {
                    const int row = 16*nf + r;
                    const unsigned boff = (unsigned)(row * 128)
                        + (((unsigned)(ks*64 + g*16)) ^ ((unsigned)((row & 7) << 4)));
                    kh[nf] = *reinterpret_cast<const bf16x8*>((const char*)Khi + boff);
                    kl[nf] = *reinterpret_cast<const bf16x8*>((const char*)Klo + boff);
                }
                #pragma unroll
                for (int nf = 0; nf < 4; ++nf) {
                    sa[nf] = __builtin_amdgcn_mfma_f32_16x16x32_bf16(qh[ks], kh[nf], sa[nf], 0, 0, 0);
                    sa[nf] = __builtin_amdgcn_mfma_f32_16x16x32_bf16(ql[ks], kh[nf], sa[nf], 0, 0, 0);
                    sa[nf] = __builtin_amdgcn_mfma_f32_16x16x32_bf16(qh[ks], kl[nf], sa[nf], 0, 0, 0);
                }
            }

            // ---- issue next tile's staging loads into registers (T14) ----
            if (kt < qt) {
                const size_t kb = ksrc0 + (size_t)((kt+1)*64) * (3*M_);
                const size_t vb = vsrc0 + (size_t)((kt+1)*64);
                const size_t kstep = (size_t)32 * (3*M_);
                stg[0] = *reinterpret_cast<const bf16x8*>(qkvh + kb);
                stg[1] = *reinterpret_cast<const bf16x8*>(qkvh + kb + kstep);
                stg[2] = *reinterpret_cast<const bf16x8*>(qkvl + kb);
                stg[3] = *reinterpret_cast<const bf16x8*>(qkvl + kb + kstep);
                stg[4] = *reinterpret_cast<const bf16x8*>(vth + vb);
                stg[5] = *reinterpret_cast<const bf16x8*>(vth + vb + 32*T_);
                stg[6] = *reinterpret_cast<const bf16x8*>(vtl + vb);
                stg[7] = *reinterpret_cast<const bf16x8*>(vtl + vb + 32*T_);
            }

            // ---- scale + causal mask ----
            float sv[4][4];
            #pragma unroll
            for (int nf = 0; nf < 4; ++nf)
                #pragma unroll
                for (int i = 0; i < 4; ++i)
                    sv[nf][i] = sa[nf][i] * 0.125f;
            if (kt == qt) {
                #pragma unroll
                for (int nf = 0; nf < 4; ++nf) {
                    const int kvg = kt*64 + 16*nf + r;
                    #pragma unroll
                    for (int i = 0; i < 4; ++i) {
                        const int qg = q0 + 16*w + 4*g + i;
                        if (kvg > qg) sv[nf][i] = -3.0e38f;
                    }
                }
            }

            // ---- online softmax (native exp) ----
            float tmax[4];
            #pragma unroll
            for (int i = 0; i < 4; ++i)
                tmax[i] = fmaxf(fmaxf(sv[0][i], sv[1][i]), fmaxf(sv[2][i], sv[3][i]));
            #pragma unroll
            for (int off = 1; off < 16; off <<= 1)
                #pragma unroll
                for (int i = 0; i < 4; ++i)
                    tmax[i] = fmaxf(tmax[i], __shfl_xor(tmax[i], off));
            float mnew[4], corr[4];
            #pragma unroll
            for (int i = 0; i < 4; ++i) {
                mnew[i] = fmaxf(mrow[i], tmax[i]);
                corr[i] = __expf(mrow[i] - mnew[i]);
            }
            float p[4][4];
            float rsum[4] = {};
            #pragma unroll
            for (int nf = 0; nf < 4; ++nf)
                #pragma unroll
                for (int i = 0; i < 4; ++i) {
                    p[nf][i] = __expf(sv[nf][i] - mnew[i]);
                    rsum[i] += p[nf][i];
                }
            #pragma unroll
            for (int off = 1; off < 16; off <<= 1)
                #pragma unroll
                for (int i = 0; i < 4; ++i)
                    rsum[i] += __shfl_xor(rsum[i], off);
            #pragma unroll
            for (int i = 0; i < 4; ++i) {
                lrow[i] = lrow[i] * corr[i] + rsum[i];
                mrow[i] = mnew[i];
            }
            #pragma unroll
            for (int df = 0; df < 4; ++df)
                #pragma unroll
                for (int i = 0; i < 4; ++i)
                    oa[df][i] *= corr[i];

            __syncthreads();   // all waves done reading K -> safe to alias P

            // ---- write P into K region (per-wave [16][64], XOR-swizzled) ----
            #pragma unroll
            for (int nf = 0; nf < 4; ++nf) {
                #pragma unroll
                for (int i = 0; i < 4; ++i) {
                    const int q = 4*g + i;
                    const int kv = (16*nf + r) ^ ((q & 7) << 3);
                    const ushort_t phb = f2bf(p[nf][i]);
                    Pwh[q * 64 + kv] = phb;
                    Pwl[q * 64 + kv] = f2bf(p[nf][i] - bf2f(phb));
                }
            }
            lgkm0();   // P writes visible to this wave's reads (per-wave slice)

            // ---- PV: O += P·V, bf16x3 ----
            #pragma unroll
            for (int ks = 0; ks < 2; ++ks) {
                const unsigned poff = (unsigned)(r * 64 + ((32*ks + 8*g) ^ ((r & 7) << 3)));
                const bf16x8 ph = *reinterpret_cast<const bf16x8*>(&Pwh[poff]);
                const bf16x8 pl = *reinterpret_cast<const bf16x8*>(&Pwl[poff]);
                #pragma unroll
                for (int df = 0; df < 4; ++df) {
                    const int vrow = 16*df + r;
                    const unsigned voff = (unsigned)(vrow * 128)
                        + (((unsigned)(ks*64 + g*16)) ^ ((unsigned)((vrow & 7) << 4)));
                    const bf16x8 vhf = *reinterpret_cast<const bf16x8*>((const char*)Vhi + voff);
                    const bf16x8 vlf = *reinterpret_cast<const bf16x8*>((const char*)Vlo + voff);
                    oa[df] = __builtin_amdgcn_mfma_f32_16x16x32_bf16(ph, vhf, oa[df], 0, 0, 0);
                    oa[df] = __builtin_amdgcn_mfma_f32_16x16x32_bf16(pl, vhf, oa[df], 0, 0, 0);
                    oa[df] = __builtin_amdgcn_mfma_f32_16x16x32_bf16(ph, vlf, oa[df], 0, 0, 0);
                }
            }

            // ---- commit staged registers to LDS for next tile ----
            if (kt < qt) {
                __syncthreads();                   // V readers done; P dead
                *reinterpret_cast<bf16x8*>(&Khi[d0])        = stg[0];
                *reinterpret_cast<bf16x8*>(&Khi[d0 + 2048]) = stg[1];
                *reinterpret_cast<bf16x8*>(&Klo[d0])        = stg[2];
                *reinterpret_cast<bf16x8*>(&Klo[d0 + 2048]) = stg[3];
                *reinterpret_cast<bf16x8*>(&Vhi[d0])        = stg[4];
                *reinterpret_cast<bf16x8*>(&Vhi[d0 + 2048]) = stg[5];
                *reinterpret_cast<bf16x8*>(&Vlo[d0])        = stg[6];
                *reinterpret_cast<bf16x8*>(&Vlo[d0 + 2048]) = stg[7];
                __syncthreads();                   // writes visible
            }
        }

        // ---- epilogue: hi/lo split of O / l ----
        #pragma unroll
        for (int i = 0; i < 4; ++i) {
            const float inv = 1.0f / lrow[i];
            const size_t row = (rowbase + q0 + 16*w + 4*g + i) * (size_t)M_ + hoff;
            #pragma unroll
            for (int df = 0; df < 4; ++df) {
                const float v = oa[df][i] * inv;
                const ushort_t hb = f2bf(v);
                ohi[row + 16*df + r] = hb;
                olo[row + 16*df + r] = f2bf(v - bf2f(hb));
            }
        }
    }
}

// ---------------------------------------------------------------------------
// Router + deepspeed dispatch bookkeeping (exact, f32).
// ---------------------------------------------------------------------------
__global__ __launch_bounds__(256) void gate_kernel(const float* __restrict__ h2,
                                                   const float* __restrict__ wg,
                                                   int* __restrict__ gidx,
                                                   float* __restrict__ gtop)
{
    const int s = blockIdx.x;
    const int e = threadIdx.x >> 5;
    const int l = threadIdx.x & 31;
    const float* row = h2 + (size_t)s * M_;
    float acc = 0.0f;
    for (int m = l; m < M_; m += 32) acc = fmaf(row[m], wg[m * E_ + e], acc);
    #pragma unroll
    for (int off = 16; off > 0; off >>= 1) acc += __shfl_down(acc, off, 32);
    __shared__ float lg[E_];
    if (l == 0) lg[e] = acc;
    __syncthreads();
    if (threadIdx.x == 0) {
        float mx = lg[0]; int bi = 0;
        #pragma unroll
        for (int i = 1; i < E_; ++i) { if (lg[i] > mx) { mx = lg[i]; bi = i; } }
        float den = 0.0f;
        #pragma unroll
        for (int i = 0; i < E_; ++i) den += expf(lg[i] - mx);
        gidx[s] = bi;
        gtop[s] = 1.0f / den;
    }
}

__global__ __launch_bounds__(1024) void scan_kernel(const int* __restrict__ gidx,
                                                    const float* __restrict__ gtop,
                                                    float* __restrict__ gate_val,
                                                    int* __restrict__ token_at)
{
    __shared__ int hist[1024][E_];
    const int tid = threadIdx.x;
    for (int i = tid; i < E_ * C_; i += 1024) token_at[i] = -1;
    int my[8];
    #pragma unroll
    for (int t = 0; t < 8; ++t) my[t] = gidx[tid * 8 + t];
    #pragma unroll
    for (int e = 0; e < E_; ++e) {
        int c = 0;
        #pragma unroll
        for (int t = 0; t < 8; ++t) c += (my[t] == e) ? 1 : 0;
        hist[tid][e] = c;
    }
    __syncthreads();
    if (tid < E_) {
        int run = 0;
        for (int t = 0; t < 1024; ++t) {
            const int v = hist[t][tid];
            hist[t][tid] = run;
            run += v;
        }
    }
    __syncthreads();
    #pragma unroll
    for (int t = 0; t < 8; ++t) {
        const int s = tid * 8 + t;
        const int e = my[t];
        const int p = hist[tid][e];
        hist[tid][e] = p + 1;
        const bool keep = (p < C_);
        gate_val[s] = keep ? gtop[s] : 0.0f;
        if (keep) token_at[e * C_ + p] = s;
    }
}

__global__ __launch_bounds__(256) void dispatch_bf16_kernel(const float* __restrict__ h2,
                                                            const int* __restrict__ token_at,
                                                            ushort_t* __restrict__ disp)
{
    const int ec = blockIdx.x;
    const int s = token_at[ec];
    ushort4* dst = reinterpret_cast<ushort4*>(disp + (size_t)ec * M_);
    if (s >= 0) {
        const float4 v = reinterpret_cast<const float4*>(h2 + (size_t)s * M_)[threadIdx.x];
        dst[threadIdx.x] = make_ushort4(f2bf(v.x), f2bf(v.y), f2bf(v.z), f2bf(v.w));
    } else {
        dst[threadIdx.x] = make_ushort4(0, 0, 0, 0);
    }
}

// Transpose+convert: in[e][R][Cc] f32 -> out[e][Cc][R] bf16.
__global__ __launch_bounds__(256) void transpose_bf16_kernel(const float* __restrict__ in,
                                                             ushort_t* __restrict__ outp,
                                                             int R, int Cc)
{
    __shared__ float tile[32][33];
    const int e = blockIdx.z;
    in   += (size_t)e * R * Cc;
    outp += (size_t)e * R * Cc;
    const int tx = threadIdx.x & 31, ty0 = threadIdx.x >> 5;
    const int c0 = blockIdx.x * 32, r0 = blockIdx.y * 32;
    #pragma unroll
    for (int i = 0; i < 4; ++i)
        tile[ty0 + 8*i][tx] = in[(size_t)(r0 + ty0 + 8*i) * Cc + c0 + tx];
    __syncthreads();
    #pragma unroll
    for (int i = 0; i < 4; ++i)
        outp[(size_t)(c0 + ty0 + 8*i) * R + r0 + tx] = f2bf(tile[tx][ty0 + 8*i]);
}

// ---------------------------------------------------------------------------
// bf16 MFMA GEMM (MoE FFN, post-router) — unchanged, verified.
// ---------------------------------------------------------------------------
template<int EPI>
__global__ __launch_bounds__(256) void gemm_mfma(
    const ushort_t* __restrict__ A, const ushort_t* __restrict__ Bt,
    const float* __restrict__ bias,
    const int* __restrict__ token_at, const float* __restrict__ gate_val,
    void* __restrict__ Cout, int N, int K,
    long strA, long strB, long strBias, long strC)
{
    const int e = blockIdx.z;
    A    += (size_t)e * (size_t)strA;
    Bt   += (size_t)e * (size_t)strB;
    bias += (size_t)e * (size_t)strBias;

    __shared__ ushort_t As[128 * 32];
    __shared__ ushort_t Bs[128 * 32];

    const int t  = threadIdx.x;
    const int l  = t & 63;
    const int wv = t >> 6;
    const int wm = (wv & 1) * 64, wn = (wv >> 1) * 64;
    const int fr = l & 15, fk = (l >> 4) * 8;
    const int m0 = blockIdx.y * 128, n0 = blockIdx.x * 128;

    const ushort_t* gA = A + (size_t)(m0 + (t >> 2)) * K + (t & 3) * 8;
    const ushort_t* gB = Bt + (size_t)(n0 + (t >> 2)) * K + (t & 3) * 8;
    ushort_t* lA = As + wv * 512;
    ushort_t* lB = Bs + wv * 512;

    f32x4 acc[4][4] = {};

    for (int k0 = 0; k0 < K; k0 += 32) {
        __syncthreads();
        gload_lds16(gA + k0, lA);
        gload_lds16(gA + k0 + (size_t)64 * K, lA + 2048);
        gload_lds16(gB + k0, lB);
        gload_lds16(gB + k0 + (size_t)64 * K, lB + 2048);
        __syncthreads();
        bf16x8 af[4], bfr[4];
        #pragma unroll
        for (int i = 0; i < 4; ++i)
            af[i] = *reinterpret_cast<const bf16x8*>(&As[(wm + i*16 + fr) * 32 + fk]);
        #pragma unroll
        for (int i = 0; i < 4; ++i)
            bfr[i] = *reinterpret_cast<const bf16x8*>(&Bs[(wn + i*16 + fr) * 32 + fk]);
        #pragma unroll
        for (int mi = 0; mi < 4; ++mi) {
            #pragma unroll
            for (int ni = 0; ni < 4; ++ni)
                acc[mi][ni] = __builtin_amdgcn_mfma_f32_16x16x32_bf16(
                    af[mi], bfr[ni], acc[mi][ni], 0, 0, 0);
        }
    }

    const int l4 = (l >> 4) * 4;
    if (EPI == 0) {
        ushort_t* Cc = (ushort_t*)Cout + (size_t)e * (size_t)strC;
        #pragma unroll
        for (int ni = 0; ni < 4; ++ni) {
            const int cl = n0 + wn + ni*16 + fr;
            const float bb = bias[cl];
            #pragma unroll
            for (int mi = 0; mi < 4; ++mi) {
                #pragma unroll
                for (int i = 0; i < 4; ++i) {
                    const int rr = m0 + wm + mi*16 + l4 + i;
                    Cc[(size_t)rr * N + cl] = f2bf(gelu_exact(acc[mi][ni][i] + bb));
                }
            }
        }
    } else {
        float* Co = (float*)Cout;
        const int* ta = token_at + e * C_;
        #pragma unroll
        for (int mi = 0; mi < 4; ++mi) {
            #pragma unroll
            for (int i = 0; i < 4; ++i) {
                const int rr = m0 + wm + mi*16 + l4 + i;
                const int s = ta[rr];
                if (s >= 0) {
                    const float gvl = gate_val[s];
                    #pragma unroll
                    for (int ni = 0; ni < 4; ++ni) {
                        const int cl = n0 + wn + ni*16 + fr;
                        Co[(size_t)s * N + cl] += gvl * (acc[mi][ni][i] + bias[cl]);
                    }
                }
            }
        }
    }
}

// ---------------------------------------------------------------------------
extern "C" void kernel_launch(void* const* d_in, const int* in_sizes, int n_in,
                              void* d_out, int out_size, void* d_ws, size_t ws_size,
                              hipStream_t stream)
{
    const float* x    = (const float*)d_in[0];
    const float* ln1g = (const float*)d_in[1];
    const float* ln1b = (const float*)d_in[2];
    const float* Wqkv = (const float*)d_in[3];
    const float* bqkv = (const float*)d_in[4];
    const float* Wout = (const float*)d_in[5];
    const float* bout = (const float*)d_in[6];
    const float* ln2g = (const float*)d_in[7];
    const float* ln2b = (const float*)d_in[8];
    const float* wg   = (const float*)d_in[9];
    const float* w1   = (const float*)d_in[10];
    const float* b1   = (const float*)d_in[11];
    const float* w2   = (const float*)d_in[12];
    const float* b2   = (const float*)d_in[13];
    float* out = (float*)d_out;

    // Workspace (MiB offsets), lifetime-scheduled. Peak ~196 MiB.
    char* ws = (char*)d_ws;
    ushort_t* ahi   = (ushort_t*)ws;
    ushort_t* alo   = (ushort_t*)(ws + ((size_t)16  << 20));
    float*    buf_h = (float*)ws;
    ushort_t* qkvh  = (ushort_t*)(ws + ((size_t)32  << 20));
    ushort_t* qkvl  = (ushort_t*)(ws + ((size_t)80  << 20));
    ushort_t* vth   = (ushort_t*)(ws + ((size_t)128 << 20));
    ushort_t* vtl   = (ushort_t*)(ws + ((size_t)144 << 20));
    ushort_t* ohi   = (ushort_t*)(ws + ((size_t)160 << 20));
    ushort_t* olo   = (ushort_t*)(ws + ((size_t)176 << 20));
    ushort_t* wqh   = (ushort_t*)(ws + ((size_t)128 << 20));   // ph1 only
    ushort_t* wql   = (ushort_t*)(ws + ((size_t)134 << 20));   // ph1 only
    ushort_t* woh   = (ushort_t*)(ws + ((size_t)192 << 20));
    ushort_t* wol   = (ushort_t*)(ws + ((size_t)194 << 20));
    ushort_t* w1t   = (ushort_t*)(ws + ((size_t)32  << 20));
    ushort_t* w2t   = (ushort_t*)(ws + ((size_t)32  << 20));
    ushort_t* dispb = (ushort_t*)(ws + ((size_t)96  << 20));
    ushort_t* h1b   = (ushort_t*)(ws + ((size_t)112 << 20));
    float*    buf_gtop = (float*)(ws + ((size_t)196 << 20));
    float*    buf_gv   = buf_gtop + S_;
    int*      buf_idx  = (int*)(buf_gv + S_);
    int*      buf_ta   = buf_idx + S_;

    // --- pre-router path (f32-grade via bf16x3 MFMA) ---
    split_kernel<<<(3*M_*M_/4 + 255)/256, 256, 0, stream>>>(Wqkv, wqh, wql, 3*M_*M_/4);
    split_kernel<<<(M_*M_/4 + 255)/256, 256, 0, stream>>>(Wout, woh, wol, M_*M_/4);
    ln_split_kernel<<<S_, 256, 0, stream>>>(x, ln1g, ln1b, ahi, alo);
    gemm_bf16x3<2><<<dim3(3*M_/128, S_/128, 1), 256, 0, stream>>>(
        ahi, alo, wqh, wql, bqkv, nullptr, qkvh, qkvl, 3*M_, M_);
    vtrans_kernel<<<dim3(T_/64, H_, B_), 256, 0, stream>>>(qkvh, qkvl, vth, vtl);
    attn_mfma_kernel<<<dim3(1024, 1, 1), 256, 0, stream>>>(qkvh, qkvl, vth, vtl, ohi, olo);
    gemm_bf16x3<1><<<dim3(M_/128, S_/128, 1), 256, 0, stream>>>(
        ohi, olo, woh, wol, bout, x, out, nullptr, M_, M_);

    // --- router (exact f32) ---
    ln_kernel<<<S_, 256, 0, stream>>>(out, ln2g, ln2b, buf_h);
    gate_kernel<<<S_, 256, 0, stream>>>(buf_h, wg, buf_idx, buf_gtop);
    scan_kernel<<<1, 1024, 0, stream>>>(buf_idx, buf_gtop, buf_gv, buf_ta);
    dispatch_bf16_kernel<<<E_*C_, 256, 0, stream>>>(buf_h, buf_ta, dispb);

    // --- MoE FFN (bf16 MFMA, post-router) ---
    transpose_bf16_kernel<<<dim3(F_/32, M_/32, E_), 256, 0, stream>>>(w1, w1t, M_, F_);
    gemm_mfma<0><<<dim3(F_/128, C_/128, E_), 256, 0, stream>>>(
        dispb, w1t, b1, nullptr, nullptr, h1b, F_, M_,
        (long)C_*M_, (long)F_*M_, (long)F_, (long)C_*F_);
    transpose_bf16_kernel<<<dim3(M_/32, F_/32, E_), 256, 0, stream>>>(w2, w2t, F_, M_);
    gemm_mfma<1><<<dim3(M_/128, C_/128, E_), 256, 0, stream>>>(
        h1b, w2t, b2, buf_ta, buf_gv, out, M_, F_,
        (long)C_*F_, (long)M_*F_, (long)M_, 0);
}

// Round 14
// 908.499 us; speedup vs baseline: 1.2681x; 1.0806x over previous
//
#include <hip/hip_runtime.h>
#include <hip/hip_bf16.h>
#include <math.h>

#define B_ 4
#define T_ 2048
#define M_ 1024
#define H_ 16
#define E_ 8
#define S_ (B_*T_)      // 8192
#define C_ (S_/E_)      // 1024
#define D_ (M_/H_)      // 64
#define F_ (4*M_)       // 4096

typedef unsigned short ushort_t;
typedef __attribute__((ext_vector_type(8))) short bf16x8;
typedef __attribute__((ext_vector_type(4))) float f32x4;

__device__ __forceinline__ float gelu_exact(float x) {
    return 0.5f * x * (1.0f + erff(x * 0.70710678118654752440f));
}

__device__ __forceinline__ unsigned short f2bf(float f) {
    unsigned int u = __float_as_uint(f);
    u = (u + 0x7FFFu + ((u >> 16) & 1u)) >> 16;   // RNE
    return (unsigned short)u;
}

__device__ __forceinline__ float bf2f(unsigned short h) {
    return __uint_as_float(((unsigned)h) << 16);
}

__device__ __forceinline__ void gload_lds16(const void* g, void* l) {
    __builtin_amdgcn_global_load_lds(
        (const __attribute__((address_space(1))) unsigned int*)g,
        (__attribute__((address_space(3))) unsigned int*)l,
        16, 0, 0);
}

__device__ __forceinline__ void lgkm0() {
    asm volatile("s_waitcnt lgkmcnt(0)" ::: "memory");
}

// ---------------------------------------------------------------------------
// LayerNorm fused with hi/lo bf16 split output (LN1).
// ---------------------------------------------------------------------------
__global__ __launch_bounds__(256) void ln_split_kernel(const float* __restrict__ x,
                                                       const float* __restrict__ g,
                                                       const float* __restrict__ bta,
                                                       ushort_t* __restrict__ hi,
                                                       ushort_t* __restrict__ lo)
{
    const int row = blockIdx.x;
    const int tid = threadIdx.x;
    const float4 v = reinterpret_cast<const float4*>(x + (size_t)row * M_)[tid];
    float s = v.x + v.y + v.z + v.w;
    __shared__ float red[4];
    #pragma unroll
    for (int off = 32; off > 0; off >>= 1) s += __shfl_down(s, off);
    if ((tid & 63) == 0) red[tid >> 6] = s;
    __syncthreads();
    const float mu = (red[0] + red[1] + red[2] + red[3]) * (1.0f / (float)M_);
    __syncthreads();
    float4 d;
    d.x = v.x - mu; d.y = v.y - mu; d.z = v.z - mu; d.w = v.w - mu;
    float q = d.x*d.x + d.y*d.y + d.z*d.z + d.w*d.w;
    #pragma unroll
    for (int off = 32; off > 0; off >>= 1) q += __shfl_down(q, off);
    if ((tid & 63) == 0) red[tid >> 6] = q;
    __syncthreads();
    const float var  = (red[0] + red[1] + red[2] + red[3]) * (1.0f / (float)M_);
    const float rstd = 1.0f / sqrtf(var + 1e-5f);
    const float4 gv = reinterpret_cast<const float4*>(g)[tid];
    const float4 bv = reinterpret_cast<const float4*>(bta)[tid];
    float o[4];
    o[0] = d.x * rstd * gv.x + bv.x;
    o[1] = d.y * rstd * gv.y + bv.y;
    o[2] = d.z * rstd * gv.z + bv.z;
    o[3] = d.w * rstd * gv.w + bv.w;
    ushort4 hh, ll;
    hh.x = f2bf(o[0]); ll.x = f2bf(o[0] - bf2f(hh.x));
    hh.y = f2bf(o[1]); ll.y = f2bf(o[1] - bf2f(hh.y));
    hh.z = f2bf(o[2]); ll.z = f2bf(o[2] - bf2f(hh.z));
    hh.w = f2bf(o[3]); ll.w = f2bf(o[3] - bf2f(hh.w));
    reinterpret_cast<ushort4*>(hi + (size_t)row * M_)[tid] = hh;
    reinterpret_cast<ushort4*>(lo + (size_t)row * M_)[tid] = ll;
}

// ---------------------------------------------------------------------------
// Fused LN2 + router gate: h2 = LN(out) (f32, for dispatch), plus per-token
// logits = h2 @ wg, first-max-wins argmax, gtop = softmax value of top expert.
// ---------------------------------------------------------------------------
__global__ __launch_bounds__(256) void ln_gate_kernel(const float* __restrict__ x,
                                                      const float* __restrict__ g,
                                                      const float* __restrict__ bta,
                                                      const float* __restrict__ wg,
                                                      float* __restrict__ h2,
                                                      int* __restrict__ gidx,
                                                      float* __restrict__ gtop)
{
    const int row = blockIdx.x;
    const int tid = threadIdx.x;
    const int wv = tid >> 6, ln = tid & 63;
    const float4 v = reinterpret_cast<const float4*>(x + (size_t)row * M_)[tid];
    float s = v.x + v.y + v.z + v.w;
    __shared__ float red[4];
    __shared__ float red2[4][E_];
    #pragma unroll
    for (int off = 32; off > 0; off >>= 1) s += __shfl_down(s, off);
    if (ln == 0) red[wv] = s;
    __syncthreads();
    const float mu = (red[0] + red[1] + red[2] + red[3]) * (1.0f / (float)M_);
    __syncthreads();
    float4 d;
    d.x = v.x - mu; d.y = v.y - mu; d.z = v.z - mu; d.w = v.w - mu;
    float q = d.x*d.x + d.y*d.y + d.z*d.z + d.w*d.w;
    #pragma unroll
    for (int off = 32; off > 0; off >>= 1) q += __shfl_down(q, off);
    if (ln == 0) red[wv] = q;
    __syncthreads();
    const float var  = (red[0] + red[1] + red[2] + red[3]) * (1.0f / (float)M_);
    const float rstd = 1.0f / sqrtf(var + 1e-5f);
    const float4 gv = reinterpret_cast<const float4*>(g)[tid];
    const float4 bv = reinterpret_cast<const float4*>(bta)[tid];
    float o[4];
    o[0] = d.x * rstd * gv.x + bv.x;
    o[1] = d.y * rstd * gv.y + bv.y;
    o[2] = d.z * rstd * gv.z + bv.z;
    o[3] = d.w * rstd * gv.w + bv.w;
    reinterpret_cast<float4*>(h2 + (size_t)row * M_)[tid] = make_float4(o[0], o[1], o[2], o[3]);

    // logits: thread covers cols 4*tid..4*tid+3; wg is [M][E] row-major.
    float part[E_] = {};
    #pragma unroll
    for (int j = 0; j < 4; ++j) {
        const float4 w0 = reinterpret_cast<const float4*>(wg)[(4*tid + j) * 2];
        const float4 w1 = reinterpret_cast<const float4*>(wg)[(4*tid + j) * 2 + 1];
        part[0] = fmaf(o[j], w0.x, part[0]); part[1] = fmaf(o[j], w0.y, part[1]);
        part[2] = fmaf(o[j], w0.z, part[2]); part[3] = fmaf(o[j], w0.w, part[3]);
        part[4] = fmaf(o[j], w1.x, part[4]); part[5] = fmaf(o[j], w1.y, part[5]);
        part[6] = fmaf(o[j], w1.z, part[6]); part[7] = fmaf(o[j], w1.w, part[7]);
    }
    #pragma unroll
    for (int off = 32; off > 0; off >>= 1)
        #pragma unroll
        for (int e = 0; e < E_; ++e) part[e] += __shfl_down(part[e], off);
    if (ln == 0)
        #pragma unroll
        for (int e = 0; e < E_; ++e) red2[wv][e] = part[e];
    __syncthreads();
    if (tid == 0) {
        float lg[E_];
        #pragma unroll
        for (int e = 0; e < E_; ++e)
            lg[e] = red2[0][e] + red2[1][e] + red2[2][e] + red2[3][e];
        float mx = lg[0]; int bi = 0;
        #pragma unroll
        for (int i = 1; i < E_; ++i) { if (lg[i] > mx) { mx = lg[i]; bi = i; } }
        float den = 0.0f;
        #pragma unroll
        for (int i = 0; i < E_; ++i) den += expf(lg[i] - mx);
        gidx[row] = bi;
        gtop[row] = 1.0f / den;
    }
}

// Elementwise f32 -> hi/lo bf16 split (weights).
__global__ __launch_bounds__(256) void split_kernel(const float* __restrict__ in,
                                                    ushort_t* __restrict__ hi,
                                                    ushort_t* __restrict__ lo,
                                                    int n4)
{
    const int i = blockIdx.x * 256 + threadIdx.x;
    if (i >= n4) return;
    const float4 v = reinterpret_cast<const float4*>(in)[i];
    ushort4 hh, ll;
    hh.x = f2bf(v.x); ll.x = f2bf(v.x - bf2f(hh.x));
    hh.y = f2bf(v.y); ll.y = f2bf(v.y - bf2f(hh.y));
    hh.z = f2bf(v.z); ll.z = f2bf(v.z - bf2f(hh.z));
    hh.w = f2bf(v.w); ll.w = f2bf(v.w - bf2f(hh.w));
    reinterpret_cast<ushort4*>(hi)[i] = hh;
    reinterpret_cast<ushort4*>(lo)[i] = ll;
}

// V^T pre-transpose: qkv hi/lo [s][3M] (V slice) -> vt hi/lo [(b*H+h)*64+d][T].
__global__ __launch_bounds__(256) void vtrans_kernel(const ushort_t* __restrict__ qkvh,
                                                     const ushort_t* __restrict__ qkvl,
                                                     ushort_t* __restrict__ vth,
                                                     ushort_t* __restrict__ vtl)
{
    __shared__ ushort_t tile[64][72];
    const int t0 = blockIdx.x * 64, h = blockIdx.y, b = blockIdx.z;
    const int tid = threadIdx.x;
    const int tr = tid & 63, dc = (tid >> 6) * 16;
    const size_t src = ((size_t)(b*T_ + t0 + tr)) * (3*M_) + 2*M_ + h*64 + dc;
    const int dr = tid & 63, tc = (tid >> 6) * 16;
    const size_t dst = ((size_t)((b*H_ + h)*64 + dr)) * T_ + t0 + tc;

    #pragma unroll
    for (int pass = 0; pass < 2; ++pass) {
        const ushort_t* in = pass ? qkvl : qkvh;
        ushort_t* outp     = pass ? vtl  : vth;
        *reinterpret_cast<bf16x8*>(&tile[tr][dc])     = *reinterpret_cast<const bf16x8*>(in + src);
        *reinterpret_cast<bf16x8*>(&tile[tr][dc + 8]) = *reinterpret_cast<const bf16x8*>(in + src + 8);
        __syncthreads();
        bf16x8 o0, o1;
        #pragma unroll
        for (int j = 0; j < 8; ++j) {
            o0[j] = (short)tile[tc + j][dr];
            o1[j] = (short)tile[tc + 8 + j][dr];
        }
        *reinterpret_cast<bf16x8*>(outp + dst)     = o0;
        *reinterpret_cast<bf16x8*>(outp + dst + 8) = o1;
        __syncthreads();
    }
}

// ---------------------------------------------------------------------------
// bf16x3 MFMA GEMM (f32-grade, pre-router). m97 structure, 4 LDS buffers.
// EPI 1: f32 out = acc + bias + res.   EPI 2: hi/lo bf16 out = split(acc+bias).
// ---------------------------------------------------------------------------
template<int EPI>
__global__ __launch_bounds__(256) void gemm_bf16x3(
    const ushort_t* __restrict__ Ahi, const ushort_t* __restrict__ Alo,
    const ushort_t* __restrict__ Bhi, const ushort_t* __restrict__ Blo,
    const float* __restrict__ bias, const float* __restrict__ res,
    void* __restrict__ C0, ushort_t* __restrict__ C1, int N, int K)
{
    __shared__ ushort_t AsH[128*32], AsL[128*32];
    __shared__ ushort_t BsH[128*32], BsL[128*32];

    const int t  = threadIdx.x;
    const int l  = t & 63;
    const int wv = t >> 6;
    const int wm = (wv & 1) * 64, wn = (wv >> 1) * 64;
    const int fr = l & 15, fk = (l >> 4) * 8;
    const int m0 = blockIdx.y * 128, n0 = blockIdx.x * 128;

    const size_t arow = (size_t)(m0 + (t >> 2)) * K + (t & 3) * 8;
    const size_t brow = (size_t)(n0 + (t >> 2)) * K + (t & 3) * 8;
    ushort_t* lAH = AsH + wv * 512;
    ushort_t* lAL = AsL + wv * 512;
    ushort_t* lBH = BsH + wv * 512;
    ushort_t* lBL = BsL + wv * 512;

    f32x4 acc[4][4] = {};

    for (int k0 = 0; k0 < K; k0 += 32) {
        __syncthreads();
        gload_lds16(Ahi + arow + k0, lAH);
        gload_lds16(Ahi + arow + k0 + (size_t)64 * K, lAH + 2048);
        gload_lds16(Alo + arow + k0, lAL);
        gload_lds16(Alo + arow + k0 + (size_t)64 * K, lAL + 2048);
        gload_lds16(Bhi + brow + k0, lBH);
        gload_lds16(Bhi + brow + k0 + (size_t)64 * K, lBH + 2048);
        gload_lds16(Blo + brow + k0, lBL);
        gload_lds16(Blo + brow + k0 + (size_t)64 * K, lBL + 2048);
        __syncthreads();
        bf16x8 ah[4], al[4], bh[4], bl[4];
        #pragma unroll
        for (int i = 0; i < 4; ++i) {
            ah[i] = *reinterpret_cast<const bf16x8*>(&AsH[(wm + i*16 + fr) * 32 + fk]);
            al[i] = *reinterpret_cast<const bf16x8*>(&AsL[(wm + i*16 + fr) * 32 + fk]);
            bh[i] = *reinterpret_cast<const bf16x8*>(&BsH[(wn + i*16 + fr) * 32 + fk]);
            bl[i] = *reinterpret_cast<const bf16x8*>(&BsL[(wn + i*16 + fr) * 32 + fk]);
        }
        #pragma unroll
        for (int mi = 0; mi < 4; ++mi) {
            #pragma unroll
            for (int ni = 0; ni < 4; ++ni) {
                acc[mi][ni] = __builtin_amdgcn_mfma_f32_16x16x32_bf16(ah[mi], bh[ni], acc[mi][ni], 0, 0, 0);
                acc[mi][ni] = __builtin_amdgcn_mfma_f32_16x16x32_bf16(al[mi], bh[ni], acc[mi][ni], 0, 0, 0);
                acc[mi][ni] = __builtin_amdgcn_mfma_f32_16x16x32_bf16(ah[mi], bl[ni], acc[mi][ni], 0, 0, 0);
            }
        }
    }

    // C/D: col = lane&15, row = (lane>>4)*4 + reg
    const int l4 = (l >> 4) * 4;
    #pragma unroll
    for (int mi = 0; mi < 4; ++mi) {
        #pragma unroll
        for (int i = 0; i < 4; ++i) {
            const int row = m0 + wm + mi*16 + l4 + i;
            #pragma unroll
            for (int ni = 0; ni < 4; ++ni) {
                const int col = n0 + wn + ni*16 + fr;
                float v = acc[mi][ni][i] + bias[col];
                if (EPI == 1) {
                    v += res[(size_t)row * N + col];
                    ((float*)C0)[(size_t)row * N + col] = v;
                } else {
                    const ushort_t hb = f2bf(v);
                    ((ushort_t*)C0)[(size_t)row * N + col] = hb;
                    C1[(size_t)row * N + col] = f2bf(v - bf2f(hb));
                }
            }
        }
    }
}

// ---------------------------------------------------------------------------
// bf16x3 MFMA flash attention — PERSISTENT, 1024 blocks, 2 snake-paired items
// each. LDS diet (P aliases K, 32 KB, zero bank conflicts) + natural VGPR
// allocation (no clamp, ~104 VGPR, no spill). Round-14 edits: (a) next-tile
// staging loads issued BEFORE QK^T (more latency hiding); (b) bit-identical
// defer-max fast path (skip corr-exp + O-rescale when corr==1 exactly).
// ---------------------------------------------------------------------------
__global__ __launch_bounds__(256) void attn_mfma_kernel(
    const ushort_t* __restrict__ qkvh, const ushort_t* __restrict__ qkvl,
    const ushort_t* __restrict__ vth,  const ushort_t* __restrict__ vtl,
    ushort_t* __restrict__ ohi, ushort_t* __restrict__ olo)
{
    const int j = (int)blockIdx.x;                 // 0..1023
    const int t = threadIdx.x;
    const int w = t >> 6, l = t & 63;
    const int r = l & 15, g = l >> 4;

    __shared__ ushort_t Khi[64*64], Klo[64*64];    // [kv][64] swizzled; P alias
    __shared__ ushort_t Vhi[64*64], Vlo[64*64];    // V^T [d][64 kv] swizzled

    ushort_t* Pwh = Khi + w * 1024;                // per-wave P [16 q][64 kv]
    ushort_t* Pwl = Klo + w * 1024;

    const int items[2] = { j, 2047 - j };

    // staging lane geometry (item-independent)
    const int srow = w*8 + (l >> 3);
    const int scol = ((l & 7) ^ (l >> 3)) * 8;
    const int d0 = w * 512 + l * 8;                // ushort index; +2048 = rows+32

    for (int ii = 0; ii < 2; ++ii) {
        const int item = items[ii];
        const int qt  = 31 - (item >> 6);          // rank -> qt (descending)
        const int rem = item & 63;
        const int h = rem >> 2, b = rem & 3;
        const int q0 = qt * 64;
        const size_t rowbase = (size_t)b * T_;
        const int hoff = h * D_;

        // Q fragments (A-frag: row = l&15, k = 32ks + 8g + j)
        bf16x8 qh[2], ql[2];
        {
            const size_t qrow = (rowbase + q0 + 16*w + r) * (size_t)(3*M_) + hoff;
            #pragma unroll
            for (int ks = 0; ks < 2; ++ks) {
                qh[ks] = *reinterpret_cast<const bf16x8*>(qkvh + qrow + 32*ks + 8*g);
                ql[ks] = *reinterpret_cast<const bf16x8*>(qkvl + qrow + 32*ks + 8*g);
            }
        }

        const size_t ksrc0 = (rowbase + srow) * (size_t)(3*M_) + hoff + M_ + scol;
        const size_t vsrc0 = ((size_t)((b*H_ + h)*64 + srow)) * T_ + scol;

        bf16x8 stg[8];
        __syncthreads();   // previous item's LDS readers done
        // prologue: stage tile 0
        {
            const size_t kb = ksrc0, vb = vsrc0;
            const size_t kstep = (size_t)32 * (3*M_);
            stg[0] = *reinterpret_cast<const bf16x8*>(qkvh + kb);
            stg[1] = *reinterpret_cast<const bf16x8*>(qkvh + kb + kstep);
            stg[2] = *reinterpret_cast<const bf16x8*>(qkvl + kb);
            stg[3] = *reinterpret_cast<const bf16x8*>(qkvl + kb + kstep);
            stg[4] = *reinterpret_cast<const bf16x8*>(vth + vb);
            stg[5] = *reinterpret_cast<const bf16x8*>(vth + vb + 32*T_);
            stg[6] = *reinterpret_cast<const bf16x8*>(vtl + vb);
            stg[7] = *reinterpret_cast<const bf16x8*>(vtl + vb + 32*T_);
            *reinterpret_cast<bf16x8*>(&Khi[d0])        = stg[0];
            *reinterpret_cast<bf16x8*>(&Khi[d0 + 2048]) = stg[1];
            *reinterpret_cast<bf16x8*>(&Klo[d0])        = stg[2];
            *reinterpret_cast<bf16x8*>(&Klo[d0 + 2048]) = stg[3];
            *reinterpret_cast<bf16x8*>(&Vhi[d0])        = stg[4];
            *reinterpret_cast<bf16x8*>(&Vhi[d0 + 2048]) = stg[5];
            *reinterpret_cast<bf16x8*>(&Vlo[d0])        = stg[6];
            *reinterpret_cast<bf16x8*>(&Vlo[d0 + 2048]) = stg[7];
        }
        __syncthreads();

        f32x4 oa[4] = {};
        float mrow[4] = {-__builtin_inff(), -__builtin_inff(), -__builtin_inff(), -__builtin_inff()};
        float lrow[4] = {};

        for (int kt = 0; kt <= qt; ++kt) {
            // ---- issue next tile's staging loads FIRST (max latency hiding) ----
            if (kt < qt) {
                const size_t kb = ksrc0 + (size_t)((kt+1)*64) * (3*M_);
                const size_t vb = vsrc0 + (size_t)((kt+1)*64);
                const size_t kstep = (size_t)32 * (3*M_);
                stg[0] = *reinterpret_cast<const bf16x8*>(qkvh + kb);
                stg[1] = *reinterpret_cast<const bf16x8*>(qkvh + kb + kstep);
                stg[2] = *reinterpret_cast<const bf16x8*>(qkvl + kb);
                stg[3] = *reinterpret_cast<const bf16x8*>(qkvl + kb + kstep);
                stg[4] = *reinterpret_cast<const bf16x8*>(vth + vb);
                stg[5] = *reinterpret_cast<const bf16x8*>(vth + vb + 32*T_);
                stg[6] = *reinterpret_cast<const bf16x8*>(vtl + vb);
                stg[7] = *reinterpret_cast<const bf16x8*>(vtl + vb + 32*T_);
            }

            // ---- QK^T: S[16 q][64 kv], bf16x3, K frags from LDS ----
            f32x4 sa[4] = {};
            #pragma unroll
            for (int ks = 0; ks < 2; ++ks) {
                bf16x8 kh[4], kl[4];
                #pragma unroll
                for (int nf = 0; nf < 4; ++nf) {
                    const int row = 16*nf + r;
                    const unsigned boff = (unsigned)(row * 128)
                        + (((unsigned)(ks*64 + g*16)) ^ ((unsigned)((row & 7) << 4)));
                    kh[nf] = *reinterpret_cast<const bf16x8*>((const char*)Khi + boff);
                    kl[nf] = *reinterpret_cast<const bf16x8*>((const char*)Klo + boff);
                }
                #pragma unroll
                for (int nf = 0; nf < 4; ++nf) {
                    sa[nf] = __builtin_amdgcn_mfma_f32_16x16x32_bf16(qh[ks], kh[nf], sa[nf], 0, 0, 0);
                    sa[nf] = __builtin_amdgcn_mfma_f32_16x16x32_bf16(ql[ks], kh[nf], sa[nf], 0, 0, 0);
                    sa[nf] = __builtin_amdgcn_mfma_f32_16x16x32_bf16(qh[ks], kl[nf], sa[nf], 0, 0, 0);
                }
            }

            // ---- scale + causal mask ----
            float sv[4][4];
            #pragma unroll
            for (int nf = 0; nf < 4; ++nf)
                #pragma unroll
                for (int i = 0; i < 4; ++i)
                    sv[nf][i] = sa[nf][i] * 0.125f;
            if (kt == qt) {
                #pragma unroll
                for (int nf = 0; nf < 4; ++nf) {
                    const int kvg = kt*64 + 16*nf + r;
                    #pragma unroll
                    for (int i = 0; i < 4; ++i) {
                        const int qg = q0 + 16*w + 4*g + i;
                        if (kvg > qg) sv[nf][i] = -3.0e38f;
                    }
                }
            }

            // ---- online softmax (native exp; bit-identical defer-max path) ----
            float tmax[4];
            #pragma unroll
            for (int i = 0; i < 4; ++i)
                tmax[i] = fmaxf(fmaxf(sv[0][i], sv[1][i]), fmaxf(sv[2][i], sv[3][i]));
            #pragma unroll
            for (int off = 1; off < 16; off <<= 1)
                #pragma unroll
                for (int i = 0; i < 4; ++i)
                    tmax[i] = fmaxf(tmax[i], __shfl_xor(tmax[i], off));
            float mnew[4];
            bool grow = false;
            #pragma unroll
            for (int i = 0; i < 4; ++i) {
                mnew[i] = fmaxf(mrow[i], tmax[i]);
                grow |= (tmax[i] > mrow[i]);
            }
            const bool need = __any(grow);         // wave-uniform
            float p[4][4];
            float rsum[4] = {};
            #pragma unroll
            for (int nf = 0; nf < 4; ++nf)
                #pragma unroll
                for (int i = 0; i < 4; ++i) {
                    p[nf][i] = __expf(sv[nf][i] - mnew[i]);
                    rsum[i] += p[nf][i];
                }
            #pragma unroll
            for (int off = 1; off < 16; off <<= 1)
                #pragma unroll
                for (int i = 0; i < 4; ++i)
                    rsum[i] += __shfl_xor(rsum[i], off);
            if (need) {                            // corr != 1 somewhere
                float corr[4];
                #pragma unroll
                for (int i = 0; i < 4; ++i) corr[i] = __expf(mrow[i] - mnew[i]);
                #pragma unroll
                for (int i = 0; i < 4; ++i) {
                    lrow[i] = lrow[i] * corr[i] + rsum[i];
                    mrow[i] = mnew[i];
                }
                #pragma unroll
                for (int df = 0; df < 4; ++df)
                    #pragma unroll
                    for (int i = 0; i < 4; ++i)
                        oa[df][i] *= corr[i];
            } else {                               // corr == 1 exactly
                #pragma unroll
                for (int i = 0; i < 4; ++i) lrow[i] += rsum[i];
            }

            __syncthreads();   // all waves done reading K -> safe to alias P

            // ---- write P into K region (per-wave [16][64], XOR-swizzled) ----
            #pragma unroll
            for (int nf = 0; nf < 4; ++nf) {
                #pragma unroll
                for (int i = 0; i < 4; ++i) {
                    const int qq = 4*g + i;
                    const int kv = (16*nf + r) ^ ((qq & 7) << 3);
                    const ushort_t phb = f2bf(p[nf][i]);
                    Pwh[qq * 64 + kv] = phb;
                    Pwl[qq * 64 + kv] = f2bf(p[nf][i] - bf2f(phb));
                }
            }
            lgkm0();   // P writes visible to this wave's reads (per-wave slice)

            // ---- PV: O += P·V, bf16x3 ----
            #pragma unroll
            for (int ks = 0; ks < 2; ++ks) {
                const unsigned poff = (unsigned)(r * 64 + ((32*ks + 8*g) ^ ((r & 7) << 3)));
                const bf16x8 ph = *reinterpret_cast<const bf16x8*>(&Pwh[poff]);
                const bf16x8 pl = *reinterpret_cast<const bf16x8*>(&Pwl[poff]);
                #pragma unroll
                for (int df = 0; df < 4; ++df) {
                    const int vrow = 16*df + r;
                    const unsigned voff = (unsigned)(vrow * 128)
                        + (((unsigned)(ks*64 + g*16)) ^ ((unsigned)((vrow & 7) << 4)));
                    const bf16x8 vhf = *reinterpret_cast<const bf16x8*>((const char*)Vhi + voff);
                    const bf16x8 vlf = *reinterpret_cast<const bf16x8*>((const char*)Vlo + voff);
                    oa[df] = __builtin_amdgcn_mfma_f32_16x16x32_bf16(ph, vhf, oa[df], 0, 0, 0);
                    oa[df] = __builtin_amdgcn_mfma_f32_16x16x32_bf16(pl, vhf, oa[df], 0, 0, 0);
                    oa[df] = __builtin_amdgcn_mfma_f32_16x16x32_bf16(ph, vlf, oa[df], 0, 0, 0);
                }
            }

            // ---- commit staged registers to LDS for next tile ----
            if (kt < qt) {
                __syncthreads();                   // V readers done; P dead
                *reinterpret_cast<bf16x8*>(&Khi[d0])        = stg[0];
                *reinterpret_cast<bf16x8*>(&Khi[d0 + 2048]) = stg[1];
                *reinterpret_cast<bf16x8*>(&Klo[d0])        = stg[2];
                *reinterpret_cast<bf16x8*>(&Klo[d0 + 2048]) = stg[3];
                *reinterpret_cast<bf16x8*>(&Vhi[d0])        = stg[4];
                *reinterpret_cast<bf16x8*>(&Vhi[d0 + 2048]) = stg[5];
                *reinterpret_cast<bf16x8*>(&Vlo[d0])        = stg[6];
                *reinterpret_cast<bf16x8*>(&Vlo[d0 + 2048]) = stg[7];
                __syncthreads();                   // writes visible
            }
        }

        // ---- epilogue: hi/lo split of O / l ----
        #pragma unroll
        for (int i = 0; i < 4; ++i) {
            const float inv = 1.0f / lrow[i];
            const size_t row = (rowbase + q0 + 16*w + 4*g + i) * (size_t)M_ + hoff;
            #pragma unroll
            for (int df = 0; df < 4; ++df) {
                const float v = oa[df][i] * inv;
                const ushort_t hb = f2bf(v);
                ohi[row + 16*df + r] = hb;
                olo[row + 16*df + r] = f2bf(v - bf2f(hb));
            }
        }
    }
}

// ---------------------------------------------------------------------------
// Deepspeed dispatch bookkeeping (exact, f32).
// ---------------------------------------------------------------------------
__global__ __launch_bounds__(1024) void scan_kernel(const int* __restrict__ gidx,
                                                    const float* __restrict__ gtop,
                                                    float* __restrict__ gate_val,
                                                    int* __restrict__ token_at)
{
    __shared__ int hist[1024][E_];
    const int tid = threadIdx.x;
    for (int i = tid; i < E_ * C_; i += 1024) token_at[i] = -1;
    int my[8];
    #pragma unroll
    for (int t = 0; t < 8; ++t) my[t] = gidx[tid * 8 + t];
    #pragma unroll
    for (int e = 0; e < E_; ++e) {
        int c = 0;
        #pragma unroll
        for (int t = 0; t < 8; ++t) c += (my[t] == e) ? 1 : 0;
        hist[tid][e] = c;
    }
    __syncthreads();
    if (tid < E_) {
        int run = 0;
        for (int t = 0; t < 1024; ++t) {
            const int v = hist[t][tid];
            hist[t][tid] = run;
            run += v;
        }
    }
    __syncthreads();
    #pragma unroll
    for (int t = 0; t < 8; ++t) {
        const int s = tid * 8 + t;
        const int e = my[t];
        const int p = hist[tid][e];
        hist[tid][e] = p + 1;
        const bool keep = (p < C_);
        gate_val[s] = keep ? gtop[s] : 0.0f;
        if (keep) token_at[e * C_ + p] = s;
    }
}

__global__ __launch_bounds__(256) void dispatch_bf16_kernel(const float* __restrict__ h2,
                                                            const int* __restrict__ token_at,
                                                            ushort_t* __restrict__ disp)
{
    const int ec = blockIdx.x;
    const int s = token_at[ec];
    ushort4* dst = reinterpret_cast<ushort4*>(disp + (size_t)ec * M_);
    if (s >= 0) {
        const float4 v = reinterpret_cast<const float4*>(h2 + (size_t)s * M_)[threadIdx.x];
        dst[threadIdx.x] = make_ushort4(f2bf(v.x), f2bf(v.y), f2bf(v.z), f2bf(v.w));
    } else {
        dst[threadIdx.x] = make_ushort4(0, 0, 0, 0);
    }
}

// Transpose+convert: in[e][R][Cc] f32 -> out[e][Cc][R] bf16.
__global__ __launch_bounds__(256) void transpose_bf16_kernel(const float* __restrict__ in,
                                                             ushort_t* __restrict__ outp,
                                                             int R, int Cc)
{
    __shared__ float tile[32][33];
    const int e = blockIdx.z;
    in   += (size_t)e * R * Cc;
    outp += (size_t)e * R * Cc;
    const int tx = threadIdx.x & 31, ty0 = threadIdx.x >> 5;
    const int c0 = blockIdx.x * 32, r0 = blockIdx.y * 32;
    #pragma unroll
    for (int i = 0; i < 4; ++i)
        tile[ty0 + 8*i][tx] = in[(size_t)(r0 + ty0 + 8*i) * Cc + c0 + tx];
    __syncthreads();
    #pragma unroll
    for (int i = 0; i < 4; ++i)
        outp[(size_t)(c0 + ty0 + 8*i) * R + r0 + tx] = f2bf(tile[tx][ty0 + 8*i]);
}

// ---------------------------------------------------------------------------
// bf16 MFMA GEMM (MoE FFN, post-router) — unchanged, verified.
// ---------------------------------------------------------------------------
template<int EPI>
__global__ __launch_bounds__(256) void gemm_mfma(
    const ushort_t* __restrict__ A, const ushort_t* __restrict__ Bt,
    const float* __restrict__ bias,
    const int* __restrict__ token_at, const float* __restrict__ gate_val,
    void* __restrict__ Cout, int N, int K,
    long strA, long strB, long strBias, long strC)
{
    const int e = blockIdx.z;
    A    += (size_t)e * (size_t)strA;
    Bt   += (size_t)e * (size_t)strB;
    bias += (size_t)e * (size_t)strBias;

    __shared__ ushort_t As[128 * 32];
    __shared__ ushort_t Bs[128 * 32];

    const int t  = threadIdx.x;
    const int l  = t & 63;
    const int wv = t >> 6;
    const int wm = (wv & 1) * 64, wn = (wv >> 1) * 64;
    const int fr = l & 15, fk = (l >> 4) * 8;
    const int m0 = blockIdx.y * 128, n0 = blockIdx.x * 128;

    const ushort_t* gA = A + (size_t)(m0 + (t >> 2)) * K + (t & 3) * 8;
    const ushort_t* gB = Bt + (size_t)(n0 + (t >> 2)) * K + (t & 3) * 8;
    ushort_t* lA = As + wv * 512;
    ushort_t* lB = Bs + wv * 512;

    f32x4 acc[4][4] = {};

    for (int k0 = 0; k0 < K; k0 += 32) {
        __syncthreads();
        gload_lds16(gA + k0, lA);
        gload_lds16(gA + k0 + (size_t)64 * K, lA + 2048);
        gload_lds16(gB + k0, lB);
        gload_lds16(gB + k0 + (size_t)64 * K, lB + 2048);
        __syncthreads();
        bf16x8 af[4], bfr[4];
        #pragma unroll
        for (int i = 0; i < 4; ++i)
            af[i] = *reinterpret_cast<const bf16x8*>(&As[(wm + i*16 + fr) * 32 + fk]);
        #pragma unroll
        for (int i = 0; i < 4; ++i)
            bfr[i] = *reinterpret_cast<const bf16x8*>(&Bs[(wn + i*16 + fr) * 32 + fk]);
        #pragma unroll
        for (int mi = 0; mi < 4; ++mi) {
            #pragma unroll
            for (int ni = 0; ni < 4; ++ni)
                acc[mi][ni] = __builtin_amdgcn_mfma_f32_16x16x32_bf16(
                    af[mi], bfr[ni], acc[mi][ni], 0, 0, 0);
        }
    }

    const int l4 = (l >> 4) * 4;
    if (EPI == 0) {
        ushort_t* Cc = (ushort_t*)Cout + (size_t)e * (size_t)strC;
        #pragma unroll
        for (int ni = 0; ni < 4; ++ni) {
            const int cl = n0 + wn + ni*16 + fr;
            const float bb = bias[cl];
            #pragma unroll
            for (int mi = 0; mi < 4; ++mi) {
                #pragma unroll
                for (int i = 0; i < 4; ++i) {
                    const int rr = m0 + wm + mi*16 + l4 + i;
                    Cc[(size_t)rr * N + cl] = f2bf(gelu_exact(acc[mi][ni][i] + bb));
                }
            }
        }
    } else {
        float* Co = (float*)Cout;
        const int* ta = token_at + e * C_;
        #pragma unroll
        for (int mi = 0; mi < 4; ++mi) {
            #pragma unroll
            for (int i = 0; i < 4; ++i) {
                const int rr = m0 + wm + mi*16 + l4 + i;
                const int s = ta[rr];
                if (s >= 0) {
                    const float gvl = gate_val[s];
                    #pragma unroll
                    for (int ni = 0; ni < 4; ++ni) {
                        const int cl = n0 + wn + ni*16 + fr;
                        Co[(size_t)s * N + cl] += gvl * (acc[mi][ni][i] + bias[cl]);
                    }
                }
            }
        }
    }
}

// ---------------------------------------------------------------------------
extern "C" void kernel_launch(void* const* d_in, const int* in_sizes, int n_in,
                              void* d_out, int out_size, void* d_ws, size_t ws_size,
                              hipStream_t stream)
{
    const float* x    = (const float*)d_in[0];
    const float* ln1g = (const float*)d_in[1];
    const float* ln1b = (const float*)d_in[2];
    const float* Wqkv = (const float*)d_in[3];
    const float* bqkv = (const float*)d_in[4];
    const float* Wout = (const float*)d_in[5];
    const float* bout = (const float*)d_in[6];
    const float* ln2g = (const float*)d_in[7];
    const float* ln2b = (const float*)d_in[8];
    const float* wg   = (const float*)d_in[9];
    const float* w1   = (const float*)d_in[10];
    const float* b1   = (const float*)d_in[11];
    const float* w2   = (const float*)d_in[12];
    const float* b2   = (const float*)d_in[13];
    float* out = (float*)d_out;

    // Workspace (MiB offsets), lifetime-scheduled. Peak ~196 MiB.
    char* ws = (char*)d_ws;
    ushort_t* ahi   = (ushort_t*)ws;
    ushort_t* alo   = (ushort_t*)(ws + ((size_t)16  << 20));
    float*    buf_h = (float*)ws;
    ushort_t* qkvh  = (ushort_t*)(ws + ((size_t)32  << 20));
    ushort_t* qkvl  = (ushort_t*)(ws + ((size_t)80  << 20));
    ushort_t* vth   = (ushort_t*)(ws + ((size_t)128 << 20));
    ushort_t* vtl   = (ushort_t*)(ws + ((size_t)144 << 20));
    ushort_t* ohi   = (ushort_t*)(ws + ((size_t)160 << 20));
    ushort_t* olo   = (ushort_t*)(ws + ((size_t)176 << 20));
    ushort_t* wqh   = (ushort_t*)(ws + ((size_t)128 << 20));   // ph1 only
    ushort_t* wql   = (ushort_t*)(ws + ((size_t)134 << 20));   // ph1 only
    ushort_t* woh   = (ushort_t*)(ws + ((size_t)192 << 20));
    ushort_t* wol   = (ushort_t*)(ws + ((size_t)194 << 20));
    ushort_t* w1t   = (ushort_t*)(ws + ((size_t)32  << 20));
    ushort_t* w2t   = (ushort_t*)(ws + ((size_t)32  << 20));
    ushort_t* dispb = (ushort_t*)(ws + ((size_t)96  << 20));
    ushort_t* h1b   = (ushort_t*)(ws + ((size_t)112 << 20));
    float*    buf_gtop = (float*)(ws + ((size_t)196 << 20));
    float*    buf_gv   = buf_gtop + S_;
    int*      buf_idx  = (int*)(buf_gv + S_);
    int*      buf_ta   = buf_idx + S_;

    // --- pre-router path (f32-grade via bf16x3 MFMA) ---
    split_kernel<<<(3*M_*M_/4 + 255)/256, 256, 0, stream>>>(Wqkv, wqh, wql, 3*M_*M_/4);
    split_kernel<<<(M_*M_/4 + 255)/256, 256, 0, stream>>>(Wout, woh, wol, M_*M_/4);
    ln_split_kernel<<<S_, 256, 0, stream>>>(x, ln1g, ln1b, ahi, alo);
    gemm_bf16x3<2><<<dim3(3*M_/128, S_/128, 1), 256, 0, stream>>>(
        ahi, alo, wqh, wql, bqkv, nullptr, qkvh, qkvl, 3*M_, M_);
    vtrans_kernel<<<dim3(T_/64, H_, B_), 256, 0, stream>>>(qkvh, qkvl, vth, vtl);
    attn_mfma_kernel<<<dim3(1024, 1, 1), 256, 0, stream>>>(qkvh, qkvl, vth, vtl, ohi, olo);
    gemm_bf16x3<1><<<dim3(M_/128, S_/128, 1), 256, 0, stream>>>(
        ohi, olo, woh, wol, bout, x, out, nullptr, M_, M_);

    // --- router (exact f32; fused LN2 + gate) ---
    ln_gate_kernel<<<S_, 256, 0, stream>>>(out, ln2g, ln2b, wg, buf_h, buf_idx, buf_gtop);
    scan_kernel<<<1, 1024, 0, stream>>>(buf_idx, buf_gtop, buf_gv, buf_ta);
    dispatch_bf16_kernel<<<E_*C_, 256, 0, stream>>>(buf_h, buf_ta, dispb);

    // --- MoE FFN (bf16 MFMA, post-router) ---
    transpose_bf16_kernel<<<dim3(F_/32, M_/32, E_), 256, 0, stream>>>(w1, w1t, M_, F_);
    gemm_mfma<0><<<dim3(F_/128, C_/128, E_), 256, 0, stream>>>(
        dispb, w1t, b1, nullptr, nullptr, h1b, F_, M_,
        (long)C_*M_, (long)F_*M_, (long)F_, (long)C_*F_);
    transpose_bf16_kernel<<<dim3(M_/32, F_/32, E_), 256, 0, stream>>>(w2, w2t, F_, M_);
    gemm_mfma<1><<<dim3(M_/128, C_/128, E_), 256, 0, stream>>>(
        h1b, w2t, b2, buf_ta, buf_gv, out, M_, F_,
        (long)C_*F_, (long)M_*F_, (long)M_, 0);
}

// Round 15
// 896.637 us; speedup vs baseline: 1.2849x; 1.0132x over previous
//
#include <hip/hip_runtime.h>
#include <hip/hip_bf16.h>
#include <math.h>

#define B_ 4
#define T_ 2048
#define M_ 1024
#define H_ 16
#define E_ 8
#define S_ (B_*T_)      // 8192
#define C_ (S_/E_)      // 1024
#define D_ (M_/H_)      // 64
#define F_ (4*M_)       // 4096

typedef unsigned short ushort_t;
typedef __attribute__((ext_vector_type(8))) short bf16x8;
typedef __attribute__((ext_vector_type(4))) float f32x4;

__device__ __forceinline__ float gelu_exact(float x) {
    return 0.5f * x * (1.0f + erff(x * 0.70710678118654752440f));
}

__device__ __forceinline__ unsigned short f2bf(float f) {
    unsigned int u = __float_as_uint(f);
    u = (u + 0x7FFFu + ((u >> 16) & 1u)) >> 16;   // RNE
    return (unsigned short)u;
}

__device__ __forceinline__ float bf2f(unsigned short h) {
    return __uint_as_float(((unsigned)h) << 16);
}

__device__ __forceinline__ void gload_lds16(const void* g, void* l) {
    __builtin_amdgcn_global_load_lds(
        (const __attribute__((address_space(1))) unsigned int*)g,
        (__attribute__((address_space(3))) unsigned int*)l,
        16, 0, 0);
}

__device__ __forceinline__ void lgkm0() {
    asm volatile("s_waitcnt lgkmcnt(0)" ::: "memory");
}

// ---------------------------------------------------------------------------
// LayerNorm fused with hi/lo bf16 split output (LN1).
// ---------------------------------------------------------------------------
__global__ __launch_bounds__(256) void ln_split_kernel(const float* __restrict__ x,
                                                       const float* __restrict__ g,
                                                       const float* __restrict__ bta,
                                                       ushort_t* __restrict__ hi,
                                                       ushort_t* __restrict__ lo)
{
    const int row = blockIdx.x;
    const int tid = threadIdx.x;
    const float4 v = reinterpret_cast<const float4*>(x + (size_t)row * M_)[tid];
    float s = v.x + v.y + v.z + v.w;
    __shared__ float red[4];
    #pragma unroll
    for (int off = 32; off > 0; off >>= 1) s += __shfl_down(s, off);
    if ((tid & 63) == 0) red[tid >> 6] = s;
    __syncthreads();
    const float mu = (red[0] + red[1] + red[2] + red[3]) * (1.0f / (float)M_);
    __syncthreads();
    float4 d;
    d.x = v.x - mu; d.y = v.y - mu; d.z = v.z - mu; d.w = v.w - mu;
    float q = d.x*d.x + d.y*d.y + d.z*d.z + d.w*d.w;
    #pragma unroll
    for (int off = 32; off > 0; off >>= 1) q += __shfl_down(q, off);
    if ((tid & 63) == 0) red[tid >> 6] = q;
    __syncthreads();
    const float var  = (red[0] + red[1] + red[2] + red[3]) * (1.0f / (float)M_);
    const float rstd = 1.0f / sqrtf(var + 1e-5f);
    const float4 gv = reinterpret_cast<const float4*>(g)[tid];
    const float4 bv = reinterpret_cast<const float4*>(bta)[tid];
    float o[4];
    o[0] = d.x * rstd * gv.x + bv.x;
    o[1] = d.y * rstd * gv.y + bv.y;
    o[2] = d.z * rstd * gv.z + bv.z;
    o[3] = d.w * rstd * gv.w + bv.w;
    ushort4 hh, ll;
    hh.x = f2bf(o[0]); ll.x = f2bf(o[0] - bf2f(hh.x));
    hh.y = f2bf(o[1]); ll.y = f2bf(o[1] - bf2f(hh.y));
    hh.z = f2bf(o[2]); ll.z = f2bf(o[2] - bf2f(hh.z));
    hh.w = f2bf(o[3]); ll.w = f2bf(o[3] - bf2f(hh.w));
    reinterpret_cast<ushort4*>(hi + (size_t)row * M_)[tid] = hh;
    reinterpret_cast<ushort4*>(lo + (size_t)row * M_)[tid] = ll;
}

// ---------------------------------------------------------------------------
// Fused LN2 + router gate (verified round 14).
// ---------------------------------------------------------------------------
__global__ __launch_bounds__(256) void ln_gate_kernel(const float* __restrict__ x,
                                                      const float* __restrict__ g,
                                                      const float* __restrict__ bta,
                                                      const float* __restrict__ wg,
                                                      float* __restrict__ h2,
                                                      int* __restrict__ gidx,
                                                      float* __restrict__ gtop)
{
    const int row = blockIdx.x;
    const int tid = threadIdx.x;
    const int wv = tid >> 6, ln = tid & 63;
    const float4 v = reinterpret_cast<const float4*>(x + (size_t)row * M_)[tid];
    float s = v.x + v.y + v.z + v.w;
    __shared__ float red[4];
    __shared__ float red2[4][E_];
    #pragma unroll
    for (int off = 32; off > 0; off >>= 1) s += __shfl_down(s, off);
    if (ln == 0) red[wv] = s;
    __syncthreads();
    const float mu = (red[0] + red[1] + red[2] + red[3]) * (1.0f / (float)M_);
    __syncthreads();
    float4 d;
    d.x = v.x - mu; d.y = v.y - mu; d.z = v.z - mu; d.w = v.w - mu;
    float q = d.x*d.x + d.y*d.y + d.z*d.z + d.w*d.w;
    #pragma unroll
    for (int off = 32; off > 0; off >>= 1) q += __shfl_down(q, off);
    if (ln == 0) red[wv] = q;
    __syncthreads();
    const float var  = (red[0] + red[1] + red[2] + red[3]) * (1.0f / (float)M_);
    const float rstd = 1.0f / sqrtf(var + 1e-5f);
    const float4 gv = reinterpret_cast<const float4*>(g)[tid];
    const float4 bv = reinterpret_cast<const float4*>(bta)[tid];
    float o[4];
    o[0] = d.x * rstd * gv.x + bv.x;
    o[1] = d.y * rstd * gv.y + bv.y;
    o[2] = d.z * rstd * gv.z + bv.z;
    o[3] = d.w * rstd * gv.w + bv.w;
    reinterpret_cast<float4*>(h2 + (size_t)row * M_)[tid] = make_float4(o[0], o[1], o[2], o[3]);

    // logits: thread covers cols 4*tid..4*tid+3; wg is [M][E] row-major.
    float part[E_] = {};
    #pragma unroll
    for (int j = 0; j < 4; ++j) {
        const float4 w0 = reinterpret_cast<const float4*>(wg)[(4*tid + j) * 2];
        const float4 w1 = reinterpret_cast<const float4*>(wg)[(4*tid + j) * 2 + 1];
        part[0] = fmaf(o[j], w0.x, part[0]); part[1] = fmaf(o[j], w0.y, part[1]);
        part[2] = fmaf(o[j], w0.z, part[2]); part[3] = fmaf(o[j], w0.w, part[3]);
        part[4] = fmaf(o[j], w1.x, part[4]); part[5] = fmaf(o[j], w1.y, part[5]);
        part[6] = fmaf(o[j], w1.z, part[6]); part[7] = fmaf(o[j], w1.w, part[7]);
    }
    #pragma unroll
    for (int off = 32; off > 0; off >>= 1)
        #pragma unroll
        for (int e = 0; e < E_; ++e) part[e] += __shfl_down(part[e], off);
    if (ln == 0)
        #pragma unroll
        for (int e = 0; e < E_; ++e) red2[wv][e] = part[e];
    __syncthreads();
    if (tid == 0) {
        float lg[E_];
        #pragma unroll
        for (int e = 0; e < E_; ++e)
            lg[e] = red2[0][e] + red2[1][e] + red2[2][e] + red2[3][e];
        float mx = lg[0]; int bi = 0;
        #pragma unroll
        for (int i = 1; i < E_; ++i) { if (lg[i] > mx) { mx = lg[i]; bi = i; } }
        float den = 0.0f;
        #pragma unroll
        for (int i = 0; i < E_; ++i) den += expf(lg[i] - mx);
        gidx[row] = bi;
        gtop[row] = 1.0f / den;
    }
}

// Elementwise f32 -> hi/lo bf16 split (weights).
__global__ __launch_bounds__(256) void split_kernel(const float* __restrict__ in,
                                                    ushort_t* __restrict__ hi,
                                                    ushort_t* __restrict__ lo,
                                                    int n4)
{
    const int i = blockIdx.x * 256 + threadIdx.x;
    if (i >= n4) return;
    const float4 v = reinterpret_cast<const float4*>(in)[i];
    ushort4 hh, ll;
    hh.x = f2bf(v.x); ll.x = f2bf(v.x - bf2f(hh.x));
    hh.y = f2bf(v.y); ll.y = f2bf(v.y - bf2f(hh.y));
    hh.z = f2bf(v.z); ll.z = f2bf(v.z - bf2f(hh.z));
    hh.w = f2bf(v.w); ll.w = f2bf(v.w - bf2f(hh.w));
    reinterpret_cast<ushort4*>(hi)[i] = hh;
    reinterpret_cast<ushort4*>(lo)[i] = ll;
}

// V^T pre-transpose: qkv hi/lo [s][3M] (V slice) -> vt hi/lo [(b*H+h)*64+d][T].
__global__ __launch_bounds__(256) void vtrans_kernel(const ushort_t* __restrict__ qkvh,
                                                     const ushort_t* __restrict__ qkvl,
                                                     ushort_t* __restrict__ vth,
                                                     ushort_t* __restrict__ vtl)
{
    __shared__ ushort_t tile[64][72];
    const int t0 = blockIdx.x * 64, h = blockIdx.y, b = blockIdx.z;
    const int tid = threadIdx.x;
    const int tr = tid & 63, dc = (tid >> 6) * 16;
    const size_t src = ((size_t)(b*T_ + t0 + tr)) * (3*M_) + 2*M_ + h*64 + dc;
    const int dr = tid & 63, tc = (tid >> 6) * 16;
    const size_t dst = ((size_t)((b*H_ + h)*64 + dr)) * T_ + t0 + tc;

    #pragma unroll
    for (int pass = 0; pass < 2; ++pass) {
        const ushort_t* in = pass ? qkvl : qkvh;
        ushort_t* outp     = pass ? vtl  : vth;
        *reinterpret_cast<bf16x8*>(&tile[tr][dc])     = *reinterpret_cast<const bf16x8*>(in + src);
        *reinterpret_cast<bf16x8*>(&tile[tr][dc + 8]) = *reinterpret_cast<const bf16x8*>(in + src + 8);
        __syncthreads();
        bf16x8 o0, o1;
        #pragma unroll
        for (int j = 0; j < 8; ++j) {
            o0[j] = (short)tile[tc + j][dr];
            o1[j] = (short)tile[tc + 8 + j][dr];
        }
        *reinterpret_cast<bf16x8*>(outp + dst)     = o0;
        *reinterpret_cast<bf16x8*>(outp + dst + 8) = o1;
        __syncthreads();
    }
}

// ---------------------------------------------------------------------------
// bf16x3 MFMA GEMM (f32-grade, pre-router). m97 structure, 4 LDS buffers.
// EPI 1: f32 out = acc + bias + res.   EPI 2: hi/lo bf16 out = split(acc+bias).
// ---------------------------------------------------------------------------
template<int EPI>
__global__ __launch_bounds__(256) void gemm_bf16x3(
    const ushort_t* __restrict__ Ahi, const ushort_t* __restrict__ Alo,
    const ushort_t* __restrict__ Bhi, const ushort_t* __restrict__ Blo,
    const float* __restrict__ bias, const float* __restrict__ res,
    void* __restrict__ C0, ushort_t* __restrict__ C1, int N, int K)
{
    __shared__ ushort_t AsH[128*32], AsL[128*32];
    __shared__ ushort_t BsH[128*32], BsL[128*32];

    const int t  = threadIdx.x;
    const int l  = t & 63;
    const int wv = t >> 6;
    const int wm = (wv & 1) * 64, wn = (wv >> 1) * 64;
    const int fr = l & 15, fk = (l >> 4) * 8;
    const int m0 = blockIdx.y * 128, n0 = blockIdx.x * 128;

    const size_t arow = (size_t)(m0 + (t >> 2)) * K + (t & 3) * 8;
    const size_t brow = (size_t)(n0 + (t >> 2)) * K + (t & 3) * 8;
    ushort_t* lAH = AsH + wv * 512;
    ushort_t* lAL = AsL + wv * 512;
    ushort_t* lBH = BsH + wv * 512;
    ushort_t* lBL = BsL + wv * 512;

    f32x4 acc[4][4] = {};

    for (int k0 = 0; k0 < K; k0 += 32) {
        __syncthreads();
        gload_lds16(Ahi + arow + k0, lAH);
        gload_lds16(Ahi + arow + k0 + (size_t)64 * K, lAH + 2048);
        gload_lds16(Alo + arow + k0, lAL);
        gload_lds16(Alo + arow + k0 + (size_t)64 * K, lAL + 2048);
        gload_lds16(Bhi + brow + k0, lBH);
        gload_lds16(Bhi + brow + k0 + (size_t)64 * K, lBH + 2048);
        gload_lds16(Blo + brow + k0, lBL);
        gload_lds16(Blo + brow + k0 + (size_t)64 * K, lBL + 2048);
        __syncthreads();
        bf16x8 ah[4], al[4], bh[4], bl[4];
        #pragma unroll
        for (int i = 0; i < 4; ++i) {
            ah[i] = *reinterpret_cast<const bf16x8*>(&AsH[(wm + i*16 + fr) * 32 + fk]);
            al[i] = *reinterpret_cast<const bf16x8*>(&AsL[(wm + i*16 + fr) * 32 + fk]);
            bh[i] = *reinterpret_cast<const bf16x8*>(&BsH[(wn + i*16 + fr) * 32 + fk]);
            bl[i] = *reinterpret_cast<const bf16x8*>(&BsL[(wn + i*16 + fr) * 32 + fk]);
        }
        #pragma unroll
        for (int mi = 0; mi < 4; ++mi) {
            #pragma unroll
            for (int ni = 0; ni < 4; ++ni) {
                acc[mi][ni] = __builtin_amdgcn_mfma_f32_16x16x32_bf16(ah[mi], bh[ni], acc[mi][ni], 0, 0, 0);
                acc[mi][ni] = __builtin_amdgcn_mfma_f32_16x16x32_bf16(al[mi], bh[ni], acc[mi][ni], 0, 0, 0);
                acc[mi][ni] = __builtin_amdgcn_mfma_f32_16x16x32_bf16(ah[mi], bl[ni], acc[mi][ni], 0, 0, 0);
            }
        }
    }

    // C/D: col = lane&15, row = (lane>>4)*4 + reg
    const int l4 = (l >> 4) * 4;
    #pragma unroll
    for (int mi = 0; mi < 4; ++mi) {
        #pragma unroll
        for (int i = 0; i < 4; ++i) {
            const int row = m0 + wm + mi*16 + l4 + i;
            #pragma unroll
            for (int ni = 0; ni < 4; ++ni) {
                const int col = n0 + wn + ni*16 + fr;
                float v = acc[mi][ni][i] + bias[col];
                if (EPI == 1) {
                    v += res[(size_t)row * N + col];
                    ((float*)C0)[(size_t)row * N + col] = v;
                } else {
                    const ushort_t hb = f2bf(v);
                    ((ushort_t*)C0)[(size_t)row * N + col] = hb;
                    C1[(size_t)row * N + col] = f2bf(v - bf2f(hb));
                }
            }
        }
    }
}

// ---------------------------------------------------------------------------
// bf16x3 MFMA flash attention — PERSISTENT, 1024 blocks, 2 snake-paired items
// each. LDS diet (P aliases K, 32 KB, zero bank conflicts), natural VGPR
// allocation. EXACT round-13 body (verified 223 us) — round-14's staging
// hoist and defer-max branch reverted (measured net regression).
// ---------------------------------------------------------------------------
__global__ __launch_bounds__(256) void attn_mfma_kernel(
    const ushort_t* __restrict__ qkvh, const ushort_t* __restrict__ qkvl,
    const ushort_t* __restrict__ vth,  const ushort_t* __restrict__ vtl,
    ushort_t* __restrict__ ohi, ushort_t* __restrict__ olo)
{
    const int j = (int)blockIdx.x;                 // 0..1023
    const int t = threadIdx.x;
    const int w = t >> 6, l = t & 63;
    const int r = l & 15, g = l >> 4;

    __shared__ ushort_t Khi[64*64], Klo[64*64];    // [kv][64] swizzled; P alias
    __shared__ ushort_t Vhi[64*64], Vlo[64*64];    // V^T [d][64 kv] swizzled

    ushort_t* Pwh = Khi + w * 1024;                // per-wave P [16 q][64 kv]
    ushort_t* Pwl = Klo + w * 1024;

    const int items[2] = { j, 2047 - j };

    // staging lane geometry (item-independent)
    const int srow = w*8 + (l >> 3);
    const int scol = ((l & 7) ^ (l >> 3)) * 8;
    const int d0 = w * 512 + l * 8;                // ushort index; +2048 = rows+32

    for (int ii = 0; ii < 2; ++ii) {
        const int item = items[ii];
        const int qt  = 31 - (item >> 6);          // rank -> qt (descending)
        const int rem = item & 63;
        const int h = rem >> 2, b = rem & 3;
        const int q0 = qt * 64;
        const size_t rowbase = (size_t)b * T_;
        const int hoff = h * D_;

        // Q fragments (A-frag: row = l&15, k = 32ks + 8g + j)
        bf16x8 qh[2], ql[2];
        {
            const size_t qrow = (rowbase + q0 + 16*w + r) * (size_t)(3*M_) + hoff;
            #pragma unroll
            for (int ks = 0; ks < 2; ++ks) {
                qh[ks] = *reinterpret_cast<const bf16x8*>(qkvh + qrow + 32*ks + 8*g);
                ql[ks] = *reinterpret_cast<const bf16x8*>(qkvl + qrow + 32*ks + 8*g);
            }
        }

        const size_t ksrc0 = (rowbase + srow) * (size_t)(3*M_) + hoff + M_ + scol;
        const size_t vsrc0 = ((size_t)((b*H_ + h)*64 + srow)) * T_ + scol;

        bf16x8 stg[8];
        __syncthreads();   // previous item's LDS readers done
        // prologue: stage tile 0
        {
            const size_t kb = ksrc0, vb = vsrc0;
            const size_t kstep = (size_t)32 * (3*M_);
            stg[0] = *reinterpret_cast<const bf16x8*>(qkvh + kb);
            stg[1] = *reinterpret_cast<const bf16x8*>(qkvh + kb + kstep);
            stg[2] = *reinterpret_cast<const bf16x8*>(qkvl + kb);
            stg[3] = *reinterpret_cast<const bf16x8*>(qkvl + kb + kstep);
            stg[4] = *reinterpret_cast<const bf16x8*>(vth + vb);
            stg[5] = *reinterpret_cast<const bf16x8*>(vth + vb + 32*T_);
            stg[6] = *reinterpret_cast<const bf16x8*>(vtl + vb);
            stg[7] = *reinterpret_cast<const bf16x8*>(vtl + vb + 32*T_);
            *reinterpret_cast<bf16x8*>(&Khi[d0])        = stg[0];
            *reinterpret_cast<bf16x8*>(&Khi[d0 + 2048]) = stg[1];
            *reinterpret_cast<bf16x8*>(&Klo[d0])        = stg[2];
            *reinterpret_cast<bf16x8*>(&Klo[d0 + 2048]) = stg[3];
            *reinterpret_cast<bf16x8*>(&Vhi[d0])        = stg[4];
            *reinterpret_cast<bf16x8*>(&Vhi[d0 + 2048]) = stg[5];
            *reinterpret_cast<bf16x8*>(&Vlo[d0])        = stg[6];
            *reinterpret_cast<bf16x8*>(&Vlo[d0 + 2048]) = stg[7];
        }
        __syncthreads();

        f32x4 oa[4] = {};
        float mrow[4] = {-__builtin_inff(), -__builtin_inff(), -__builtin_inff(), -__builtin_inff()};
        float lrow[4] = {};

        for (int kt = 0; kt <= qt; ++kt) {
            // ---- QK^T: S[16 q][64 kv], bf16x3, K frags from LDS ----
            f32x4 sa[4] = {};
            #pragma unroll
            for (int ks = 0; ks < 2; ++ks) {
                bf16x8 kh[4], kl[4];
                #pragma unroll
                for (int nf = 0; nf < 4; ++nf) {
                    const int row = 16*nf + r;
                    const unsigned boff = (unsigned)(row * 128)
                        + (((unsigned)(ks*64 + g*16)) ^ ((unsigned)((row & 7) << 4)));
                    kh[nf] = *reinterpret_cast<const bf16x8*>((const char*)Khi + boff);
                    kl[nf] = *reinterpret_cast<const bf16x8*>((const char*)Klo + boff);
                }
                #pragma unroll
                for (int nf = 0; nf < 4; ++nf) {
                    sa[nf] = __builtin_amdgcn_mfma_f32_16x16x32_bf16(qh[ks], kh[nf], sa[nf], 0, 0, 0);
                    sa[nf] = __builtin_amdgcn_mfma_f32_16x16x32_bf16(ql[ks], kh[nf], sa[nf], 0, 0, 0);
                    sa[nf] = __builtin_amdgcn_mfma_f32_16x16x32_bf16(qh[ks], kl[nf], sa[nf], 0, 0, 0);
                }
            }

            // ---- issue next tile's staging loads into registers (T14) ----
            if (kt < qt) {
                const size_t kb = ksrc0 + (size_t)((kt+1)*64) * (3*M_);
                const size_t vb = vsrc0 + (size_t)((kt+1)*64);
                const size_t kstep = (size_t)32 * (3*M_);
                stg[0] = *reinterpret_cast<const bf16x8*>(qkvh + kb);
                stg[1] = *reinterpret_cast<const bf16x8*>(qkvh + kb + kstep);
                stg[2] = *reinterpret_cast<const bf16x8*>(qkvl + kb);
                stg[3] = *reinterpret_cast<const bf16x8*>(qkvl + kb + kstep);
                stg[4] = *reinterpret_cast<const bf16x8*>(vth + vb);
                stg[5] = *reinterpret_cast<const bf16x8*>(vth + vb + 32*T_);
                stg[6] = *reinterpret_cast<const bf16x8*>(vtl + vb);
                stg[7] = *reinterpret_cast<const bf16x8*>(vtl + vb + 32*T_);
            }

            // ---- scale + causal mask ----
            float sv[4][4];
            #pragma unroll
            for (int nf = 0; nf < 4; ++nf)
                #pragma unroll
                for (int i = 0; i < 4; ++i)
                    sv[nf][i] = sa[nf][i] * 0.125f;
            if (kt == qt) {
                #pragma unroll
                for (int nf = 0; nf < 4; ++nf) {
                    const int kvg = kt*64 + 16*nf + r;
                    #pragma unroll
                    for (int i = 0; i < 4; ++i) {
                        const int qg = q0 + 16*w + 4*g + i;
                        if (kvg > qg) sv[nf][i] = -3.0e38f;
                    }
                }
            }

            // ---- online softmax (native exp) ----
            float tmax[4];
            #pragma unroll
            for (int i = 0; i < 4; ++i)
                tmax[i] = fmaxf(fmaxf(sv[0][i], sv[1][i]), fmaxf(sv[2][i], sv[3][i]));
            #pragma unroll
            for (int off = 1; off < 16; off <<= 1)
                #pragma unroll
                for (int i = 0; i < 4; ++i)
                    tmax[i] = fmaxf(tmax[i], __shfl_xor(tmax[i], off));
            float mnew[4], corr[4];
            #pragma unroll
            for (int i = 0; i < 4; ++i) {
                mnew[i] = fmaxf(mrow[i], tmax[i]);
                corr[i] = __expf(mrow[i] - mnew[i]);
            }
            float p[4][4];
            float rsum[4] = {};
            #pragma unroll
            for (int nf = 0; nf < 4; ++nf)
                #pragma unroll
                for (int i = 0; i < 4; ++i) {
                    p[nf][i] = __expf(sv[nf][i] - mnew[i]);
                    rsum[i] += p[nf][i];
                }
            #pragma unroll
            for (int off = 1; off < 16; off <<= 1)
                #pragma unroll
                for (int i = 0; i < 4; ++i)
                    rsum[i] += __shfl_xor(rsum[i], off);
            #pragma unroll
            for (int i = 0; i < 4; ++i) {
                lrow[i] = lrow[i] * corr[i] + rsum[i];
                mrow[i] = mnew[i];
            }
            #pragma unroll
            for (int df = 0; df < 4; ++df)
                #pragma unroll
                for (int i = 0; i < 4; ++i)
                    oa[df][i] *= corr[i];

            __syncthreads();   // all waves done reading K -> safe to alias P

            // ---- write P into K region (per-wave [16][64], XOR-swizzled) ----
            #pragma unroll
            for (int nf = 0; nf < 4; ++nf) {
                #pragma unroll
                for (int i = 0; i < 4; ++i) {
                    const int q = 4*g + i;
                    const int kv = (16*nf + r) ^ ((q & 7) << 3);
                    const ushort_t phb = f2bf(p[nf][i]);
                    Pwh[q * 64 + kv] = phb;
                    Pwl[q * 64 + kv] = f2bf(p[nf][i] - bf2f(phb));
                }
            }
            lgkm0();   // P writes visible to this wave's reads (per-wave slice)

            // ---- PV: O += P·V, bf16x3 ----
            #pragma unroll
            for (int ks = 0; ks < 2; ++ks) {
                const unsigned poff = (unsigned)(r * 64 + ((32*ks + 8*g) ^ ((r & 7) << 3)));
                const bf16x8 ph = *reinterpret_cast<const bf16x8*>(&Pwh[poff]);
                const bf16x8 pl = *reinterpret_cast<const bf16x8*>(&Pwl[poff]);
                #pragma unroll
                for (int df = 0; df < 4; ++df) {
                    const int vrow = 16*df + r;
                    const unsigned voff = (unsigned)(vrow * 128)
                        + (((unsigned)(ks*64 + g*16)) ^ ((unsigned)((vrow & 7) << 4)));
                    const bf16x8 vhf = *reinterpret_cast<const bf16x8*>((const char*)Vhi + voff);
                    const bf16x8 vlf = *reinterpret_cast<const bf16x8*>((const char*)Vlo + voff);
                    oa[df] = __builtin_amdgcn_mfma_f32_16x16x32_bf16(ph, vhf, oa[df], 0, 0, 0);
                    oa[df] = __builtin_amdgcn_mfma_f32_16x16x32_bf16(pl, vhf, oa[df], 0, 0, 0);
                    oa[df] = __builtin_amdgcn_mfma_f32_16x16x32_bf16(ph, vlf, oa[df], 0, 0, 0);
                }
            }

            // ---- commit staged registers to LDS for next tile ----
            if (kt < qt) {
                __syncthreads();                   // V readers done; P dead
                *reinterpret_cast<bf16x8*>(&Khi[d0])        = stg[0];
                *reinterpret_cast<bf16x8*>(&Khi[d0 + 2048]) = stg[1];
                *reinterpret_cast<bf16x8*>(&Klo[d0])        = stg[2];
                *reinterpret_cast<bf16x8*>(&Klo[d0 + 2048]) = stg[3];
                *reinterpret_cast<bf16x8*>(&Vhi[d0])        = stg[4];
                *reinterpret_cast<bf16x8*>(&Vhi[d0 + 2048]) = stg[5];
                *reinterpret_cast<bf16x8*>(&Vlo[d0])        = stg[6];
                *reinterpret_cast<bf16x8*>(&Vlo[d0 + 2048]) = stg[7];
                __syncthreads();                   // writes visible
            }
        }

        // ---- epilogue: hi/lo split of O / l ----
        #pragma unroll
        for (int i = 0; i < 4; ++i) {
            const float inv = 1.0f / lrow[i];
            const size_t row = (rowbase + q0 + 16*w + 4*g + i) * (size_t)M_ + hoff;
            #pragma unroll
            for (int df = 0; df < 4; ++df) {
                const float v = oa[df][i] * inv;
                const ushort_t hb = f2bf(v);
                ohi[row + 16*df + r] = hb;
                olo[row + 16*df + r] = f2bf(v - bf2f(hb));
            }
        }
    }
}

// ---------------------------------------------------------------------------
// Deepspeed dispatch bookkeeping (exact, f32).
// ---------------------------------------------------------------------------
__global__ __launch_bounds__(1024) void scan_kernel(const int* __restrict__ gidx,
                                                    const float* __restrict__ gtop,
                                                    float* __restrict__ gate_val,
                                                    int* __restrict__ token_at)
{
    __shared__ int hist[1024][E_];
    const int tid = threadIdx.x;
    for (int i = tid; i < E_ * C_; i += 1024) token_at[i] = -1;
    int my[8];
    #pragma unroll
    for (int t = 0; t < 8; ++t) my[t] = gidx[tid * 8 + t];
    #pragma unroll
    for (int e = 0; e < E_; ++e) {
        int c = 0;
        #pragma unroll
        for (int t = 0; t < 8; ++t) c += (my[t] == e) ? 1 : 0;
        hist[tid][e] = c;
    }
    __syncthreads();
    if (tid < E_) {
        int run = 0;
        for (int t = 0; t < 1024; ++t) {
            const int v = hist[t][tid];
            hist[t][tid] = run;
            run += v;
        }
    }
    __syncthreads();
    #pragma unroll
    for (int t = 0; t < 8; ++t) {
        const int s = tid * 8 + t;
        const int e = my[t];
        const int p = hist[tid][e];
        hist[tid][e] = p + 1;
        const bool keep = (p < C_);
        gate_val[s] = keep ? gtop[s] : 0.0f;
        if (keep) token_at[e * C_ + p] = s;
    }
}

__global__ __launch_bounds__(256) void dispatch_bf16_kernel(const float* __restrict__ h2,
                                                            const int* __restrict__ token_at,
                                                            ushort_t* __restrict__ disp)
{
    const int ec = blockIdx.x;
    const int s = token_at[ec];
    ushort4* dst = reinterpret_cast<ushort4*>(disp + (size_t)ec * M_);
    if (s >= 0) {
        const float4 v = reinterpret_cast<const float4*>(h2 + (size_t)s * M_)[threadIdx.x];
        dst[threadIdx.x] = make_ushort4(f2bf(v.x), f2bf(v.y), f2bf(v.z), f2bf(v.w));
    } else {
        dst[threadIdx.x] = make_ushort4(0, 0, 0, 0);
    }
}

// Transpose+convert: in[e][R][Cc] f32 -> out[e][Cc][R] bf16.
__global__ __launch_bounds__(256) void transpose_bf16_kernel(const float* __restrict__ in,
                                                             ushort_t* __restrict__ outp,
                                                             int R, int Cc)
{
    __shared__ float tile[32][33];
    const int e = blockIdx.z;
    in   += (size_t)e * R * Cc;
    outp += (size_t)e * R * Cc;
    const int tx = threadIdx.x & 31, ty0 = threadIdx.x >> 5;
    const int c0 = blockIdx.x * 32, r0 = blockIdx.y * 32;
    #pragma unroll
    for (int i = 0; i < 4; ++i)
        tile[ty0 + 8*i][tx] = in[(size_t)(r0 + ty0 + 8*i) * Cc + c0 + tx];
    __syncthreads();
    #pragma unroll
    for (int i = 0; i < 4; ++i)
        outp[(size_t)(c0 + ty0 + 8*i) * R + r0 + tx] = f2bf(tile[tx][ty0 + 8*i]);
}

// ---------------------------------------------------------------------------
// bf16 MFMA GEMM (MoE FFN, post-router) — unchanged, verified.
// ---------------------------------------------------------------------------
template<int EPI>
__global__ __launch_bounds__(256) void gemm_mfma(
    const ushort_t* __restrict__ A, const ushort_t* __restrict__ Bt,
    const float* __restrict__ bias,
    const int* __restrict__ token_at, const float* __restrict__ gate_val,
    void* __restrict__ Cout, int N, int K,
    long strA, long strB, long strBias, long strC)
{
    const int e = blockIdx.z;
    A    += (size_t)e * (size_t)strA;
    Bt   += (size_t)e * (size_t)strB;
    bias += (size_t)e * (size_t)strBias;

    __shared__ ushort_t As[128 * 32];
    __shared__ ushort_t Bs[128 * 32];

    const int t  = threadIdx.x;
    const int l  = t & 63;
    const int wv = t >> 6;
    const int wm = (wv & 1) * 64, wn = (wv >> 1) * 64;
    const int fr = l & 15, fk = (l >> 4) * 8;
    const int m0 = blockIdx.y * 128, n0 = blockIdx.x * 128;

    const ushort_t* gA = A + (size_t)(m0 + (t >> 2)) * K + (t & 3) * 8;
    const ushort_t* gB = Bt + (size_t)(n0 + (t >> 2)) * K + (t & 3) * 8;
    ushort_t* lA = As + wv * 512;
    ushort_t* lB = Bs + wv * 512;

    f32x4 acc[4][4] = {};

    for (int k0 = 0; k0 < K; k0 += 32) {
        __syncthreads();
        gload_lds16(gA + k0, lA);
        gload_lds16(gA + k0 + (size_t)64 * K, lA + 2048);
        gload_lds16(gB + k0, lB);
        gload_lds16(gB + k0 + (size_t)64 * K, lB + 2048);
        __syncthreads();
        bf16x8 af[4], bfr[4];
        #pragma unroll
        for (int i = 0; i < 4; ++i)
            af[i] = *reinterpret_cast<const bf16x8*>(&As[(wm + i*16 + fr) * 32 + fk]);
        #pragma unroll
        for (int i = 0; i < 4; ++i)
            bfr[i] = *reinterpret_cast<const bf16x8*>(&Bs[(wn + i*16 + fr) * 32 + fk]);
        #pragma unroll
        for (int mi = 0; mi < 4; ++mi) {
            #pragma unroll
            for (int ni = 0; ni < 4; ++ni)
                acc[mi][ni] = __builtin_amdgcn_mfma_f32_16x16x32_bf16(
                    af[mi], bfr[ni], acc[mi][ni], 0, 0, 0);
        }
    }

    const int l4 = (l >> 4) * 4;
    if (EPI == 0) {
        ushort_t* Cc = (ushort_t*)Cout + (size_t)e * (size_t)strC;
        #pragma unroll
        for (int ni = 0; ni < 4; ++ni) {
            const int cl = n0 + wn + ni*16 + fr;
            const float bb = bias[cl];
            #pragma unroll
            for (int mi = 0; mi < 4; ++mi) {
                #pragma unroll
                for (int i = 0; i < 4; ++i) {
                    const int rr = m0 + wm + mi*16 + l4 + i;
                    Cc[(size_t)rr * N + cl] = f2bf(gelu_exact(acc[mi][ni][i] + bb));
                }
            }
        }
    } else {
        float* Co = (float*)Cout;
        const int* ta = token_at + e * C_;
        #pragma unroll
        for (int mi = 0; mi < 4; ++mi) {
            #pragma unroll
            for (int i = 0; i < 4; ++i) {
                const int rr = m0 + wm + mi*16 + l4 + i;
                const int s = ta[rr];
                if (s >= 0) {
                    const float gvl = gate_val[s];
                    #pragma unroll
                    for (int ni = 0; ni < 4; ++ni) {
                        const int cl = n0 + wn + ni*16 + fr;
                        Co[(size_t)s * N + cl] += gvl * (acc[mi][ni][i] + bias[cl]);
                    }
                }
            }
        }
    }
}

// ---------------------------------------------------------------------------
extern "C" void kernel_launch(void* const* d_in, const int* in_sizes, int n_in,
                              void* d_out, int out_size, void* d_ws, size_t ws_size,
                              hipStream_t stream)
{
    const float* x    = (const float*)d_in[0];
    const float* ln1g = (const float*)d_in[1];
    const float* ln1b = (const float*)d_in[2];
    const float* Wqkv = (const float*)d_in[3];
    const float* bqkv = (const float*)d_in[4];
    const float* Wout = (const float*)d_in[5];
    const float* bout = (const float*)d_in[6];
    const float* ln2g = (const float*)d_in[7];
    const float* ln2b = (const float*)d_in[8];
    const float* wg   = (const float*)d_in[9];
    const float* w1   = (const float*)d_in[10];
    const float* b1   = (const float*)d_in[11];
    const float* w2   = (const float*)d_in[12];
    const float* b2   = (const float*)d_in[13];
    float* out = (float*)d_out;

    // Workspace (MiB offsets), lifetime-scheduled. Peak ~196 MiB.
    char* ws = (char*)d_ws;
    ushort_t* ahi   = (ushort_t*)ws;
    ushort_t* alo   = (ushort_t*)(ws + ((size_t)16  << 20));
    float*    buf_h = (float*)ws;
    ushort_t* qkvh  = (ushort_t*)(ws + ((size_t)32  << 20));
    ushort_t* qkvl  = (ushort_t*)(ws + ((size_t)80  << 20));
    ushort_t* vth   = (ushort_t*)(ws + ((size_t)128 << 20));
    ushort_t* vtl   = (ushort_t*)(ws + ((size_t)144 << 20));
    ushort_t* ohi   = (ushort_t*)(ws + ((size_t)160 << 20));
    ushort_t* olo   = (ushort_t*)(ws + ((size_t)176 << 20));
    ushort_t* wqh   = (ushort_t*)(ws + ((size_t)128 << 20));   // ph1 only
    ushort_t* wql   = (ushort_t*)(ws + ((size_t)134 << 20));   // ph1 only
    ushort_t* woh   = (ushort_t*)(ws + ((size_t)192 << 20));
    ushort_t* wol   = (ushort_t*)(ws + ((size_t)194 << 20));
    ushort_t* w1t   = (ushort_t*)(ws + ((size_t)32  << 20));
    ushort_t* w2t   = (ushort_t*)(ws + ((size_t)32  << 20));
    ushort_t* dispb = (ushort_t*)(ws + ((size_t)96  << 20));
    ushort_t* h1b   = (ushort_t*)(ws + ((size_t)112 << 20));
    float*    buf_gtop = (float*)(ws + ((size_t)196 << 20));
    float*    buf_gv   = buf_gtop + S_;
    int*      buf_idx  = (int*)(buf_gv + S_);
    int*      buf_ta   = buf_idx + S_;

    // --- pre-router path (f32-grade via bf16x3 MFMA) ---
    split_kernel<<<(3*M_*M_/4 + 255)/256, 256, 0, stream>>>(Wqkv, wqh, wql, 3*M_*M_/4);
    split_kernel<<<(M_*M_/4 + 255)/256, 256, 0, stream>>>(Wout, woh, wol, M_*M_/4);
    ln_split_kernel<<<S_, 256, 0, stream>>>(x, ln1g, ln1b, ahi, alo);
    gemm_bf16x3<2><<<dim3(3*M_/128, S_/128, 1), 256, 0, stream>>>(
        ahi, alo, wqh, wql, bqkv, nullptr, qkvh, qkvl, 3*M_, M_);
    vtrans_kernel<<<dim3(T_/64, H_, B_), 256, 0, stream>>>(qkvh, qkvl, vth, vtl);
    attn_mfma_kernel<<<dim3(1024, 1, 1), 256, 0, stream>>>(qkvh, qkvl, vth, vtl, ohi, olo);
    gemm_bf16x3<1><<<dim3(M_/128, S_/128, 1), 256, 0, stream>>>(
        ohi, olo, woh, wol, bout, x, out, nullptr, M_, M_);

    // --- router (exact f32; fused LN2 + gate) ---
    ln_gate_kernel<<<S_, 256, 0, stream>>>(out, ln2g, ln2b, wg, buf_h, buf_idx, buf_gtop);
    scan_kernel<<<1, 1024, 0, stream>>>(buf_idx, buf_gtop, buf_gv, buf_ta);
    dispatch_bf16_kernel<<<E_*C_, 256, 0, stream>>>(buf_h, buf_ta, dispb);

    // --- MoE FFN (bf16 MFMA, post-router) ---
    transpose_bf16_kernel<<<dim3(F_/32, M_/32, E_), 256, 0, stream>>>(w1, w1t, M_, F_);
    gemm_mfma<0><<<dim3(F_/128, C_/128, E_), 256, 0, stream>>>(
        dispb, w1t, b1, nullptr, nullptr, h1b, F_, M_,
        (long)C_*M_, (long)F_*M_, (long)F_, (long)C_*F_);
    transpose_bf16_kernel<<<dim3(M_/32, F_/32, E_), 256, 0, stream>>>(w2, w2t, F_, M_);
    gemm_mfma<1><<<dim3(M_/128, C_/128, E_), 256, 0, stream>>>(
        h1b, w2t, b2, buf_ta, buf_gv, out, M_, F_,
        (long)C_*F_, (long)M_*F_, (long)M_, 0);
}

// Round 16
// 893.127 us; speedup vs baseline: 1.2899x; 1.0039x over previous
//
#include <hip/hip_runtime.h>
#include <hip/hip_bf16.h>
#include <math.h>

#define B_ 4
#define T_ 2048
#define M_ 1024
#define H_ 16
#define E_ 8
#define S_ (B_*T_)      // 8192
#define C_ (S_/E_)      // 1024
#define D_ (M_/H_)      // 64
#define F_ (4*M_)       // 4096

typedef unsigned short ushort_t;
typedef __attribute__((ext_vector_type(8))) short bf16x8;
typedef __attribute__((ext_vector_type(4))) float f32x4;

__device__ __forceinline__ float gelu_exact(float x) {
    return 0.5f * x * (1.0f + erff(x * 0.70710678118654752440f));
}

__device__ __forceinline__ unsigned short f2bf(float f) {
    unsigned int u = __float_as_uint(f);
    u = (u + 0x7FFFu + ((u >> 16) & 1u)) >> 16;   // RNE
    return (unsigned short)u;
}

__device__ __forceinline__ float bf2f(unsigned short h) {
    return __uint_as_float(((unsigned)h) << 16);
}

__device__ __forceinline__ void gload_lds16(const void* g, void* l) {
    __builtin_amdgcn_global_load_lds(
        (const __attribute__((address_space(1))) unsigned int*)g,
        (__attribute__((address_space(3))) unsigned int*)l,
        16, 0, 0);
}

__device__ __forceinline__ void lgkm0() {
    asm volatile("s_waitcnt lgkmcnt(0)" ::: "memory");
}

// ---------------------------------------------------------------------------
// LayerNorm fused with hi/lo bf16 split output (LN1).
// ---------------------------------------------------------------------------
__global__ __launch_bounds__(256) void ln_split_kernel(const float* __restrict__ x,
                                                       const float* __restrict__ g,
                                                       const float* __restrict__ bta,
                                                       ushort_t* __restrict__ hi,
                                                       ushort_t* __restrict__ lo)
{
    const int row = blockIdx.x;
    const int tid = threadIdx.x;
    const float4 v = reinterpret_cast<const float4*>(x + (size_t)row * M_)[tid];
    float s = v.x + v.y + v.z + v.w;
    __shared__ float red[4];
    #pragma unroll
    for (int off = 32; off > 0; off >>= 1) s += __shfl_down(s, off);
    if ((tid & 63) == 0) red[tid >> 6] = s;
    __syncthreads();
    const float mu = (red[0] + red[1] + red[2] + red[3]) * (1.0f / (float)M_);
    __syncthreads();
    float4 d;
    d.x = v.x - mu; d.y = v.y - mu; d.z = v.z - mu; d.w = v.w - mu;
    float q = d.x*d.x + d.y*d.y + d.z*d.z + d.w*d.w;
    #pragma unroll
    for (int off = 32; off > 0; off >>= 1) q += __shfl_down(q, off);
    if ((tid & 63) == 0) red[tid >> 6] = q;
    __syncthreads();
    const float var  = (red[0] + red[1] + red[2] + red[3]) * (1.0f / (float)M_);
    const float rstd = 1.0f / sqrtf(var + 1e-5f);
    const float4 gv = reinterpret_cast<const float4*>(g)[tid];
    const float4 bv = reinterpret_cast<const float4*>(bta)[tid];
    float o[4];
    o[0] = d.x * rstd * gv.x + bv.x;
    o[1] = d.y * rstd * gv.y + bv.y;
    o[2] = d.z * rstd * gv.z + bv.z;
    o[3] = d.w * rstd * gv.w + bv.w;
    ushort4 hh, ll;
    hh.x = f2bf(o[0]); ll.x = f2bf(o[0] - bf2f(hh.x));
    hh.y = f2bf(o[1]); ll.y = f2bf(o[1] - bf2f(hh.y));
    hh.z = f2bf(o[2]); ll.z = f2bf(o[2] - bf2f(hh.z));
    hh.w = f2bf(o[3]); ll.w = f2bf(o[3] - bf2f(hh.w));
    reinterpret_cast<ushort4*>(hi + (size_t)row * M_)[tid] = hh;
    reinterpret_cast<ushort4*>(lo + (size_t)row * M_)[tid] = ll;
}

// ---------------------------------------------------------------------------
// Fused LN2 + router gate. h2 emitted directly as bf16 (identical values to
// the previous f32->dispatch->f2bf path; dispatch consumed only f2bf(h2)).
// ---------------------------------------------------------------------------
__global__ __launch_bounds__(256) void ln_gate_kernel(const float* __restrict__ x,
                                                      const float* __restrict__ g,
                                                      const float* __restrict__ bta,
                                                      const float* __restrict__ wg,
                                                      ushort_t* __restrict__ h2b,
                                                      int* __restrict__ gidx,
                                                      float* __restrict__ gtop)
{
    const int row = blockIdx.x;
    const int tid = threadIdx.x;
    const int wv = tid >> 6, ln = tid & 63;
    const float4 v = reinterpret_cast<const float4*>(x + (size_t)row * M_)[tid];
    float s = v.x + v.y + v.z + v.w;
    __shared__ float red[4];
    __shared__ float red2[4][E_];
    #pragma unroll
    for (int off = 32; off > 0; off >>= 1) s += __shfl_down(s, off);
    if (ln == 0) red[wv] = s;
    __syncthreads();
    const float mu = (red[0] + red[1] + red[2] + red[3]) * (1.0f / (float)M_);
    __syncthreads();
    float4 d;
    d.x = v.x - mu; d.y = v.y - mu; d.z = v.z - mu; d.w = v.w - mu;
    float q = d.x*d.x + d.y*d.y + d.z*d.z + d.w*d.w;
    #pragma unroll
    for (int off = 32; off > 0; off >>= 1) q += __shfl_down(q, off);
    if (ln == 0) red[wv] = q;
    __syncthreads();
    const float var  = (red[0] + red[1] + red[2] + red[3]) * (1.0f / (float)M_);
    const float rstd = 1.0f / sqrtf(var + 1e-5f);
    const float4 gv = reinterpret_cast<const float4*>(g)[tid];
    const float4 bv = reinterpret_cast<const float4*>(bta)[tid];
    float o[4];
    o[0] = d.x * rstd * gv.x + bv.x;
    o[1] = d.y * rstd * gv.y + bv.y;
    o[2] = d.z * rstd * gv.z + bv.z;
    o[3] = d.w * rstd * gv.w + bv.w;
    ushort4 hb;
    hb.x = f2bf(o[0]); hb.y = f2bf(o[1]); hb.z = f2bf(o[2]); hb.w = f2bf(o[3]);
    reinterpret_cast<ushort4*>(h2b + (size_t)row * M_)[tid] = hb;

    // logits: thread covers cols 4*tid..4*tid+3; wg is [M][E] row-major.
    float part[E_] = {};
    #pragma unroll
    for (int j = 0; j < 4; ++j) {
        const float4 w0 = reinterpret_cast<const float4*>(wg)[(4*tid + j) * 2];
        const float4 w1 = reinterpret_cast<const float4*>(wg)[(4*tid + j) * 2 + 1];
        part[0] = fmaf(o[j], w0.x, part[0]); part[1] = fmaf(o[j], w0.y, part[1]);
        part[2] = fmaf(o[j], w0.z, part[2]); part[3] = fmaf(o[j], w0.w, part[3]);
        part[4] = fmaf(o[j], w1.x, part[4]); part[5] = fmaf(o[j], w1.y, part[5]);
        part[6] = fmaf(o[j], w1.z, part[6]); part[7] = fmaf(o[j], w1.w, part[7]);
    }
    #pragma unroll
    for (int off = 32; off > 0; off >>= 1)
        #pragma unroll
        for (int e = 0; e < E_; ++e) part[e] += __shfl_down(part[e], off);
    if (ln == 0)
        #pragma unroll
        for (int e = 0; e < E_; ++e) red2[wv][e] = part[e];
    __syncthreads();
    if (tid == 0) {
        float lg[E_];
        #pragma unroll
        for (int e = 0; e < E_; ++e)
            lg[e] = red2[0][e] + red2[1][e] + red2[2][e] + red2[3][e];
        float mx = lg[0]; int bi = 0;
        #pragma unroll
        for (int i = 1; i < E_; ++i) { if (lg[i] > mx) { mx = lg[i]; bi = i; } }
        float den = 0.0f;
        #pragma unroll
        for (int i = 0; i < E_; ++i) den += expf(lg[i] - mx);
        gidx[row] = bi;
        gtop[row] = 1.0f / den;
    }
}

// Elementwise f32 -> hi/lo bf16 split (weights).
__global__ __launch_bounds__(256) void split_kernel(const float* __restrict__ in,
                                                    ushort_t* __restrict__ hi,
                                                    ushort_t* __restrict__ lo,
                                                    int n4)
{
    const int i = blockIdx.x * 256 + threadIdx.x;
    if (i >= n4) return;
    const float4 v = reinterpret_cast<const float4*>(in)[i];
    ushort4 hh, ll;
    hh.x = f2bf(v.x); ll.x = f2bf(v.x - bf2f(hh.x));
    hh.y = f2bf(v.y); ll.y = f2bf(v.y - bf2f(hh.y));
    hh.z = f2bf(v.z); ll.z = f2bf(v.z - bf2f(hh.z));
    hh.w = f2bf(v.w); ll.w = f2bf(v.w - bf2f(hh.w));
    reinterpret_cast<ushort4*>(hi)[i] = hh;
    reinterpret_cast<ushort4*>(lo)[i] = ll;
}

// V^T pre-transpose: qkv hi/lo [s][3M] (V slice) -> vt hi/lo [(b*H+h)*64+d][T].
__global__ __launch_bounds__(256) void vtrans_kernel(const ushort_t* __restrict__ qkvh,
                                                     const ushort_t* __restrict__ qkvl,
                                                     ushort_t* __restrict__ vth,
                                                     ushort_t* __restrict__ vtl)
{
    __shared__ ushort_t tile[64][72];
    const int t0 = blockIdx.x * 64, h = blockIdx.y, b = blockIdx.z;
    const int tid = threadIdx.x;
    const int tr = tid & 63, dc = (tid >> 6) * 16;
    const size_t src = ((size_t)(b*T_ + t0 + tr)) * (3*M_) + 2*M_ + h*64 + dc;
    const int dr = tid & 63, tc = (tid >> 6) * 16;
    const size_t dst = ((size_t)((b*H_ + h)*64 + dr)) * T_ + t0 + tc;

    #pragma unroll
    for (int pass = 0; pass < 2; ++pass) {
        const ushort_t* in = pass ? qkvl : qkvh;
        ushort_t* outp     = pass ? vtl  : vth;
        *reinterpret_cast<bf16x8*>(&tile[tr][dc])     = *reinterpret_cast<const bf16x8*>(in + src);
        *reinterpret_cast<bf16x8*>(&tile[tr][dc + 8]) = *reinterpret_cast<const bf16x8*>(in + src + 8);
        __syncthreads();
        bf16x8 o0, o1;
        #pragma unroll
        for (int j = 0; j < 8; ++j) {
            o0[j] = (short)tile[tc + j][dr];
            o1[j] = (short)tile[tc + 8 + j][dr];
        }
        *reinterpret_cast<bf16x8*>(outp + dst)     = o0;
        *reinterpret_cast<bf16x8*>(outp + dst + 8) = o1;
        __syncthreads();
    }
}

// ---------------------------------------------------------------------------
// bf16x3 MFMA GEMM (f32-grade, pre-router). m97 structure, 4 LDS buffers.
// EPI 1: f32 out = acc + bias + res.   EPI 2: hi/lo bf16 out = split(acc+bias).
// ---------------------------------------------------------------------------
template<int EPI>
__global__ __launch_bounds__(256) void gemm_bf16x3(
    const ushort_t* __restrict__ Ahi, const ushort_t* __restrict__ Alo,
    const ushort_t* __restrict__ Bhi, const ushort_t* __restrict__ Blo,
    const float* __restrict__ bias, const float* __restrict__ res,
    void* __restrict__ C0, ushort_t* __restrict__ C1, int N, int K)
{
    __shared__ ushort_t AsH[128*32], AsL[128*32];
    __shared__ ushort_t BsH[128*32], BsL[128*32];

    const int t  = threadIdx.x;
    const int l  = t & 63;
    const int wv = t >> 6;
    const int wm = (wv & 1) * 64, wn = (wv >> 1) * 64;
    const int fr = l & 15, fk = (l >> 4) * 8;
    const int m0 = blockIdx.y * 128, n0 = blockIdx.x * 128;

    const size_t arow = (size_t)(m0 + (t >> 2)) * K + (t & 3) * 8;
    const size_t brow = (size_t)(n0 + (t >> 2)) * K + (t & 3) * 8;
    ushort_t* lAH = AsH + wv * 512;
    ushort_t* lAL = AsL + wv * 512;
    ushort_t* lBH = BsH + wv * 512;
    ushort_t* lBL = BsL + wv * 512;

    f32x4 acc[4][4] = {};

    for (int k0 = 0; k0 < K; k0 += 32) {
        __syncthreads();
        gload_lds16(Ahi + arow + k0, lAH);
        gload_lds16(Ahi + arow + k0 + (size_t)64 * K, lAH + 2048);
        gload_lds16(Alo + arow + k0, lAL);
        gload_lds16(Alo + arow + k0 + (size_t)64 * K, lAL + 2048);
        gload_lds16(Bhi + brow + k0, lBH);
        gload_lds16(Bhi + brow + k0 + (size_t)64 * K, lBH + 2048);
        gload_lds16(Blo + brow + k0, lBL);
        gload_lds16(Blo + brow + k0 + (size_t)64 * K, lBL + 2048);
        __syncthreads();
        bf16x8 ah[4], al[4], bh[4], bl[4];
        #pragma unroll
        for (int i = 0; i < 4; ++i) {
            ah[i] = *reinterpret_cast<const bf16x8*>(&AsH[(wm + i*16 + fr) * 32 + fk]);
            al[i] = *reinterpret_cast<const bf16x8*>(&AsL[(wm + i*16 + fr) * 32 + fk]);
            bh[i] = *reinterpret_cast<const bf16x8*>(&BsH[(wn + i*16 + fr) * 32 + fk]);
            bl[i] = *reinterpret_cast<const bf16x8*>(&BsL[(wn + i*16 + fr) * 32 + fk]);
        }
        #pragma unroll
        for (int mi = 0; mi < 4; ++mi) {
            #pragma unroll
            for (int ni = 0; ni < 4; ++ni) {
                acc[mi][ni] = __builtin_amdgcn_mfma_f32_16x16x32_bf16(ah[mi], bh[ni], acc[mi][ni], 0, 0, 0);
                acc[mi][ni] = __builtin_amdgcn_mfma_f32_16x16x32_bf16(al[mi], bh[ni], acc[mi][ni], 0, 0, 0);
                acc[mi][ni] = __builtin_amdgcn_mfma_f32_16x16x32_bf16(ah[mi], bl[ni], acc[mi][ni], 0, 0, 0);
            }
        }
    }

    // C/D: col = lane&15, row = (lane>>4)*4 + reg
    const int l4 = (l >> 4) * 4;
    #pragma unroll
    for (int mi = 0; mi < 4; ++mi) {
        #pragma unroll
        for (int i = 0; i < 4; ++i) {
            const int row = m0 + wm + mi*16 + l4 + i;
            #pragma unroll
            for (int ni = 0; ni < 4; ++ni) {
                const int col = n0 + wn + ni*16 + fr;
                float v = acc[mi][ni][i] + bias[col];
                if (EPI == 1) {
                    v += res[(size_t)row * N + col];
                    ((float*)C0)[(size_t)row * N + col] = v;
                } else {
                    const ushort_t hb = f2bf(v);
                    ((ushort_t*)C0)[(size_t)row * N + col] = hb;
                    C1[(size_t)row * N + col] = f2bf(v - bf2f(hb));
                }
            }
        }
    }
}

// ---------------------------------------------------------------------------
// bf16x3 MFMA flash attention — PERSISTENT, 1024 blocks, 2 snake-paired items
// each. LDS diet (P aliases K, 32 KB, zero bank conflicts), natural VGPR
// allocation. Verified round-13/15 body (223 us).
// ---------------------------------------------------------------------------
__global__ __launch_bounds__(256) void attn_mfma_kernel(
    const ushort_t* __restrict__ qkvh, const ushort_t* __restrict__ qkvl,
    const ushort_t* __restrict__ vth,  const ushort_t* __restrict__ vtl,
    ushort_t* __restrict__ ohi, ushort_t* __restrict__ olo)
{
    const int j = (int)blockIdx.x;                 // 0..1023
    const int t = threadIdx.x;
    const int w = t >> 6, l = t & 63;
    const int r = l & 15, g = l >> 4;

    __shared__ ushort_t Khi[64*64], Klo[64*64];    // [kv][64] swizzled; P alias
    __shared__ ushort_t Vhi[64*64], Vlo[64*64];    // V^T [d][64 kv] swizzled

    ushort_t* Pwh = Khi + w * 1024;                // per-wave P [16 q][64 kv]
    ushort_t* Pwl = Klo + w * 1024;

    const int items[2] = { j, 2047 - j };

    // staging lane geometry (item-independent)
    const int srow = w*8 + (l >> 3);
    const int scol = ((l & 7) ^ (l >> 3)) * 8;
    const int d0 = w * 512 + l * 8;                // ushort index; +2048 = rows+32

    for (int ii = 0; ii < 2; ++ii) {
        const int item = items[ii];
        const int qt  = 31 - (item >> 6);          // rank -> qt (descending)
        const int rem = item & 63;
        const int h = rem >> 2, b = rem & 3;
        const int q0 = qt * 64;
        const size_t rowbase = (size_t)b * T_;
        const int hoff = h * D_;

        // Q fragments (A-frag: row = l&15, k = 32ks + 8g + j)
        bf16x8 qh[2], ql[2];
        {
            const size_t qrow = (rowbase + q0 + 16*w + r) * (size_t)(3*M_) + hoff;
            #pragma unroll
            for (int ks = 0; ks < 2; ++ks) {
                qh[ks] = *reinterpret_cast<const bf16x8*>(qkvh + qrow + 32*ks + 8*g);
                ql[ks] = *reinterpret_cast<const bf16x8*>(qkvl + qrow + 32*ks + 8*g);
            }
        }

        const size_t ksrc0 = (rowbase + srow) * (size_t)(3*M_) + hoff + M_ + scol;
        const size_t vsrc0 = ((size_t)((b*H_ + h)*64 + srow)) * T_ + scol;

        bf16x8 stg[8];
        __syncthreads();   // previous item's LDS readers done
        // prologue: stage tile 0
        {
            const size_t kb = ksrc0, vb = vsrc0;
            const size_t kstep = (size_t)32 * (3*M_);
            stg[0] = *reinterpret_cast<const bf16x8*>(qkvh + kb);
            stg[1] = *reinterpret_cast<const bf16x8*>(qkvh + kb + kstep);
            stg[2] = *reinterpret_cast<const bf16x8*>(qkvl + kb);
            stg[3] = *reinterpret_cast<const bf16x8*>(qkvl + kb + kstep);
            stg[4] = *reinterpret_cast<const bf16x8*>(vth + vb);
            stg[5] = *reinterpret_cast<const bf16x8*>(vth + vb + 32*T_);
            stg[6] = *reinterpret_cast<const bf16x8*>(vtl + vb);
            stg[7] = *reinterpret_cast<const bf16x8*>(vtl + vb + 32*T_);
            *reinterpret_cast<bf16x8*>(&Khi[d0])        = stg[0];
            *reinterpret_cast<bf16x8*>(&Khi[d0 + 2048]) = stg[1];
            *reinterpret_cast<bf16x8*>(&Klo[d0])        = stg[2];
            *reinterpret_cast<bf16x8*>(&Klo[d0 + 2048]) = stg[3];
            *reinterpret_cast<bf16x8*>(&Vhi[d0])        = stg[4];
            *reinterpret_cast<bf16x8*>(&Vhi[d0 + 2048]) = stg[5];
            *reinterpret_cast<bf16x8*>(&Vlo[d0])        = stg[6];
            *reinterpret_cast<bf16x8*>(&Vlo[d0 + 2048]) = stg[7];
        }
        __syncthreads();

        f32x4 oa[4] = {};
        float mrow[4] = {-__builtin_inff(), -__builtin_inff(), -__builtin_inff(), -__builtin_inff()};
        float lrow[4] = {};

        for (int kt = 0; kt <= qt; ++kt) {
            // ---- QK^T: S[16 q][64 kv], bf16x3, K frags from LDS ----
            f32x4 sa[4] = {};
            #pragma unroll
            for (int ks = 0; ks < 2; ++ks) {
                bf16x8 kh[4], kl[4];
                #pragma unroll
                for (int nf = 0; nf < 4; ++nf) {
                    const int row = 16*nf + r;
                    const unsigned boff = (unsigned)(row * 128)
                        + (((unsigned)(ks*64 + g*16)) ^ ((unsigned)((row & 7) << 4)));
                    kh[nf] = *reinterpret_cast<const bf16x8*>((const char*)Khi + boff);
                    kl[nf] = *reinterpret_cast<const bf16x8*>((const char*)Klo + boff);
                }
                #pragma unroll
                for (int nf = 0; nf < 4; ++nf) {
                    sa[nf] = __builtin_amdgcn_mfma_f32_16x16x32_bf16(qh[ks], kh[nf], sa[nf], 0, 0, 0);
                    sa[nf] = __builtin_amdgcn_mfma_f32_16x16x32_bf16(ql[ks], kh[nf], sa[nf], 0, 0, 0);
                    sa[nf] = __builtin_amdgcn_mfma_f32_16x16x32_bf16(qh[ks], kl[nf], sa[nf], 0, 0, 0);
                }
            }

            // ---- issue next tile's staging loads into registers (T14) ----
            if (kt < qt) {
                const size_t kb = ksrc0 + (size_t)((kt+1)*64) * (3*M_);
                const size_t vb = vsrc0 + (size_t)((kt+1)*64);
                const size_t kstep = (size_t)32 * (3*M_);
                stg[0] = *reinterpret_cast<const bf16x8*>(qkvh + kb);
                stg[1] = *reinterpret_cast<const bf16x8*>(qkvh + kb + kstep);
                stg[2] = *reinterpret_cast<const bf16x8*>(qkvl + kb);
                stg[3] = *reinterpret_cast<const bf16x8*>(qkvl + kb + kstep);
                stg[4] = *reinterpret_cast<const bf16x8*>(vth + vb);
                stg[5] = *reinterpret_cast<const bf16x8*>(vth + vb + 32*T_);
                stg[6] = *reinterpret_cast<const bf16x8*>(vtl + vb);
                stg[7] = *reinterpret_cast<const bf16x8*>(vtl + vb + 32*T_);
            }

            // ---- scale + causal mask ----
            float sv[4][4];
            #pragma unroll
            for (int nf = 0; nf < 4; ++nf)
                #pragma unroll
                for (int i = 0; i < 4; ++i)
                    sv[nf][i] = sa[nf][i] * 0.125f;
            if (kt == qt) {
                #pragma unroll
                for (int nf = 0; nf < 4; ++nf) {
                    const int kvg = kt*64 + 16*nf + r;
                    #pragma unroll
                    for (int i = 0; i < 4; ++i) {
                        const int qg = q0 + 16*w + 4*g + i;
                        if (kvg > qg) sv[nf][i] = -3.0e38f;
                    }
                }
            }

            // ---- online softmax (native exp) ----
            float tmax[4];
            #pragma unroll
            for (int i = 0; i < 4; ++i)
                tmax[i] = fmaxf(fmaxf(sv[0][i], sv[1][i]), fmaxf(sv[2][i], sv[3][i]));
            #pragma unroll
            for (int off = 1; off < 16; off <<= 1)
                #pragma unroll
                for (int i = 0; i < 4; ++i)
                    tmax[i] = fmaxf(tmax[i], __shfl_xor(tmax[i], off));
            float mnew[4], corr[4];
            #pragma unroll
            for (int i = 0; i < 4; ++i) {
                mnew[i] = fmaxf(mrow[i], tmax[i]);
                corr[i] = __expf(mrow[i] - mnew[i]);
            }
            float p[4][4];
            float rsum[4] = {};
            #pragma unroll
            for (int nf = 0; nf < 4; ++nf)
                #pragma unroll
                for (int i = 0; i < 4; ++i) {
                    p[nf][i] = __expf(sv[nf][i] - mnew[i]);
                    rsum[i] += p[nf][i];
                }
            #pragma unroll
            for (int off = 1; off < 16; off <<= 1)
                #pragma unroll
                for (int i = 0; i < 4; ++i)
                    rsum[i] += __shfl_xor(rsum[i], off);
            #pragma unroll
            for (int i = 0; i < 4; ++i) {
                lrow[i] = lrow[i] * corr[i] + rsum[i];
                mrow[i] = mnew[i];
            }
            #pragma unroll
            for (int df = 0; df < 4; ++df)
                #pragma unroll
                for (int i = 0; i < 4; ++i)
                    oa[df][i] *= corr[i];

            __syncthreads();   // all waves done reading K -> safe to alias P

            // ---- write P into K region (per-wave [16][64], XOR-swizzled) ----
            #pragma unroll
            for (int nf = 0; nf < 4; ++nf) {
                #pragma unroll
                for (int i = 0; i < 4; ++i) {
                    const int q = 4*g + i;
                    const int kv = (16*nf + r) ^ ((q & 7) << 3);
                    const ushort_t phb = f2bf(p[nf][i]);
                    Pwh[q * 64 + kv] = phb;
                    Pwl[q * 64 + kv] = f2bf(p[nf][i] - bf2f(phb));
                }
            }
            lgkm0();   // P writes visible to this wave's reads (per-wave slice)

            // ---- PV: O += P·V, bf16x3 ----
            #pragma unroll
            for (int ks = 0; ks < 2; ++ks) {
                const unsigned poff = (unsigned)(r * 64 + ((32*ks + 8*g) ^ ((r & 7) << 3)));
                const bf16x8 ph = *reinterpret_cast<const bf16x8*>(&Pwh[poff]);
                const bf16x8 pl = *reinterpret_cast<const bf16x8*>(&Pwl[poff]);
                #pragma unroll
                for (int df = 0; df < 4; ++df) {
                    const int vrow = 16*df + r;
                    const unsigned voff = (unsigned)(vrow * 128)
                        + (((unsigned)(ks*64 + g*16)) ^ ((unsigned)((vrow & 7) << 4)));
                    const bf16x8 vhf = *reinterpret_cast<const bf16x8*>((const char*)Vhi + voff);
                    const bf16x8 vlf = *reinterpret_cast<const bf16x8*>((const char*)Vlo + voff);
                    oa[df] = __builtin_amdgcn_mfma_f32_16x16x32_bf16(ph, vhf, oa[df], 0, 0, 0);
                    oa[df] = __builtin_amdgcn_mfma_f32_16x16x32_bf16(pl, vhf, oa[df], 0, 0, 0);
                    oa[df] = __builtin_amdgcn_mfma_f32_16x16x32_bf16(ph, vlf, oa[df], 0, 0, 0);
                }
            }

            // ---- commit staged registers to LDS for next tile ----
            if (kt < qt) {
                __syncthreads();                   // V readers done; P dead
                *reinterpret_cast<bf16x8*>(&Khi[d0])        = stg[0];
                *reinterpret_cast<bf16x8*>(&Khi[d0 + 2048]) = stg[1];
                *reinterpret_cast<bf16x8*>(&Klo[d0])        = stg[2];
                *reinterpret_cast<bf16x8*>(&Klo[d0 + 2048]) = stg[3];
                *reinterpret_cast<bf16x8*>(&Vhi[d0])        = stg[4];
                *reinterpret_cast<bf16x8*>(&Vhi[d0 + 2048]) = stg[5];
                *reinterpret_cast<bf16x8*>(&Vlo[d0])        = stg[6];
                *reinterpret_cast<bf16x8*>(&Vlo[d0 + 2048]) = stg[7];
                __syncthreads();                   // writes visible
            }
        }

        // ---- epilogue: hi/lo split of O / l ----
        #pragma unroll
        for (int i = 0; i < 4; ++i) {
            const float inv = 1.0f / lrow[i];
            const size_t row = (rowbase + q0 + 16*w + 4*g + i) * (size_t)M_ + hoff;
            #pragma unroll
            for (int df = 0; df < 4; ++df) {
                const float v = oa[df][i] * inv;
                const ushort_t hb = f2bf(v);
                ohi[row + 16*df + r] = hb;
                olo[row + 16*df + r] = f2bf(v - bf2f(hb));
            }
        }
    }
}

// ---------------------------------------------------------------------------
// Deepspeed dispatch bookkeeping — parallel Hillis-Steele scan (integer adds,
// positions identical to the serial token-order scan).
// ---------------------------------------------------------------------------
__global__ __launch_bounds__(1024) void scan_kernel(const int* __restrict__ gidx,
                                                    const float* __restrict__ gtop,
                                                    float* __restrict__ gate_val,
                                                    int* __restrict__ token_at)
{
    __shared__ int hist[1024][E_];
    const int tid = threadIdx.x;
    for (int i = tid; i < E_ * C_; i += 1024) token_at[i] = -1;
    int my[8];
    #pragma unroll
    for (int t = 0; t < 8; ++t) my[t] = gidx[tid * 8 + t];
    int cnt[E_] = {};
    #pragma unroll
    for (int t = 0; t < 8; ++t) ++cnt[my[t]];
    #pragma unroll
    for (int e = 0; e < E_; ++e) hist[tid][e] = cnt[e];
    __syncthreads();
    for (int off = 1; off < 1024; off <<= 1) {
        int add[E_];
        #pragma unroll
        for (int e = 0; e < E_; ++e) add[e] = (tid >= off) ? hist[tid - off][e] : 0;
        __syncthreads();
        #pragma unroll
        for (int e = 0; e < E_; ++e) hist[tid][e] += add[e];
        __syncthreads();
    }
    int base[E_];
    #pragma unroll
    for (int e = 0; e < E_; ++e) base[e] = hist[tid][e] - cnt[e];   // exclusive
    int run[E_] = {};
    #pragma unroll
    for (int t = 0; t < 8; ++t) {
        const int s = tid * 8 + t;
        const int e = my[t];
        const int p = base[e] + run[e];
        ++run[e];
        const bool keep = (p < C_);
        gate_val[s] = keep ? gtop[s] : 0.0f;
        if (keep) token_at[e * C_ + p] = s;
    }
}

// Gather-dispatch from bf16 h2 (values identical to prior f32->f2bf path).
__global__ __launch_bounds__(256) void dispatch_bf16_kernel(const ushort_t* __restrict__ h2b,
                                                            const int* __restrict__ token_at,
                                                            ushort_t* __restrict__ disp)
{
    const int ec = blockIdx.x;
    const int s = token_at[ec];
    ushort4* dst = reinterpret_cast<ushort4*>(disp + (size_t)ec * M_);
    if (s >= 0) {
        dst[threadIdx.x] = reinterpret_cast<const ushort4*>(h2b + (size_t)s * M_)[threadIdx.x];
    } else {
        dst[threadIdx.x] = make_ushort4(0, 0, 0, 0);
    }
}

// Transpose+convert: in[e][R][Cc] f32 -> out[e][Cc][R] bf16.
__global__ __launch_bounds__(256) void transpose_bf16_kernel(const float* __restrict__ in,
                                                             ushort_t* __restrict__ outp,
                                                             int R, int Cc)
{
    __shared__ float tile[32][33];
    const int e = blockIdx.z;
    in   += (size_t)e * R * Cc;
    outp += (size_t)e * R * Cc;
    const int tx = threadIdx.x & 31, ty0 = threadIdx.x >> 5;
    const int c0 = blockIdx.x * 32, r0 = blockIdx.y * 32;
    #pragma unroll
    for (int i = 0; i < 4; ++i)
        tile[ty0 + 8*i][tx] = in[(size_t)(r0 + ty0 + 8*i) * Cc + c0 + tx];
    __syncthreads();
    #pragma unroll
    for (int i = 0; i < 4; ++i)
        outp[(size_t)(c0 + ty0 + 8*i) * R + r0 + tx] = f2bf(tile[tx][ty0 + 8*i]);
}

// ---------------------------------------------------------------------------
// bf16 MFMA GEMM (MoE FFN, post-router) — unchanged, verified.
// ---------------------------------------------------------------------------
template<int EPI>
__global__ __launch_bounds__(256) void gemm_mfma(
    const ushort_t* __restrict__ A, const ushort_t* __restrict__ Bt,
    const float* __restrict__ bias,
    const int* __restrict__ token_at, const float* __restrict__ gate_val,
    void* __restrict__ Cout, int N, int K,
    long strA, long strB, long strBias, long strC)
{
    const int e = blockIdx.z;
    A    += (size_t)e * (size_t)strA;
    Bt   += (size_t)e * (size_t)strB;
    bias += (size_t)e * (size_t)strBias;

    __shared__ ushort_t As[128 * 32];
    __shared__ ushort_t Bs[128 * 32];

    const int t  = threadIdx.x;
    const int l  = t & 63;
    const int wv = t >> 6;
    const int wm = (wv & 1) * 64, wn = (wv >> 1) * 64;
    const int fr = l & 15, fk = (l >> 4) * 8;
    const int m0 = blockIdx.y * 128, n0 = blockIdx.x * 128;

    const ushort_t* gA = A + (size_t)(m0 + (t >> 2)) * K + (t & 3) * 8;
    const ushort_t* gB = Bt + (size_t)(n0 + (t >> 2)) * K + (t & 3) * 8;
    ushort_t* lA = As + wv * 512;
    ushort_t* lB = Bs + wv * 512;

    f32x4 acc[4][4] = {};

    for (int k0 = 0; k0 < K; k0 += 32) {
        __syncthreads();
        gload_lds16(gA + k0, lA);
        gload_lds16(gA + k0 + (size_t)64 * K, lA + 2048);
        gload_lds16(gB + k0, lB);
        gload_lds16(gB + k0 + (size_t)64 * K, lB + 2048);
        __syncthreads();
        bf16x8 af[4], bfr[4];
        #pragma unroll
        for (int i = 0; i < 4; ++i)
            af[i] = *reinterpret_cast<const bf16x8*>(&As[(wm + i*16 + fr) * 32 + fk]);
        #pragma unroll
        for (int i = 0; i < 4; ++i)
            bfr[i] = *reinterpret_cast<const bf16x8*>(&Bs[(wn + i*16 + fr) * 32 + fk]);
        #pragma unroll
        for (int mi = 0; mi < 4; ++mi) {
            #pragma unroll
            for (int ni = 0; ni < 4; ++ni)
                acc[mi][ni] = __builtin_amdgcn_mfma_f32_16x16x32_bf16(
                    af[mi], bfr[ni], acc[mi][ni], 0, 0, 0);
        }
    }

    const int l4 = (l >> 4) * 4;
    if (EPI == 0) {
        ushort_t* Cc = (ushort_t*)Cout + (size_t)e * (size_t)strC;
        #pragma unroll
        for (int ni = 0; ni < 4; ++ni) {
            const int cl = n0 + wn + ni*16 + fr;
            const float bb = bias[cl];
            #pragma unroll
            for (int mi = 0; mi < 4; ++mi) {
                #pragma unroll
                for (int i = 0; i < 4; ++i) {
                    const int rr = m0 + wm + mi*16 + l4 + i;
                    Cc[(size_t)rr * N + cl] = f2bf(gelu_exact(acc[mi][ni][i] + bb));
                }
            }
        }
    } else {
        float* Co = (float*)Cout;
        const int* ta = token_at + e * C_;
        #pragma unroll
        for (int mi = 0; mi < 4; ++mi) {
            #pragma unroll
            for (int i = 0; i < 4; ++i) {
                const int rr = m0 + wm + mi*16 + l4 + i;
                const int s = ta[rr];
                if (s >= 0) {
                    const float gvl = gate_val[s];
                    #pragma unroll
                    for (int ni = 0; ni < 4; ++ni) {
                        const int cl = n0 + wn + ni*16 + fr;
                        Co[(size_t)s * N + cl] += gvl * (acc[mi][ni][i] + bias[cl]);
                    }
                }
            }
        }
    }
}

// ---------------------------------------------------------------------------
extern "C" void kernel_launch(void* const* d_in, const int* in_sizes, int n_in,
                              void* d_out, int out_size, void* d_ws, size_t ws_size,
                              hipStream_t stream)
{
    const float* x    = (const float*)d_in[0];
    const float* ln1g = (const float*)d_in[1];
    const float* ln1b = (const float*)d_in[2];
    const float* Wqkv = (const float*)d_in[3];
    const float* bqkv = (const float*)d_in[4];
    const float* Wout = (const float*)d_in[5];
    const float* bout = (const float*)d_in[6];
    const float* ln2g = (const float*)d_in[7];
    const float* ln2b = (const float*)d_in[8];
    const float* wg   = (const float*)d_in[9];
    const float* w1   = (const float*)d_in[10];
    const float* b1   = (const float*)d_in[11];
    const float* w2   = (const float*)d_in[12];
    const float* b2   = (const float*)d_in[13];
    float* out = (float*)d_out;

    // Workspace (MiB offsets), lifetime-scheduled. Peak ~196 MiB.
    char* ws = (char*)d_ws;
    ushort_t* ahi   = (ushort_t*)ws;
    ushort_t* alo   = (ushort_t*)(ws + ((size_t)16  << 20));
    ushort_t* h2b   = (ushort_t*)ws;                           // router phase
    ushort_t* qkvh  = (ushort_t*)(ws + ((size_t)32  << 20));
    ushort_t* qkvl  = (ushort_t*)(ws + ((size_t)80  << 20));
    ushort_t* vth   = (ushort_t*)(ws + ((size_t)128 << 20));
    ushort_t* vtl   = (ushort_t*)(ws + ((size_t)144 << 20));
    ushort_t* ohi   = (ushort_t*)(ws + ((size_t)160 << 20));
    ushort_t* olo   = (ushort_t*)(ws + ((size_t)176 << 20));
    ushort_t* wqh   = (ushort_t*)(ws + ((size_t)128 << 20));   // ph1 only
    ushort_t* wql   = (ushort_t*)(ws + ((size_t)134 << 20));   // ph1 only
    ushort_t* woh   = (ushort_t*)(ws + ((size_t)192 << 20));
    ushort_t* wol   = (ushort_t*)(ws + ((size_t)194 << 20));
    ushort_t* w1t   = (ushort_t*)(ws + ((size_t)32  << 20));
    ushort_t* w2t   = (ushort_t*)(ws + ((size_t)32  << 20));
    ushort_t* dispb = (ushort_t*)(ws + ((size_t)96  << 20));
    ushort_t* h1b   = (ushort_t*)(ws + ((size_t)112 << 20));
    float*    buf_gtop = (float*)(ws + ((size_t)196 << 20));
    float*    buf_gv   = buf_gtop + S_;
    int*      buf_idx  = (int*)(buf_gv + S_);
    int*      buf_ta   = buf_idx + S_;

    // --- pre-router path (f32-grade via bf16x3 MFMA) ---
    split_kernel<<<(3*M_*M_/4 + 255)/256, 256, 0, stream>>>(Wqkv, wqh, wql, 3*M_*M_/4);
    split_kernel<<<(M_*M_/4 + 255)/256, 256, 0, stream>>>(Wout, woh, wol, M_*M_/4);
    ln_split_kernel<<<S_, 256, 0, stream>>>(x, ln1g, ln1b, ahi, alo);
    gemm_bf16x3<2><<<dim3(3*M_/128, S_/128, 1), 256, 0, stream>>>(
        ahi, alo, wqh, wql, bqkv, nullptr, qkvh, qkvl, 3*M_, M_);
    vtrans_kernel<<<dim3(T_/64, H_, B_), 256, 0, stream>>>(qkvh, qkvl, vth, vtl);
    attn_mfma_kernel<<<dim3(1024, 1, 1), 256, 0, stream>>>(qkvh, qkvl, vth, vtl, ohi, olo);
    gemm_bf16x3<1><<<dim3(M_/128, S_/128, 1), 256, 0, stream>>>(
        ohi, olo, woh, wol, bout, x, out, nullptr, M_, M_);

    // --- router (exact f32; fused LN2 + gate; h2 as bf16) ---
    ln_gate_kernel<<<S_, 256, 0, stream>>>(out, ln2g, ln2b, wg, h2b, buf_idx, buf_gtop);
    scan_kernel<<<1, 1024, 0, stream>>>(buf_idx, buf_gtop, buf_gv, buf_ta);
    dispatch_bf16_kernel<<<E_*C_, 256, 0, stream>>>(h2b, buf_ta, dispb);

    // --- MoE FFN (bf16 MFMA, post-router) ---
    transpose_bf16_kernel<<<dim3(F_/32, M_/32, E_), 256, 0, stream>>>(w1, w1t, M_, F_);
    gemm_mfma<0><<<dim3(F_/128, C_/128, E_), 256, 0, stream>>>(
        dispb, w1t, b1, nullptr, nullptr, h1b, F_, M_,
        (long)C_*M_, (long)F_*M_, (long)F_, (long)C_*F_);
    transpose_bf16_kernel<<<dim3(M_/32, F_/32, E_), 256, 0, stream>>>(w2, w2t, F_, M_);
    gemm_mfma<1><<<dim3(M_/128, C_/128, E_), 256, 0, stream>>>(
        h1b, w2t, b2, buf_ta, buf_gv, out, M_, F_,
        (long)C_*F_, (long)M_*F_, (long)M_, 0);
}

// Round 17
// 848.267 us; speedup vs baseline: 1.3582x; 1.0529x over previous
//
#include <hip/hip_runtime.h>
#include <hip/hip_bf16.h>
#include <math.h>

#define B_ 4
#define T_ 2048
#define M_ 1024
#define H_ 16
#define E_ 8
#define S_ (B_*T_)      // 8192
#define C_ (S_/E_)      // 1024
#define D_ (M_/H_)      // 64
#define F_ (4*M_)       // 4096

typedef unsigned short ushort_t;
typedef __attribute__((ext_vector_type(8))) short bf16x8;
typedef __attribute__((ext_vector_type(4))) float f32x4;

__device__ __forceinline__ float gelu_exact(float x) {
    return 0.5f * x * (1.0f + erff(x * 0.70710678118654752440f));
}

__device__ __forceinline__ unsigned short f2bf(float f) {
    unsigned int u = __float_as_uint(f);
    u = (u + 0x7FFFu + ((u >> 16) & 1u)) >> 16;   // RNE
    return (unsigned short)u;
}

__device__ __forceinline__ float bf2f(unsigned short h) {
    return __uint_as_float(((unsigned)h) << 16);
}

__device__ __forceinline__ void gload_lds16(const void* g, void* l) {
    __builtin_amdgcn_global_load_lds(
        (const __attribute__((address_space(1))) unsigned int*)g,
        (__attribute__((address_space(3))) unsigned int*)l,
        16, 0, 0);
}

__device__ __forceinline__ void lgkm0() {
    asm volatile("s_waitcnt lgkmcnt(0)" ::: "memory");
}

// ---------------------------------------------------------------------------
// LayerNorm fused with hi/lo bf16 split output (LN1).
// ---------------------------------------------------------------------------
__global__ __launch_bounds__(256) void ln_split_kernel(const float* __restrict__ x,
                                                       const float* __restrict__ g,
                                                       const float* __restrict__ bta,
                                                       ushort_t* __restrict__ hi,
                                                       ushort_t* __restrict__ lo)
{
    const int row = blockIdx.x;
    const int tid = threadIdx.x;
    const float4 v = reinterpret_cast<const float4*>(x + (size_t)row * M_)[tid];
    float s = v.x + v.y + v.z + v.w;
    __shared__ float red[4];
    #pragma unroll
    for (int off = 32; off > 0; off >>= 1) s += __shfl_down(s, off);
    if ((tid & 63) == 0) red[tid >> 6] = s;
    __syncthreads();
    const float mu = (red[0] + red[1] + red[2] + red[3]) * (1.0f / (float)M_);
    __syncthreads();
    float4 d;
    d.x = v.x - mu; d.y = v.y - mu; d.z = v.z - mu; d.w = v.w - mu;
    float q = d.x*d.x + d.y*d.y + d.z*d.z + d.w*d.w;
    #pragma unroll
    for (int off = 32; off > 0; off >>= 1) q += __shfl_down(q, off);
    if ((tid & 63) == 0) red[tid >> 6] = q;
    __syncthreads();
    const float var  = (red[0] + red[1] + red[2] + red[3]) * (1.0f / (float)M_);
    const float rstd = 1.0f / sqrtf(var + 1e-5f);
    const float4 gv = reinterpret_cast<const float4*>(g)[tid];
    const float4 bv = reinterpret_cast<const float4*>(bta)[tid];
    float o[4];
    o[0] = d.x * rstd * gv.x + bv.x;
    o[1] = d.y * rstd * gv.y + bv.y;
    o[2] = d.z * rstd * gv.z + bv.z;
    o[3] = d.w * rstd * gv.w + bv.w;
    ushort4 hh, ll;
    hh.x = f2bf(o[0]); ll.x = f2bf(o[0] - bf2f(hh.x));
    hh.y = f2bf(o[1]); ll.y = f2bf(o[1] - bf2f(hh.y));
    hh.z = f2bf(o[2]); ll.z = f2bf(o[2] - bf2f(hh.z));
    hh.w = f2bf(o[3]); ll.w = f2bf(o[3] - bf2f(hh.w));
    reinterpret_cast<ushort4*>(hi + (size_t)row * M_)[tid] = hh;
    reinterpret_cast<ushort4*>(lo + (size_t)row * M_)[tid] = ll;
}

// ---------------------------------------------------------------------------
// Fused LN2 + router gate. h2 emitted directly as bf16.
// ---------------------------------------------------------------------------
__global__ __launch_bounds__(256) void ln_gate_kernel(const float* __restrict__ x,
                                                      const float* __restrict__ g,
                                                      const float* __restrict__ bta,
                                                      const float* __restrict__ wg,
                                                      ushort_t* __restrict__ h2b,
                                                      int* __restrict__ gidx,
                                                      float* __restrict__ gtop)
{
    const int row = blockIdx.x;
    const int tid = threadIdx.x;
    const int wv = tid >> 6, ln = tid & 63;
    const float4 v = reinterpret_cast<const float4*>(x + (size_t)row * M_)[tid];
    float s = v.x + v.y + v.z + v.w;
    __shared__ float red[4];
    __shared__ float red2[4][E_];
    #pragma unroll
    for (int off = 32; off > 0; off >>= 1) s += __shfl_down(s, off);
    if (ln == 0) red[wv] = s;
    __syncthreads();
    const float mu = (red[0] + red[1] + red[2] + red[3]) * (1.0f / (float)M_);
    __syncthreads();
    float4 d;
    d.x = v.x - mu; d.y = v.y - mu; d.z = v.z - mu; d.w = v.w - mu;
    float q = d.x*d.x + d.y*d.y + d.z*d.z + d.w*d.w;
    #pragma unroll
    for (int off = 32; off > 0; off >>= 1) q += __shfl_down(q, off);
    if (ln == 0) red[wv] = q;
    __syncthreads();
    const float var  = (red[0] + red[1] + red[2] + red[3]) * (1.0f / (float)M_);
    const float rstd = 1.0f / sqrtf(var + 1e-5f);
    const float4 gv = reinterpret_cast<const float4*>(g)[tid];
    const float4 bv = reinterpret_cast<const float4*>(bta)[tid];
    float o[4];
    o[0] = d.x * rstd * gv.x + bv.x;
    o[1] = d.y * rstd * gv.y + bv.y;
    o[2] = d.z * rstd * gv.z + bv.z;
    o[3] = d.w * rstd * gv.w + bv.w;
    ushort4 hb;
    hb.x = f2bf(o[0]); hb.y = f2bf(o[1]); hb.z = f2bf(o[2]); hb.w = f2bf(o[3]);
    reinterpret_cast<ushort4*>(h2b + (size_t)row * M_)[tid] = hb;

    // logits: thread covers cols 4*tid..4*tid+3; wg is [M][E] row-major.
    float part[E_] = {};
    #pragma unroll
    for (int j = 0; j < 4; ++j) {
        const float4 w0 = reinterpret_cast<const float4*>(wg)[(4*tid + j) * 2];
        const float4 w1 = reinterpret_cast<const float4*>(wg)[(4*tid + j) * 2 + 1];
        part[0] = fmaf(o[j], w0.x, part[0]); part[1] = fmaf(o[j], w0.y, part[1]);
        part[2] = fmaf(o[j], w0.z, part[2]); part[3] = fmaf(o[j], w0.w, part[3]);
        part[4] = fmaf(o[j], w1.x, part[4]); part[5] = fmaf(o[j], w1.y, part[5]);
        part[6] = fmaf(o[j], w1.z, part[6]); part[7] = fmaf(o[j], w1.w, part[7]);
    }
    #pragma unroll
    for (int off = 32; off > 0; off >>= 1)
        #pragma unroll
        for (int e = 0; e < E_; ++e) part[e] += __shfl_down(part[e], off);
    if (ln == 0)
        #pragma unroll
        for (int e = 0; e < E_; ++e) red2[wv][e] = part[e];
    __syncthreads();
    if (tid == 0) {
        float lg[E_];
        #pragma unroll
        for (int e = 0; e < E_; ++e)
            lg[e] = red2[0][e] + red2[1][e] + red2[2][e] + red2[3][e];
        float mx = lg[0]; int bi = 0;
        #pragma unroll
        for (int i = 1; i < E_; ++i) { if (lg[i] > mx) { mx = lg[i]; bi = i; } }
        float den = 0.0f;
        #pragma unroll
        for (int i = 0; i < E_; ++i) den += expf(lg[i] - mx);
        gidx[row] = bi;
        gtop[row] = 1.0f / den;
    }
}

// Elementwise f32 -> hi/lo bf16 split (weights).
__global__ __launch_bounds__(256) void split_kernel(const float* __restrict__ in,
                                                    ushort_t* __restrict__ hi,
                                                    ushort_t* __restrict__ lo,
                                                    int n4)
{
    const int i = blockIdx.x * 256 + threadIdx.x;
    if (i >= n4) return;
    const float4 v = reinterpret_cast<const float4*>(in)[i];
    ushort4 hh, ll;
    hh.x = f2bf(v.x); ll.x = f2bf(v.x - bf2f(hh.x));
    hh.y = f2bf(v.y); ll.y = f2bf(v.y - bf2f(hh.y));
    hh.z = f2bf(v.z); ll.z = f2bf(v.z - bf2f(hh.z));
    hh.w = f2bf(v.w); ll.w = f2bf(v.w - bf2f(hh.w));
    reinterpret_cast<ushort4*>(hi)[i] = hh;
    reinterpret_cast<ushort4*>(lo)[i] = ll;
}

// V^T pre-transpose: qkv hi/lo [s][3M] (V slice) -> vt hi/lo [(b*H+h)*64+d][T].
__global__ __launch_bounds__(256) void vtrans_kernel(const ushort_t* __restrict__ qkvh,
                                                     const ushort_t* __restrict__ qkvl,
                                                     ushort_t* __restrict__ vth,
                                                     ushort_t* __restrict__ vtl)
{
    __shared__ ushort_t tile[64][72];
    const int t0 = blockIdx.x * 64, h = blockIdx.y, b = blockIdx.z;
    const int tid = threadIdx.x;
    const int tr = tid & 63, dc = (tid >> 6) * 16;
    const size_t src = ((size_t)(b*T_ + t0 + tr)) * (3*M_) + 2*M_ + h*64 + dc;
    const int dr = tid & 63, tc = (tid >> 6) * 16;
    const size_t dst = ((size_t)((b*H_ + h)*64 + dr)) * T_ + t0 + tc;

    #pragma unroll
    for (int pass = 0; pass < 2; ++pass) {
        const ushort_t* in = pass ? qkvl : qkvh;
        ushort_t* outp     = pass ? vtl  : vth;
        *reinterpret_cast<bf16x8*>(&tile[tr][dc])     = *reinterpret_cast<const bf16x8*>(in + src);
        *reinterpret_cast<bf16x8*>(&tile[tr][dc + 8]) = *reinterpret_cast<const bf16x8*>(in + src + 8);
        __syncthreads();
        bf16x8 o0, o1;
        #pragma unroll
        for (int j = 0; j < 8; ++j) {
            o0[j] = (short)tile[tc + j][dr];
            o1[j] = (short)tile[tc + 8 + j][dr];
        }
        *reinterpret_cast<bf16x8*>(outp + dst)     = o0;
        *reinterpret_cast<bf16x8*>(outp + dst + 8) = o1;
        __syncthreads();
    }
}

// ---------------------------------------------------------------------------
// bf16x3 MFMA GEMM (f32-grade, pre-router). m97 structure, 4 LDS buffers.
// EPI 1: f32 out = acc + bias + res.   EPI 2: hi/lo bf16 out = split(acc+bias).
// ---------------------------------------------------------------------------
template<int EPI>
__global__ __launch_bounds__(256) void gemm_bf16x3(
    const ushort_t* __restrict__ Ahi, const ushort_t* __restrict__ Alo,
    const ushort_t* __restrict__ Bhi, const ushort_t* __restrict__ Blo,
    const float* __restrict__ bias, const float* __restrict__ res,
    void* __restrict__ C0, ushort_t* __restrict__ C1, int N, int K)
{
    __shared__ ushort_t AsH[128*32], AsL[128*32];
    __shared__ ushort_t BsH[128*32], BsL[128*32];

    const int t  = threadIdx.x;
    const int l  = t & 63;
    const int wv = t >> 6;
    const int wm = (wv & 1) * 64, wn = (wv >> 1) * 64;
    const int fr = l & 15, fk = (l >> 4) * 8;
    const int m0 = blockIdx.y * 128, n0 = blockIdx.x * 128;

    const size_t arow = (size_t)(m0 + (t >> 2)) * K + (t & 3) * 8;
    const size_t brow = (size_t)(n0 + (t >> 2)) * K + (t & 3) * 8;
    ushort_t* lAH = AsH + wv * 512;
    ushort_t* lAL = AsL + wv * 512;
    ushort_t* lBH = BsH + wv * 512;
    ushort_t* lBL = BsL + wv * 512;

    f32x4 acc[4][4] = {};

    for (int k0 = 0; k0 < K; k0 += 32) {
        __syncthreads();
        gload_lds16(Ahi + arow + k0, lAH);
        gload_lds16(Ahi + arow + k0 + (size_t)64 * K, lAH + 2048);
        gload_lds16(Alo + arow + k0, lAL);
        gload_lds16(Alo + arow + k0 + (size_t)64 * K, lAL + 2048);
        gload_lds16(Bhi + brow + k0, lBH);
        gload_lds16(Bhi + brow + k0 + (size_t)64 * K, lBH + 2048);
        gload_lds16(Blo + brow + k0, lBL);
        gload_lds16(Blo + brow + k0 + (size_t)64 * K, lBL + 2048);
        __syncthreads();
        bf16x8 ah[4], al[4], bh[4], bl[4];
        #pragma unroll
        for (int i = 0; i < 4; ++i) {
            ah[i] = *reinterpret_cast<const bf16x8*>(&AsH[(wm + i*16 + fr) * 32 + fk]);
            al[i] = *reinterpret_cast<const bf16x8*>(&AsL[(wm + i*16 + fr) * 32 + fk]);
            bh[i] = *reinterpret_cast<const bf16x8*>(&BsH[(wn + i*16 + fr) * 32 + fk]);
            bl[i] = *reinterpret_cast<const bf16x8*>(&BsL[(wn + i*16 + fr) * 32 + fk]);
        }
        #pragma unroll
        for (int mi = 0; mi < 4; ++mi) {
            #pragma unroll
            for (int ni = 0; ni < 4; ++ni) {
                acc[mi][ni] = __builtin_amdgcn_mfma_f32_16x16x32_bf16(ah[mi], bh[ni], acc[mi][ni], 0, 0, 0);
                acc[mi][ni] = __builtin_amdgcn_mfma_f32_16x16x32_bf16(al[mi], bh[ni], acc[mi][ni], 0, 0, 0);
                acc[mi][ni] = __builtin_amdgcn_mfma_f32_16x16x32_bf16(ah[mi], bl[ni], acc[mi][ni], 0, 0, 0);
            }
        }
    }

    // C/D: col = lane&15, row = (lane>>4)*4 + reg
    const int l4 = (l >> 4) * 4;
    #pragma unroll
    for (int mi = 0; mi < 4; ++mi) {
        #pragma unroll
        for (int i = 0; i < 4; ++i) {
            const int row = m0 + wm + mi*16 + l4 + i;
            #pragma unroll
            for (int ni = 0; ni < 4; ++ni) {
                const int col = n0 + wn + ni*16 + fr;
                float v = acc[mi][ni][i] + bias[col];
                if (EPI == 1) {
                    v += res[(size_t)row * N + col];
                    ((float*)C0)[(size_t)row * N + col] = v;
                } else {
                    const ushort_t hb = f2bf(v);
                    ((ushort_t*)C0)[(size_t)row * N + col] = hb;
                    C1[(size_t)row * N + col] = f2bf(v - bf2f(hb));
                }
            }
        }
    }
}

// ---------------------------------------------------------------------------
// bf16x3 MFMA flash attention — PERSISTENT, 1024 blocks, 2 snake-paired items
// each. Verified round-13/15 body (223 us).
// ---------------------------------------------------------------------------
__global__ __launch_bounds__(256) void attn_mfma_kernel(
    const ushort_t* __restrict__ qkvh, const ushort_t* __restrict__ qkvl,
    const ushort_t* __restrict__ vth,  const ushort_t* __restrict__ vtl,
    ushort_t* __restrict__ ohi, ushort_t* __restrict__ olo)
{
    const int j = (int)blockIdx.x;                 // 0..1023
    const int t = threadIdx.x;
    const int w = t >> 6, l = t & 63;
    const int r = l & 15, g = l >> 4;

    __shared__ ushort_t Khi[64*64], Klo[64*64];    // [kv][64] swizzled; P alias
    __shared__ ushort_t Vhi[64*64], Vlo[64*64];    // V^T [d][64 kv] swizzled

    ushort_t* Pwh = Khi + w * 1024;                // per-wave P [16 q][64 kv]
    ushort_t* Pwl = Klo + w * 1024;

    const int items[2] = { j, 2047 - j };

    // staging lane geometry (item-independent)
    const int srow = w*8 + (l >> 3);
    const int scol = ((l & 7) ^ (l >> 3)) * 8;
    const int d0 = w * 512 + l * 8;                // ushort index; +2048 = rows+32

    for (int ii = 0; ii < 2; ++ii) {
        const int item = items[ii];
        const int qt  = 31 - (item >> 6);          // rank -> qt (descending)
        const int rem = item & 63;
        const int h = rem >> 2, b = rem & 3;
        const int q0 = qt * 64;
        const size_t rowbase = (size_t)b * T_;
        const int hoff = h * D_;

        // Q fragments (A-frag: row = l&15, k = 32ks + 8g + j)
        bf16x8 qh[2], ql[2];
        {
            const size_t qrow = (rowbase + q0 + 16*w + r) * (size_t)(3*M_) + hoff;
            #pragma unroll
            for (int ks = 0; ks < 2; ++ks) {
                qh[ks] = *reinterpret_cast<const bf16x8*>(qkvh + qrow + 32*ks + 8*g);
                ql[ks] = *reinterpret_cast<const bf16x8*>(qkvl + qrow + 32*ks + 8*g);
            }
        }

        const size_t ksrc0 = (rowbase + srow) * (size_t)(3*M_) + hoff + M_ + scol;
        const size_t vsrc0 = ((size_t)((b*H_ + h)*64 + srow)) * T_ + scol;

        bf16x8 stg[8];
        __syncthreads();   // previous item's LDS readers done
        // prologue: stage tile 0
        {
            const size_t kb = ksrc0, vb = vsrc0;
            const size_t kstep = (size_t)32 * (3*M_);
            stg[0] = *reinterpret_cast<const bf16x8*>(qkvh + kb);
            stg[1] = *reinterpret_cast<const bf16x8*>(qkvh + kb + kstep);
            stg[2] = *reinterpret_cast<const bf16x8*>(qkvl + kb);
            stg[3] = *reinterpret_cast<const bf16x8*>(qkvl + kb + kstep);
            stg[4] = *reinterpret_cast<const bf16x8*>(vth + vb);
            stg[5] = *reinterpret_cast<const bf16x8*>(vth + vb + 32*T_);
            stg[6] = *reinterpret_cast<const bf16x8*>(vtl + vb);
            stg[7] = *reinterpret_cast<const bf16x8*>(vtl + vb + 32*T_);
            *reinterpret_cast<bf16x8*>(&Khi[d0])        = stg[0];
            *reinterpret_cast<bf16x8*>(&Khi[d0 + 2048]) = stg[1];
            *reinterpret_cast<bf16x8*>(&Klo[d0])        = stg[2];
            *reinterpret_cast<bf16x8*>(&Klo[d0 + 2048]) = stg[3];
            *reinterpret_cast<bf16x8*>(&Vhi[d0])        = stg[4];
            *reinterpret_cast<bf16x8*>(&Vhi[d0 + 2048]) = stg[5];
            *reinterpret_cast<bf16x8*>(&Vlo[d0])        = stg[6];
            *reinterpret_cast<bf16x8*>(&Vlo[d0 + 2048]) = stg[7];
        }
        __syncthreads();

        f32x4 oa[4] = {};
        float mrow[4] = {-__builtin_inff(), -__builtin_inff(), -__builtin_inff(), -__builtin_inff()};
        float lrow[4] = {};

        for (int kt = 0; kt <= qt; ++kt) {
            // ---- QK^T: S[16 q][64 kv], bf16x3, K frags from LDS ----
            f32x4 sa[4] = {};
            #pragma unroll
            for (int ks = 0; ks < 2; ++ks) {
                bf16x8 kh[4], kl[4];
                #pragma unroll
                for (int nf = 0; nf < 4; ++nf) {
                    const int row = 16*nf + r;
                    const unsigned boff = (unsigned)(row * 128)
                        + (((unsigned)(ks*64 + g*16)) ^ ((unsigned)((row & 7) << 4)));
                    kh[nf] = *reinterpret_cast<const bf16x8*>((const char*)Khi + boff);
                    kl[nf] = *reinterpret_cast<const bf16x8*>((const char*)Klo + boff);
                }
                #pragma unroll
                for (int nf = 0; nf < 4; ++nf) {
                    sa[nf] = __builtin_amdgcn_mfma_f32_16x16x32_bf16(qh[ks], kh[nf], sa[nf], 0, 0, 0);
                    sa[nf] = __builtin_amdgcn_mfma_f32_16x16x32_bf16(ql[ks], kh[nf], sa[nf], 0, 0, 0);
                    sa[nf] = __builtin_amdgcn_mfma_f32_16x16x32_bf16(qh[ks], kl[nf], sa[nf], 0, 0, 0);
                }
            }

            // ---- issue next tile's staging loads into registers (T14) ----
            if (kt < qt) {
                const size_t kb = ksrc0 + (size_t)((kt+1)*64) * (3*M_);
                const size_t vb = vsrc0 + (size_t)((kt+1)*64);
                const size_t kstep = (size_t)32 * (3*M_);
                stg[0] = *reinterpret_cast<const bf16x8*>(qkvh + kb);
                stg[1] = *reinterpret_cast<const bf16x8*>(qkvh + kb + kstep);
                stg[2] = *reinterpret_cast<const bf16x8*>(qkvl + kb);
                stg[3] = *reinterpret_cast<const bf16x8*>(qkvl + kb + kstep);
                stg[4] = *reinterpret_cast<const bf16x8*>(vth + vb);
                stg[5] = *reinterpret_cast<const bf16x8*>(vth + vb + 32*T_);
                stg[6] = *reinterpret_cast<const bf16x8*>(vtl + vb);
                stg[7] = *reinterpret_cast<const bf16x8*>(vtl + vb + 32*T_);
            }

            // ---- scale + causal mask ----
            float sv[4][4];
            #pragma unroll
            for (int nf = 0; nf < 4; ++nf)
                #pragma unroll
                for (int i = 0; i < 4; ++i)
                    sv[nf][i] = sa[nf][i] * 0.125f;
            if (kt == qt) {
                #pragma unroll
                for (int nf = 0; nf < 4; ++nf) {
                    const int kvg = kt*64 + 16*nf + r;
                    #pragma unroll
                    for (int i = 0; i < 4; ++i) {
                        const int qg = q0 + 16*w + 4*g + i;
                        if (kvg > qg) sv[nf][i] = -3.0e38f;
                    }
                }
            }

            // ---- online softmax (native exp) ----
            float tmax[4];
            #pragma unroll
            for (int i = 0; i < 4; ++i)
                tmax[i] = fmaxf(fmaxf(sv[0][i], sv[1][i]), fmaxf(sv[2][i], sv[3][i]));
            #pragma unroll
            for (int off = 1; off < 16; off <<= 1)
                #pragma unroll
                for (int i = 0; i < 4; ++i)
                    tmax[i] = fmaxf(tmax[i], __shfl_xor(tmax[i], off));
            float mnew[4], corr[4];
            #pragma unroll
            for (int i = 0; i < 4; ++i) {
                mnew[i] = fmaxf(mrow[i], tmax[i]);
                corr[i] = __expf(mrow[i] - mnew[i]);
            }
            float p[4][4];
            float rsum[4] = {};
            #pragma unroll
            for (int nf = 0; nf < 4; ++nf)
                #pragma unroll
                for (int i = 0; i < 4; ++i) {
                    p[nf][i] = __expf(sv[nf][i] - mnew[i]);
                    rsum[i] += p[nf][i];
                }
            #pragma unroll
            for (int off = 1; off < 16; off <<= 1)
                #pragma unroll
                for (int i = 0; i < 4; ++i)
                    rsum[i] += __shfl_xor(rsum[i], off);
            #pragma unroll
            for (int i = 0; i < 4; ++i) {
                lrow[i] = lrow[i] * corr[i] + rsum[i];
                mrow[i] = mnew[i];
            }
            #pragma unroll
            for (int df = 0; df < 4; ++df)
                #pragma unroll
                for (int i = 0; i < 4; ++i)
                    oa[df][i] *= corr[i];

            __syncthreads();   // all waves done reading K -> safe to alias P

            // ---- write P into K region (per-wave [16][64], XOR-swizzled) ----
            #pragma unroll
            for (int nf = 0; nf < 4; ++nf) {
                #pragma unroll
                for (int i = 0; i < 4; ++i) {
                    const int q = 4*g + i;
                    const int kv = (16*nf + r) ^ ((q & 7) << 3);
                    const ushort_t phb = f2bf(p[nf][i]);
                    Pwh[q * 64 + kv] = phb;
                    Pwl[q * 64 + kv] = f2bf(p[nf][i] - bf2f(phb));
                }
            }
            lgkm0();   // P writes visible to this wave's reads (per-wave slice)

            // ---- PV: O += P·V, bf16x3 ----
            #pragma unroll
            for (int ks = 0; ks < 2; ++ks) {
                const unsigned poff = (unsigned)(r * 64 + ((32*ks + 8*g) ^ ((r & 7) << 3)));
                const bf16x8 ph = *reinterpret_cast<const bf16x8*>(&Pwh[poff]);
                const bf16x8 pl = *reinterpret_cast<const bf16x8*>(&Pwl[poff]);
                #pragma unroll
                for (int df = 0; df < 4; ++df) {
                    const int vrow = 16*df + r;
                    const unsigned voff = (unsigned)(vrow * 128)
                        + (((unsigned)(ks*64 + g*16)) ^ ((unsigned)((vrow & 7) << 4)));
                    const bf16x8 vhf = *reinterpret_cast<const bf16x8*>((const char*)Vhi + voff);
                    const bf16x8 vlf = *reinterpret_cast<const bf16x8*>((const char*)Vlo + voff);
                    oa[df] = __builtin_amdgcn_mfma_f32_16x16x32_bf16(ph, vhf, oa[df], 0, 0, 0);
                    oa[df] = __builtin_amdgcn_mfma_f32_16x16x32_bf16(pl, vhf, oa[df], 0, 0, 0);
                    oa[df] = __builtin_amdgcn_mfma_f32_16x16x32_bf16(ph, vlf, oa[df], 0, 0, 0);
                }
            }

            // ---- commit staged registers to LDS for next tile ----
            if (kt < qt) {
                __syncthreads();                   // V readers done; P dead
                *reinterpret_cast<bf16x8*>(&Khi[d0])        = stg[0];
                *reinterpret_cast<bf16x8*>(&Khi[d0 + 2048]) = stg[1];
                *reinterpret_cast<bf16x8*>(&Klo[d0])        = stg[2];
                *reinterpret_cast<bf16x8*>(&Klo[d0 + 2048]) = stg[3];
                *reinterpret_cast<bf16x8*>(&Vhi[d0])        = stg[4];
                *reinterpret_cast<bf16x8*>(&Vhi[d0 + 2048]) = stg[5];
                *reinterpret_cast<bf16x8*>(&Vlo[d0])        = stg[6];
                *reinterpret_cast<bf16x8*>(&Vlo[d0 + 2048]) = stg[7];
                __syncthreads();                   // writes visible
            }
        }

        // ---- epilogue: hi/lo split of O / l ----
        #pragma unroll
        for (int i = 0; i < 4; ++i) {
            const float inv = 1.0f / lrow[i];
            const size_t row = (rowbase + q0 + 16*w + 4*g + i) * (size_t)M_ + hoff;
            #pragma unroll
            for (int df = 0; df < 4; ++df) {
                const float v = oa[df][i] * inv;
                const ushort_t hb = f2bf(v);
                ohi[row + 16*df + r] = hb;
                olo[row + 16*df + r] = f2bf(v - bf2f(hb));
            }
        }
    }
}

// ---------------------------------------------------------------------------
// Deepspeed dispatch bookkeeping — parallel Hillis-Steele scan.
// ---------------------------------------------------------------------------
__global__ __launch_bounds__(1024) void scan_kernel(const int* __restrict__ gidx,
                                                    const float* __restrict__ gtop,
                                                    float* __restrict__ gate_val,
                                                    int* __restrict__ token_at)
{
    __shared__ int hist[1024][E_];
    const int tid = threadIdx.x;
    for (int i = tid; i < E_ * C_; i += 1024) token_at[i] = -1;
    int my[8];
    #pragma unroll
    for (int t = 0; t < 8; ++t) my[t] = gidx[tid * 8 + t];
    int cnt[E_] = {};
    #pragma unroll
    for (int t = 0; t < 8; ++t) ++cnt[my[t]];
    #pragma unroll
    for (int e = 0; e < E_; ++e) hist[tid][e] = cnt[e];
    __syncthreads();
    for (int off = 1; off < 1024; off <<= 1) {
        int add[E_];
        #pragma unroll
        for (int e = 0; e < E_; ++e) add[e] = (tid >= off) ? hist[tid - off][e] : 0;
        __syncthreads();
        #pragma unroll
        for (int e = 0; e < E_; ++e) hist[tid][e] += add[e];
        __syncthreads();
    }
    int base[E_];
    #pragma unroll
    for (int e = 0; e < E_; ++e) base[e] = hist[tid][e] - cnt[e];   // exclusive
    int run[E_] = {};
    #pragma unroll
    for (int t = 0; t < 8; ++t) {
        const int s = tid * 8 + t;
        const int e = my[t];
        const int p = base[e] + run[e];
        ++run[e];
        const bool keep = (p < C_);
        gate_val[s] = keep ? gtop[s] : 0.0f;
        if (keep) token_at[e * C_ + p] = s;
    }
}

// Gather-dispatch from bf16 h2.
__global__ __launch_bounds__(256) void dispatch_bf16_kernel(const ushort_t* __restrict__ h2b,
                                                            const int* __restrict__ token_at,
                                                            ushort_t* __restrict__ disp)
{
    const int ec = blockIdx.x;
    const int s = token_at[ec];
    ushort4* dst = reinterpret_cast<ushort4*>(disp + (size_t)ec * M_);
    if (s >= 0) {
        dst[threadIdx.x] = reinterpret_cast<const ushort4*>(h2b + (size_t)s * M_)[threadIdx.x];
    } else {
        dst[threadIdx.x] = make_ushort4(0, 0, 0, 0);
    }
}

// Transpose+convert: in[e][R][Cc] f32 -> out[e][Cc][R] bf16.
__global__ __launch_bounds__(256) void transpose_bf16_kernel(const float* __restrict__ in,
                                                             ushort_t* __restrict__ outp,
                                                             int R, int Cc)
{
    __shared__ float tile[32][33];
    const int e = blockIdx.z;
    in   += (size_t)e * R * Cc;
    outp += (size_t)e * R * Cc;
    const int tx = threadIdx.x & 31, ty0 = threadIdx.x >> 5;
    const int c0 = blockIdx.x * 32, r0 = blockIdx.y * 32;
    #pragma unroll
    for (int i = 0; i < 4; ++i)
        tile[ty0 + 8*i][tx] = in[(size_t)(r0 + ty0 + 8*i) * Cc + c0 + tx];
    __syncthreads();
    #pragma unroll
    for (int i = 0; i < 4; ++i)
        outp[(size_t)(c0 + ty0 + 8*i) * R + r0 + tx] = f2bf(tile[tx][ty0 + 8*i]);
}

// ---------------------------------------------------------------------------
// bf16 MFMA GEMM (MoE FFN, post-router) — BK=64 + XOR-swizzled LDS.
// Staging: pre-swizzled global source chunk ((t&7)^(row&7)) -> linear
// gload_lds dest (LDS[row][c] = G[row][c^(row&7)]); frag reads XOR
// ((row&7)<<3) elems. Conflicts: 8-way -> 2-way; barriers per MFMA halved.
// Accumulation order identical to BK=32 version (ks loop replays k0 order).
// ---------------------------------------------------------------------------
template<int EPI>
__global__ __launch_bounds__(256) void gemm_mfma(
    const ushort_t* __restrict__ A, const ushort_t* __restrict__ Bt,
    const float* __restrict__ bias,
    const int* __restrict__ token_at, const float* __restrict__ gate_val,
    void* __restrict__ Cout, int N, int K,
    long strA, long strB, long strBias, long strC)
{
    const int e = blockIdx.z;
    A    += (size_t)e * (size_t)strA;
    Bt   += (size_t)e * (size_t)strB;
    bias += (size_t)e * (size_t)strBias;

    __shared__ ushort_t As[128 * 64];   // 16 KiB
    __shared__ ushort_t Bs[128 * 64];   // 16 KiB

    const int t  = threadIdx.x;
    const int l  = t & 63;
    const int wv = t >> 6;
    const int wm = (wv & 1) * 64, wn = (wv >> 1) * 64;
    const int fr = l & 15, fk = (l >> 4) * 8;
    const int m0 = blockIdx.y * 128, n0 = blockIdx.x * 128;

    // staging: thread t covers row = t>>3 (+32 per call), chunk c = t&7;
    // source chunk pre-swizzled: c ^ (row&7). (row offsets are multiples of 32
    // so row&7 is call-invariant.)
    const int srow = t >> 3;
    const int schunk = (t & 7) ^ (srow & 7);
    const ushort_t* gA = A + (size_t)(m0 + srow) * K + schunk * 8;
    const ushort_t* gB = Bt + (size_t)(n0 + srow) * K + schunk * 8;
    ushort_t* lA = As + wv * 512;       // wave-uniform; HW adds lane*16B
    ushort_t* lB = Bs + wv * 512;

    // frag read swizzle: row&7 == fr&7 (wm, 16*i are multiples of 8)
    const int aswz = (fr & 7) << 3;

    f32x4 acc[4][4] = {};

    for (int k0 = 0; k0 < K; k0 += 64) {
        __syncthreads();
        gload_lds16(gA + k0,                  lA);
        gload_lds16(gA + k0 + (size_t)32 * K, lA + 2048);
        gload_lds16(gA + k0 + (size_t)64 * K, lA + 4096);
        gload_lds16(gA + k0 + (size_t)96 * K, lA + 6144);
        gload_lds16(gB + k0,                  lB);
        gload_lds16(gB + k0 + (size_t)32 * K, lB + 2048);
        gload_lds16(gB + k0 + (size_t)64 * K, lB + 4096);
        gload_lds16(gB + k0 + (size_t)96 * K, lB + 6144);
        __syncthreads();
        #pragma unroll
        for (int ks = 0; ks < 2; ++ks) {
            bf16x8 af[4], bfr[4];
            #pragma unroll
            for (int i = 0; i < 4; ++i) {
                af[i] = *reinterpret_cast<const bf16x8*>(
                    &As[(wm + i*16 + fr) * 64 + ((32*ks + fk) ^ aswz)]);
                bfr[i] = *reinterpret_cast<const bf16x8*>(
                    &Bs[(wn + i*16 + fr) * 64 + ((32*ks + fk) ^ aswz)]);
            }
            #pragma unroll
            for (int mi = 0; mi < 4; ++mi) {
                #pragma unroll
                for (int ni = 0; ni < 4; ++ni)
                    acc[mi][ni] = __builtin_amdgcn_mfma_f32_16x16x32_bf16(
                        af[mi], bfr[ni], acc[mi][ni], 0, 0, 0);
            }
        }
    }

    const int l4 = (l >> 4) * 4;
    if (EPI == 0) {
        ushort_t* Cc = (ushort_t*)Cout + (size_t)e * (size_t)strC;
        #pragma unroll
        for (int ni = 0; ni < 4; ++ni) {
            const int cl = n0 + wn + ni*16 + fr;
            const float bb = bias[cl];
            #pragma unroll
            for (int mi = 0; mi < 4; ++mi) {
                #pragma unroll
                for (int i = 0; i < 4; ++i) {
                    const int rr = m0 + wm + mi*16 + l4 + i;
                    Cc[(size_t)rr * N + cl] = f2bf(gelu_exact(acc[mi][ni][i] + bb));
                }
            }
        }
    } else {
        float* Co = (float*)Cout;
        const int* ta = token_at + e * C_;
        #pragma unroll
        for (int mi = 0; mi < 4; ++mi) {
            #pragma unroll
            for (int i = 0; i < 4; ++i) {
                const int rr = m0 + wm + mi*16 + l4 + i;
                const int s = ta[rr];
                if (s >= 0) {
                    const float gvl = gate_val[s];
                    #pragma unroll
                    for (int ni = 0; ni < 4; ++ni) {
                        const int cl = n0 + wn + ni*16 + fr;
                        Co[(size_t)s * N + cl] += gvl * (acc[mi][ni][i] + bias[cl]);
                    }
                }
            }
        }
    }
}

// ---------------------------------------------------------------------------
extern "C" void kernel_launch(void* const* d_in, const int* in_sizes, int n_in,
                              void* d_out, int out_size, void* d_ws, size_t ws_size,
                              hipStream_t stream)
{
    const float* x    = (const float*)d_in[0];
    const float* ln1g = (const float*)d_in[1];
    const float* ln1b = (const float*)d_in[2];
    const float* Wqkv = (const float*)d_in[3];
    const float* bqkv = (const float*)d_in[4];
    const float* Wout = (const float*)d_in[5];
    const float* bout = (const float*)d_in[6];
    const float* ln2g = (const float*)d_in[7];
    const float* ln2b = (const float*)d_in[8];
    const float* wg   = (const float*)d_in[9];
    const float* w1   = (const float*)d_in[10];
    const float* b1   = (const float*)d_in[11];
    const float* w2   = (const float*)d_in[12];
    const float* b2   = (const float*)d_in[13];
    float* out = (float*)d_out;

    // Workspace (MiB offsets), lifetime-scheduled. Peak ~196 MiB.
    char* ws = (char*)d_ws;
    ushort_t* ahi   = (ushort_t*)ws;
    ushort_t* alo   = (ushort_t*)(ws + ((size_t)16  << 20));
    ushort_t* h2b   = (ushort_t*)ws;                           // router phase
    ushort_t* qkvh  = (ushort_t*)(ws + ((size_t)32  << 20));
    ushort_t* qkvl  = (ushort_t*)(ws + ((size_t)80  << 20));
    ushort_t* vth   = (ushort_t*)(ws + ((size_t)128 << 20));
    ushort_t* vtl   = (ushort_t*)(ws + ((size_t)144 << 20));
    ushort_t* ohi   = (ushort_t*)(ws + ((size_t)160 << 20));
    ushort_t* olo   = (ushort_t*)(ws + ((size_t)176 << 20));
    ushort_t* wqh   = (ushort_t*)(ws + ((size_t)128 << 20));   // ph1 only
    ushort_t* wql   = (ushort_t*)(ws + ((size_t)134 << 20));   // ph1 only
    ushort_t* woh   = (ushort_t*)(ws + ((size_t)192 << 20));
    ushort_t* wol   = (ushort_t*)(ws + ((size_t)194 << 20));
    ushort_t* w1t   = (ushort_t*)(ws + ((size_t)32  << 20));
    ushort_t* w2t   = (ushort_t*)(ws + ((size_t)32  << 20));
    ushort_t* dispb = (ushort_t*)(ws + ((size_t)96  << 20));
    ushort_t* h1b   = (ushort_t*)(ws + ((size_t)112 << 20));
    float*    buf_gtop = (float*)(ws + ((size_t)196 << 20));
    float*    buf_gv   = buf_gtop + S_;
    int*      buf_idx  = (int*)(buf_gv + S_);
    int*      buf_ta   = buf_idx + S_;

    // --- pre-router path (f32-grade via bf16x3 MFMA) ---
    split_kernel<<<(3*M_*M_/4 + 255)/256, 256, 0, stream>>>(Wqkv, wqh, wql, 3*M_*M_/4);
    split_kernel<<<(M_*M_/4 + 255)/256, 256, 0, stream>>>(Wout, woh, wol, M_*M_/4);
    ln_split_kernel<<<S_, 256, 0, stream>>>(x, ln1g, ln1b, ahi, alo);
    gemm_bf16x3<2><<<dim3(3*M_/128, S_/128, 1), 256, 0, stream>>>(
        ahi, alo, wqh, wql, bqkv, nullptr, qkvh, qkvl, 3*M_, M_);
    vtrans_kernel<<<dim3(T_/64, H_, B_), 256, 0, stream>>>(qkvh, qkvl, vth, vtl);
    attn_mfma_kernel<<<dim3(1024, 1, 1), 256, 0, stream>>>(qkvh, qkvl, vth, vtl, ohi, olo);
    gemm_bf16x3<1><<<dim3(M_/128, S_/128, 1), 256, 0, stream>>>(
        ohi, olo, woh, wol, bout, x, out, nullptr, M_, M_);

    // --- router (exact f32; fused LN2 + gate; h2 as bf16) ---
    ln_gate_kernel<<<S_, 256, 0, stream>>>(out, ln2g, ln2b, wg, h2b, buf_idx, buf_gtop);
    scan_kernel<<<1, 1024, 0, stream>>>(buf_idx, buf_gtop, buf_gv, buf_ta);
    dispatch_bf16_kernel<<<E_*C_, 256, 0, stream>>>(h2b, buf_ta, dispb);

    // --- MoE FFN (bf16 MFMA, post-router) ---
    transpose_bf16_kernel<<<dim3(F_/32, M_/32, E_), 256, 0, stream>>>(w1, w1t, M_, F_);
    gemm_mfma<0><<<dim3(F_/128, C_/128, E_), 256, 0, stream>>>(
        dispb, w1t, b1, nullptr, nullptr, h1b, F_, M_,
        (long)C_*M_, (long)F_*M_, (long)F_, (long)C_*F_);
    transpose_bf16_kernel<<<dim3(M_/32, F_/32, E_), 256, 0, stream>>>(w2, w2t, F_, M_);
    gemm_mfma<1><<<dim3(M_/128, C_/128, E_), 256, 0, stream>>>(
        h1b, w2t, b2, buf_ta, buf_gv, out, M_, F_,
        (long)C_*F_, (long)M_*F_, (long)M_, 0);
}

// Round 18
// 848.035 us; speedup vs baseline: 1.3585x; 1.0003x over previous
//
#include <hip/hip_runtime.h>
#include <hip/hip_bf16.h>
#include <math.h>

#define B_ 4
#define T_ 2048
#define M_ 1024
#define H_ 16
#define E_ 8
#define S_ (B_*T_)      // 8192
#define C_ (S_/E_)      // 1024
#define D_ (M_/H_)      // 64
#define F_ (4*M_)       // 4096

typedef unsigned short ushort_t;
typedef __attribute__((ext_vector_type(8))) short bf16x8;
typedef __attribute__((ext_vector_type(4))) float f32x4;

__device__ __forceinline__ float gelu_exact(float x) {
    return 0.5f * x * (1.0f + erff(x * 0.70710678118654752440f));
}

__device__ __forceinline__ unsigned short f2bf(float f) {
    unsigned int u = __float_as_uint(f);
    u = (u + 0x7FFFu + ((u >> 16) & 1u)) >> 16;   // RNE
    return (unsigned short)u;
}

__device__ __forceinline__ float bf2f(unsigned short h) {
    return __uint_as_float(((unsigned)h) << 16);
}

__device__ __forceinline__ void gload_lds16(const void* g, void* l) {
    __builtin_amdgcn_global_load_lds(
        (const __attribute__((address_space(1))) unsigned int*)g,
        (__attribute__((address_space(3))) unsigned int*)l,
        16, 0, 0);
}

__device__ __forceinline__ void lgkm0() {
    asm volatile("s_waitcnt lgkmcnt(0)" ::: "memory");
}

// ---------------------------------------------------------------------------
// LayerNorm fused with hi/lo bf16 split output (LN1).
// ---------------------------------------------------------------------------
__global__ __launch_bounds__(256) void ln_split_kernel(const float* __restrict__ x,
                                                       const float* __restrict__ g,
                                                       const float* __restrict__ bta,
                                                       ushort_t* __restrict__ hi,
                                                       ushort_t* __restrict__ lo)
{
    const int row = blockIdx.x;
    const int tid = threadIdx.x;
    const float4 v = reinterpret_cast<const float4*>(x + (size_t)row * M_)[tid];
    float s = v.x + v.y + v.z + v.w;
    __shared__ float red[4];
    #pragma unroll
    for (int off = 32; off > 0; off >>= 1) s += __shfl_down(s, off);
    if ((tid & 63) == 0) red[tid >> 6] = s;
    __syncthreads();
    const float mu = (red[0] + red[1] + red[2] + red[3]) * (1.0f / (float)M_);
    __syncthreads();
    float4 d;
    d.x = v.x - mu; d.y = v.y - mu; d.z = v.z - mu; d.w = v.w - mu;
    float q = d.x*d.x + d.y*d.y + d.z*d.z + d.w*d.w;
    #pragma unroll
    for (int off = 32; off > 0; off >>= 1) q += __shfl_down(q, off);
    if ((tid & 63) == 0) red[tid >> 6] = q;
    __syncthreads();
    const float var  = (red[0] + red[1] + red[2] + red[3]) * (1.0f / (float)M_);
    const float rstd = 1.0f / sqrtf(var + 1e-5f);
    const float4 gv = reinterpret_cast<const float4*>(g)[tid];
    const float4 bv = reinterpret_cast<const float4*>(bta)[tid];
    float o[4];
    o[0] = d.x * rstd * gv.x + bv.x;
    o[1] = d.y * rstd * gv.y + bv.y;
    o[2] = d.z * rstd * gv.z + bv.z;
    o[3] = d.w * rstd * gv.w + bv.w;
    ushort4 hh, ll;
    hh.x = f2bf(o[0]); ll.x = f2bf(o[0] - bf2f(hh.x));
    hh.y = f2bf(o[1]); ll.y = f2bf(o[1] - bf2f(hh.y));
    hh.z = f2bf(o[2]); ll.z = f2bf(o[2] - bf2f(hh.z));
    hh.w = f2bf(o[3]); ll.w = f2bf(o[3] - bf2f(hh.w));
    reinterpret_cast<ushort4*>(hi + (size_t)row * M_)[tid] = hh;
    reinterpret_cast<ushort4*>(lo + (size_t)row * M_)[tid] = ll;
}

// ---------------------------------------------------------------------------
// Fused LN2 + router gate. h2 emitted directly as bf16.
// ---------------------------------------------------------------------------
__global__ __launch_bounds__(256) void ln_gate_kernel(const float* __restrict__ x,
                                                      const float* __restrict__ g,
                                                      const float* __restrict__ bta,
                                                      const float* __restrict__ wg,
                                                      ushort_t* __restrict__ h2b,
                                                      int* __restrict__ gidx,
                                                      float* __restrict__ gtop)
{
    const int row = blockIdx.x;
    const int tid = threadIdx.x;
    const int wv = tid >> 6, ln = tid & 63;
    const float4 v = reinterpret_cast<const float4*>(x + (size_t)row * M_)[tid];
    float s = v.x + v.y + v.z + v.w;
    __shared__ float red[4];
    __shared__ float red2[4][E_];
    #pragma unroll
    for (int off = 32; off > 0; off >>= 1) s += __shfl_down(s, off);
    if (ln == 0) red[wv] = s;
    __syncthreads();
    const float mu = (red[0] + red[1] + red[2] + red[3]) * (1.0f / (float)M_);
    __syncthreads();
    float4 d;
    d.x = v.x - mu; d.y = v.y - mu; d.z = v.z - mu; d.w = v.w - mu;
    float q = d.x*d.x + d.y*d.y + d.z*d.z + d.w*d.w;
    #pragma unroll
    for (int off = 32; off > 0; off >>= 1) q += __shfl_down(q, off);
    if (ln == 0) red[wv] = q;
    __syncthreads();
    const float var  = (red[0] + red[1] + red[2] + red[3]) * (1.0f / (float)M_);
    const float rstd = 1.0f / sqrtf(var + 1e-5f);
    const float4 gv = reinterpret_cast<const float4*>(g)[tid];
    const float4 bv = reinterpret_cast<const float4*>(bta)[tid];
    float o[4];
    o[0] = d.x * rstd * gv.x + bv.x;
    o[1] = d.y * rstd * gv.y + bv.y;
    o[2] = d.z * rstd * gv.z + bv.z;
    o[3] = d.w * rstd * gv.w + bv.w;
    ushort4 hb;
    hb.x = f2bf(o[0]); hb.y = f2bf(o[1]); hb.z = f2bf(o[2]); hb.w = f2bf(o[3]);
    reinterpret_cast<ushort4*>(h2b + (size_t)row * M_)[tid] = hb;

    // logits: thread covers cols 4*tid..4*tid+3; wg is [M][E] row-major.
    float part[E_] = {};
    #pragma unroll
    for (int j = 0; j < 4; ++j) {
        const float4 w0 = reinterpret_cast<const float4*>(wg)[(4*tid + j) * 2];
        const float4 w1 = reinterpret_cast<const float4*>(wg)[(4*tid + j) * 2 + 1];
        part[0] = fmaf(o[j], w0.x, part[0]); part[1] = fmaf(o[j], w0.y, part[1]);
        part[2] = fmaf(o[j], w0.z, part[2]); part[3] = fmaf(o[j], w0.w, part[3]);
        part[4] = fmaf(o[j], w1.x, part[4]); part[5] = fmaf(o[j], w1.y, part[5]);
        part[6] = fmaf(o[j], w1.z, part[6]); part[7] = fmaf(o[j], w1.w, part[7]);
    }
    #pragma unroll
    for (int off = 32; off > 0; off >>= 1)
        #pragma unroll
        for (int e = 0; e < E_; ++e) part[e] += __shfl_down(part[e], off);
    if (ln == 0)
        #pragma unroll
        for (int e = 0; e < E_; ++e) red2[wv][e] = part[e];
    __syncthreads();
    if (tid == 0) {
        float lg[E_];
        #pragma unroll
        for (int e = 0; e < E_; ++e)
            lg[e] = red2[0][e] + red2[1][e] + red2[2][e] + red2[3][e];
        float mx = lg[0]; int bi = 0;
        #pragma unroll
        for (int i = 1; i < E_; ++i) { if (lg[i] > mx) { mx = lg[i]; bi = i; } }
        float den = 0.0f;
        #pragma unroll
        for (int i = 0; i < E_; ++i) den += expf(lg[i] - mx);
        gidx[row] = bi;
        gtop[row] = 1.0f / den;
    }
}

// Elementwise f32 -> hi/lo bf16 split (weights).
__global__ __launch_bounds__(256) void split_kernel(const float* __restrict__ in,
                                                    ushort_t* __restrict__ hi,
                                                    ushort_t* __restrict__ lo,
                                                    int n4)
{
    const int i = blockIdx.x * 256 + threadIdx.x;
    if (i >= n4) return;
    const float4 v = reinterpret_cast<const float4*>(in)[i];
    ushort4 hh, ll;
    hh.x = f2bf(v.x); ll.x = f2bf(v.x - bf2f(hh.x));
    hh.y = f2bf(v.y); ll.y = f2bf(v.y - bf2f(hh.y));
    hh.z = f2bf(v.z); ll.z = f2bf(v.z - bf2f(hh.z));
    hh.w = f2bf(v.w); ll.w = f2bf(v.w - bf2f(hh.w));
    reinterpret_cast<ushort4*>(hi)[i] = hh;
    reinterpret_cast<ushort4*>(lo)[i] = ll;
}

// V^T pre-transpose: qkv hi/lo [s][3M] (V slice) -> vt hi/lo [(b*H+h)*64+d][T].
__global__ __launch_bounds__(256) void vtrans_kernel(const ushort_t* __restrict__ qkvh,
                                                     const ushort_t* __restrict__ qkvl,
                                                     ushort_t* __restrict__ vth,
                                                     ushort_t* __restrict__ vtl)
{
    __shared__ ushort_t tile[64][72];
    const int t0 = blockIdx.x * 64, h = blockIdx.y, b = blockIdx.z;
    const int tid = threadIdx.x;
    const int tr = tid & 63, dc = (tid >> 6) * 16;
    const size_t src = ((size_t)(b*T_ + t0 + tr)) * (3*M_) + 2*M_ + h*64 + dc;
    const int dr = tid & 63, tc = (tid >> 6) * 16;
    const size_t dst = ((size_t)((b*H_ + h)*64 + dr)) * T_ + t0 + tc;

    #pragma unroll
    for (int pass = 0; pass < 2; ++pass) {
        const ushort_t* in = pass ? qkvl : qkvh;
        ushort_t* outp     = pass ? vtl  : vth;
        *reinterpret_cast<bf16x8*>(&tile[tr][dc])     = *reinterpret_cast<const bf16x8*>(in + src);
        *reinterpret_cast<bf16x8*>(&tile[tr][dc + 8]) = *reinterpret_cast<const bf16x8*>(in + src + 8);
        __syncthreads();
        bf16x8 o0, o1;
        #pragma unroll
        for (int j = 0; j < 8; ++j) {
            o0[j] = (short)tile[tc + j][dr];
            o1[j] = (short)tile[tc + 8 + j][dr];
        }
        *reinterpret_cast<bf16x8*>(outp + dst)     = o0;
        *reinterpret_cast<bf16x8*>(outp + dst + 8) = o1;
        __syncthreads();
    }
}

// ---------------------------------------------------------------------------
// bf16x3 MFMA GEMM (f32-grade, pre-router). m97 structure, 4 LDS buffers.
// EPI 1: f32 out = acc + bias + res.   EPI 2: hi/lo bf16 out = split(acc+bias).
// ---------------------------------------------------------------------------
template<int EPI>
__global__ __launch_bounds__(256) void gemm_bf16x3(
    const ushort_t* __restrict__ Ahi, const ushort_t* __restrict__ Alo,
    const ushort_t* __restrict__ Bhi, const ushort_t* __restrict__ Blo,
    const float* __restrict__ bias, const float* __restrict__ res,
    void* __restrict__ C0, ushort_t* __restrict__ C1, int N, int K)
{
    __shared__ ushort_t AsH[128*32], AsL[128*32];
    __shared__ ushort_t BsH[128*32], BsL[128*32];

    const int t  = threadIdx.x;
    const int l  = t & 63;
    const int wv = t >> 6;
    const int wm = (wv & 1) * 64, wn = (wv >> 1) * 64;
    const int fr = l & 15, fk = (l >> 4) * 8;
    const int m0 = blockIdx.y * 128, n0 = blockIdx.x * 128;

    const size_t arow = (size_t)(m0 + (t >> 2)) * K + (t & 3) * 8;
    const size_t brow = (size_t)(n0 + (t >> 2)) * K + (t & 3) * 8;
    ushort_t* lAH = AsH + wv * 512;
    ushort_t* lAL = AsL + wv * 512;
    ushort_t* lBH = BsH + wv * 512;
    ushort_t* lBL = BsL + wv * 512;

    f32x4 acc[4][4] = {};

    for (int k0 = 0; k0 < K; k0 += 32) {
        __syncthreads();
        gload_lds16(Ahi + arow + k0, lAH);
        gload_lds16(Ahi + arow + k0 + (size_t)64 * K, lAH + 2048);
        gload_lds16(Alo + arow + k0, lAL);
        gload_lds16(Alo + arow + k0 + (size_t)64 * K, lAL + 2048);
        gload_lds16(Bhi + brow + k0, lBH);
        gload_lds16(Bhi + brow + k0 + (size_t)64 * K, lBH + 2048);
        gload_lds16(Blo + brow + k0, lBL);
        gload_lds16(Blo + brow + k0 + (size_t)64 * K, lBL + 2048);
        __syncthreads();
        bf16x8 ah[4], al[4], bh[4], bl[4];
        #pragma unroll
        for (int i = 0; i < 4; ++i) {
            ah[i] = *reinterpret_cast<const bf16x8*>(&AsH[(wm + i*16 + fr) * 32 + fk]);
            al[i] = *reinterpret_cast<const bf16x8*>(&AsL[(wm + i*16 + fr) * 32 + fk]);
            bh[i] = *reinterpret_cast<const bf16x8*>(&BsH[(wn + i*16 + fr) * 32 + fk]);
            bl[i] = *reinterpret_cast<const bf16x8*>(&BsL[(wn + i*16 + fr) * 32 + fk]);
        }
        #pragma unroll
        for (int mi = 0; mi < 4; ++mi) {
            #pragma unroll
            for (int ni = 0; ni < 4; ++ni) {
                acc[mi][ni] = __builtin_amdgcn_mfma_f32_16x16x32_bf16(ah[mi], bh[ni], acc[mi][ni], 0, 0, 0);
                acc[mi][ni] = __builtin_amdgcn_mfma_f32_16x16x32_bf16(al[mi], bh[ni], acc[mi][ni], 0, 0, 0);
                acc[mi][ni] = __builtin_amdgcn_mfma_f32_16x16x32_bf16(ah[mi], bl[ni], acc[mi][ni], 0, 0, 0);
            }
        }
    }

    // C/D: col = lane&15, row = (lane>>4)*4 + reg
    const int l4 = (l >> 4) * 4;
    #pragma unroll
    for (int mi = 0; mi < 4; ++mi) {
        #pragma unroll
        for (int i = 0; i < 4; ++i) {
            const int row = m0 + wm + mi*16 + l4 + i;
            #pragma unroll
            for (int ni = 0; ni < 4; ++ni) {
                const int col = n0 + wn + ni*16 + fr;
                float v = acc[mi][ni][i] + bias[col];
                if (EPI == 1) {
                    v += res[(size_t)row * N + col];
                    ((float*)C0)[(size_t)row * N + col] = v;
                } else {
                    const ushort_t hb = f2bf(v);
                    ((ushort_t*)C0)[(size_t)row * N + col] = hb;
                    C1[(size_t)row * N + col] = f2bf(v - bf2f(hb));
                }
            }
        }
    }
}

// ---------------------------------------------------------------------------
// bf16x3 MFMA flash attention — PERSISTENT, 1024 blocks, 2 snake-paired items
// each. Verified round-13/15 body (223 us).
// ---------------------------------------------------------------------------
__global__ __launch_bounds__(256) void attn_mfma_kernel(
    const ushort_t* __restrict__ qkvh, const ushort_t* __restrict__ qkvl,
    const ushort_t* __restrict__ vth,  const ushort_t* __restrict__ vtl,
    ushort_t* __restrict__ ohi, ushort_t* __restrict__ olo)
{
    const int j = (int)blockIdx.x;                 // 0..1023
    const int t = threadIdx.x;
    const int w = t >> 6, l = t & 63;
    const int r = l & 15, g = l >> 4;

    __shared__ ushort_t Khi[64*64], Klo[64*64];    // [kv][64] swizzled; P alias
    __shared__ ushort_t Vhi[64*64], Vlo[64*64];    // V^T [d][64 kv] swizzled

    ushort_t* Pwh = Khi + w * 1024;                // per-wave P [16 q][64 kv]
    ushort_t* Pwl = Klo + w * 1024;

    const int items[2] = { j, 2047 - j };

    // staging lane geometry (item-independent)
    const int srow = w*8 + (l >> 3);
    const int scol = ((l & 7) ^ (l >> 3)) * 8;
    const int d0 = w * 512 + l * 8;                // ushort index; +2048 = rows+32

    for (int ii = 0; ii < 2; ++ii) {
        const int item = items[ii];
        const int qt  = 31 - (item >> 6);          // rank -> qt (descending)
        const int rem = item & 63;
        const int h = rem >> 2, b = rem & 3;
        const int q0 = qt * 64;
        const size_t rowbase = (size_t)b * T_;
        const int hoff = h * D_;

        // Q fragments (A-frag: row = l&15, k = 32ks + 8g + j)
        bf16x8 qh[2], ql[2];
        {
            const size_t qrow = (rowbase + q0 + 16*w + r) * (size_t)(3*M_) + hoff;
            #pragma unroll
            for (int ks = 0; ks < 2; ++ks) {
                qh[ks] = *reinterpret_cast<const bf16x8*>(qkvh + qrow + 32*ks + 8*g);
                ql[ks] = *reinterpret_cast<const bf16x8*>(qkvl + qrow + 32*ks + 8*g);
            }
        }

        const size_t ksrc0 = (rowbase + srow) * (size_t)(3*M_) + hoff + M_ + scol;
        const size_t vsrc0 = ((size_t)((b*H_ + h)*64 + srow)) * T_ + scol;

        bf16x8 stg[8];
        __syncthreads();   // previous item's LDS readers done
        // prologue: stage tile 0
        {
            const size_t kb = ksrc0, vb = vsrc0;
            const size_t kstep = (size_t)32 * (3*M_);
            stg[0] = *reinterpret_cast<const bf16x8*>(qkvh + kb);
            stg[1] = *reinterpret_cast<const bf16x8*>(qkvh + kb + kstep);
            stg[2] = *reinterpret_cast<const bf16x8*>(qkvl + kb);
            stg[3] = *reinterpret_cast<const bf16x8*>(qkvl + kb + kstep);
            stg[4] = *reinterpret_cast<const bf16x8*>(vth + vb);
            stg[5] = *reinterpret_cast<const bf16x8*>(vth + vb + 32*T_);
            stg[6] = *reinterpret_cast<const bf16x8*>(vtl + vb);
            stg[7] = *reinterpret_cast<const bf16x8*>(vtl + vb + 32*T_);
            *reinterpret_cast<bf16x8*>(&Khi[d0])        = stg[0];
            *reinterpret_cast<bf16x8*>(&Khi[d0 + 2048]) = stg[1];
            *reinterpret_cast<bf16x8*>(&Klo[d0])        = stg[2];
            *reinterpret_cast<bf16x8*>(&Klo[d0 + 2048]) = stg[3];
            *reinterpret_cast<bf16x8*>(&Vhi[d0])        = stg[4];
            *reinterpret_cast<bf16x8*>(&Vhi[d0 + 2048]) = stg[5];
            *reinterpret_cast<bf16x8*>(&Vlo[d0])        = stg[6];
            *reinterpret_cast<bf16x8*>(&Vlo[d0 + 2048]) = stg[7];
        }
        __syncthreads();

        f32x4 oa[4] = {};
        float mrow[4] = {-__builtin_inff(), -__builtin_inff(), -__builtin_inff(), -__builtin_inff()};
        float lrow[4] = {};

        for (int kt = 0; kt <= qt; ++kt) {
            // ---- QK^T: S[16 q][64 kv], bf16x3, K frags from LDS ----
            f32x4 sa[4] = {};
            #pragma unroll
            for (int ks = 0; ks < 2; ++ks) {
                bf16x8 kh[4], kl[4];
                #pragma unroll
                for (int nf = 0; nf < 4; ++nf) {
                    const int row = 16*nf + r;
                    const unsigned boff = (unsigned)(row * 128)
                        + (((unsigned)(ks*64 + g*16)) ^ ((unsigned)((row & 7) << 4)));
                    kh[nf] = *reinterpret_cast<const bf16x8*>((const char*)Khi + boff);
                    kl[nf] = *reinterpret_cast<const bf16x8*>((const char*)Klo + boff);
                }
                #pragma unroll
                for (int nf = 0; nf < 4; ++nf) {
                    sa[nf] = __builtin_amdgcn_mfma_f32_16x16x32_bf16(qh[ks], kh[nf], sa[nf], 0, 0, 0);
                    sa[nf] = __builtin_amdgcn_mfma_f32_16x16x32_bf16(ql[ks], kh[nf], sa[nf], 0, 0, 0);
                    sa[nf] = __builtin_amdgcn_mfma_f32_16x16x32_bf16(qh[ks], kl[nf], sa[nf], 0, 0, 0);
                }
            }

            // ---- issue next tile's staging loads into registers (T14) ----
            if (kt < qt) {
                const size_t kb = ksrc0 + (size_t)((kt+1)*64) * (3*M_);
                const size_t vb = vsrc0 + (size_t)((kt+1)*64);
                const size_t kstep = (size_t)32 * (3*M_);
                stg[0] = *reinterpret_cast<const bf16x8*>(qkvh + kb);
                stg[1] = *reinterpret_cast<const bf16x8*>(qkvh + kb + kstep);
                stg[2] = *reinterpret_cast<const bf16x8*>(qkvl + kb);
                stg[3] = *reinterpret_cast<const bf16x8*>(qkvl + kb + kstep);
                stg[4] = *reinterpret_cast<const bf16x8*>(vth + vb);
                stg[5] = *reinterpret_cast<const bf16x8*>(vth + vb + 32*T_);
                stg[6] = *reinterpret_cast<const bf16x8*>(vtl + vb);
                stg[7] = *reinterpret_cast<const bf16x8*>(vtl + vb + 32*T_);
            }

            // ---- scale + causal mask ----
            float sv[4][4];
            #pragma unroll
            for (int nf = 0; nf < 4; ++nf)
                #pragma unroll
                for (int i = 0; i < 4; ++i)
                    sv[nf][i] = sa[nf][i] * 0.125f;
            if (kt == qt) {
                #pragma unroll
                for (int nf = 0; nf < 4; ++nf) {
                    const int kvg = kt*64 + 16*nf + r;
                    #pragma unroll
                    for (int i = 0; i < 4; ++i) {
                        const int qg = q0 + 16*w + 4*g + i;
                        if (kvg > qg) sv[nf][i] = -3.0e38f;
                    }
                }
            }

            // ---- online softmax (native exp) ----
            float tmax[4];
            #pragma unroll
            for (int i = 0; i < 4; ++i)
                tmax[i] = fmaxf(fmaxf(sv[0][i], sv[1][i]), fmaxf(sv[2][i], sv[3][i]));
            #pragma unroll
            for (int off = 1; off < 16; off <<= 1)
                #pragma unroll
                for (int i = 0; i < 4; ++i)
                    tmax[i] = fmaxf(tmax[i], __shfl_xor(tmax[i], off));
            float mnew[4], corr[4];
            #pragma unroll
            for (int i = 0; i < 4; ++i) {
                mnew[i] = fmaxf(mrow[i], tmax[i]);
                corr[i] = __expf(mrow[i] - mnew[i]);
            }
            float p[4][4];
            float rsum[4] = {};
            #pragma unroll
            for (int nf = 0; nf < 4; ++nf)
                #pragma unroll
                for (int i = 0; i < 4; ++i) {
                    p[nf][i] = __expf(sv[nf][i] - mnew[i]);
                    rsum[i] += p[nf][i];
                }
            #pragma unroll
            for (int off = 1; off < 16; off <<= 1)
                #pragma unroll
                for (int i = 0; i < 4; ++i)
                    rsum[i] += __shfl_xor(rsum[i], off);
            #pragma unroll
            for (int i = 0; i < 4; ++i) {
                lrow[i] = lrow[i] * corr[i] + rsum[i];
                mrow[i] = mnew[i];
            }
            #pragma unroll
            for (int df = 0; df < 4; ++df)
                #pragma unroll
                for (int i = 0; i < 4; ++i)
                    oa[df][i] *= corr[i];

            __syncthreads();   // all waves done reading K -> safe to alias P

            // ---- write P into K region (per-wave [16][64], XOR-swizzled) ----
            #pragma unroll
            for (int nf = 0; nf < 4; ++nf) {
                #pragma unroll
                for (int i = 0; i < 4; ++i) {
                    const int q = 4*g + i;
                    const int kv = (16*nf + r) ^ ((q & 7) << 3);
                    const ushort_t phb = f2bf(p[nf][i]);
                    Pwh[q * 64 + kv] = phb;
                    Pwl[q * 64 + kv] = f2bf(p[nf][i] - bf2f(phb));
                }
            }
            lgkm0();   // P writes visible to this wave's reads (per-wave slice)

            // ---- PV: O += P·V, bf16x3 ----
            #pragma unroll
            for (int ks = 0; ks < 2; ++ks) {
                const unsigned poff = (unsigned)(r * 64 + ((32*ks + 8*g) ^ ((r & 7) << 3)));
                const bf16x8 ph = *reinterpret_cast<const bf16x8*>(&Pwh[poff]);
                const bf16x8 pl = *reinterpret_cast<const bf16x8*>(&Pwl[poff]);
                #pragma unroll
                for (int df = 0; df < 4; ++df) {
                    const int vrow = 16*df + r;
                    const unsigned voff = (unsigned)(vrow * 128)
                        + (((unsigned)(ks*64 + g*16)) ^ ((unsigned)((vrow & 7) << 4)));
                    const bf16x8 vhf = *reinterpret_cast<const bf16x8*>((const char*)Vhi + voff);
                    const bf16x8 vlf = *reinterpret_cast<const bf16x8*>((const char*)Vlo + voff);
                    oa[df] = __builtin_amdgcn_mfma_f32_16x16x32_bf16(ph, vhf, oa[df], 0, 0, 0);
                    oa[df] = __builtin_amdgcn_mfma_f32_16x16x32_bf16(pl, vhf, oa[df], 0, 0, 0);
                    oa[df] = __builtin_amdgcn_mfma_f32_16x16x32_bf16(ph, vlf, oa[df], 0, 0, 0);
                }
            }

            // ---- commit staged registers to LDS for next tile ----
            if (kt < qt) {
                __syncthreads();                   // V readers done; P dead
                *reinterpret_cast<bf16x8*>(&Khi[d0])        = stg[0];
                *reinterpret_cast<bf16x8*>(&Khi[d0 + 2048]) = stg[1];
                *reinterpret_cast<bf16x8*>(&Klo[d0])        = stg[2];
                *reinterpret_cast<bf16x8*>(&Klo[d0 + 2048]) = stg[3];
                *reinterpret_cast<bf16x8*>(&Vhi[d0])        = stg[4];
                *reinterpret_cast<bf16x8*>(&Vhi[d0 + 2048]) = stg[5];
                *reinterpret_cast<bf16x8*>(&Vlo[d0])        = stg[6];
                *reinterpret_cast<bf16x8*>(&Vlo[d0 + 2048]) = stg[7];
                __syncthreads();                   // writes visible
            }
        }

        // ---- epilogue: hi/lo split of O / l ----
        #pragma unroll
        for (int i = 0; i < 4; ++i) {
            const float inv = 1.0f / lrow[i];
            const size_t row = (rowbase + q0 + 16*w + 4*g + i) * (size_t)M_ + hoff;
            #pragma unroll
            for (int df = 0; df < 4; ++df) {
                const float v = oa[df][i] * inv;
                const ushort_t hb = f2bf(v);
                ohi[row + 16*df + r] = hb;
                olo[row + 16*df + r] = f2bf(v - bf2f(hb));
            }
        }
    }
}

// ---------------------------------------------------------------------------
// Deepspeed dispatch bookkeeping — parallel Hillis-Steele scan.
// ---------------------------------------------------------------------------
__global__ __launch_bounds__(1024) void scan_kernel(const int* __restrict__ gidx,
                                                    const float* __restrict__ gtop,
                                                    float* __restrict__ gate_val,
                                                    int* __restrict__ token_at)
{
    __shared__ int hist[1024][E_];
    const int tid = threadIdx.x;
    for (int i = tid; i < E_ * C_; i += 1024) token_at[i] = -1;
    int my[8];
    #pragma unroll
    for (int t = 0; t < 8; ++t) my[t] = gidx[tid * 8 + t];
    int cnt[E_] = {};
    #pragma unroll
    for (int t = 0; t < 8; ++t) ++cnt[my[t]];
    #pragma unroll
    for (int e = 0; e < E_; ++e) hist[tid][e] = cnt[e];
    __syncthreads();
    for (int off = 1; off < 1024; off <<= 1) {
        int add[E_];
        #pragma unroll
        for (int e = 0; e < E_; ++e) add[e] = (tid >= off) ? hist[tid - off][e] : 0;
        __syncthreads();
        #pragma unroll
        for (int e = 0; e < E_; ++e) hist[tid][e] += add[e];
        __syncthreads();
    }
    int base[E_];
    #pragma unroll
    for (int e = 0; e < E_; ++e) base[e] = hist[tid][e] - cnt[e];   // exclusive
    int run[E_] = {};
    #pragma unroll
    for (int t = 0; t < 8; ++t) {
        const int s = tid * 8 + t;
        const int e = my[t];
        const int p = base[e] + run[e];
        ++run[e];
        const bool keep = (p < C_);
        gate_val[s] = keep ? gtop[s] : 0.0f;
        if (keep) token_at[e * C_ + p] = s;
    }
}

// Gather-dispatch from bf16 h2.
__global__ __launch_bounds__(256) void dispatch_bf16_kernel(const ushort_t* __restrict__ h2b,
                                                            const int* __restrict__ token_at,
                                                            ushort_t* __restrict__ disp)
{
    const int ec = blockIdx.x;
    const int s = token_at[ec];
    ushort4* dst = reinterpret_cast<ushort4*>(disp + (size_t)ec * M_);
    if (s >= 0) {
        dst[threadIdx.x] = reinterpret_cast<const ushort4*>(h2b + (size_t)s * M_)[threadIdx.x];
    } else {
        dst[threadIdx.x] = make_ushort4(0, 0, 0, 0);
    }
}

// Transpose+convert: in[e][R][Cc] f32 -> out[e][Cc][R] bf16. Vectorized:
// float4 loads (16 B/lane, 128 B per 8-lane row group) + ushort4 writes
// (8 B/lane). Single pass, 32x32 tile. Values identical (same f2bf).
__global__ __launch_bounds__(256) void transpose_bf16_kernel(const float* __restrict__ in,
                                                             ushort_t* __restrict__ outp,
                                                             int R, int Cc)
{
    __shared__ float tile[32][33];
    const int e = blockIdx.z;
    in   += (size_t)e * R * Cc;
    outp += (size_t)e * R * Cc;
    const int c0 = blockIdx.x * 32, r0 = blockIdx.y * 32;
    // load: thread (lr = tid>>3, lc4 = (tid&7)*4) reads float4 [r0+lr][c0+lc4..+3]
    const int lr = threadIdx.x >> 3, lc4 = (threadIdx.x & 7) * 4;
    const float4 v = *reinterpret_cast<const float4*>(&in[(size_t)(r0 + lr) * Cc + c0 + lc4]);
    tile[lr][lc4 + 0] = v.x; tile[lr][lc4 + 1] = v.y;
    tile[lr][lc4 + 2] = v.z; tile[lr][lc4 + 3] = v.w;
    __syncthreads();
    // write: thread (oc = tid>>3, or4 = (tid&7)*4) writes ushort4 out[c0+oc][r0+or4..+3]
    const int oc = threadIdx.x >> 3, or4 = (threadIdx.x & 7) * 4;
    ushort4 o;
    o.x = f2bf(tile[or4 + 0][oc]); o.y = f2bf(tile[or4 + 1][oc]);
    o.z = f2bf(tile[or4 + 2][oc]); o.w = f2bf(tile[or4 + 3][oc]);
    *reinterpret_cast<ushort4*>(&outp[(size_t)(c0 + oc) * R + r0 + or4]) = o;
}

// ---------------------------------------------------------------------------
// bf16 MFMA GEMM (MoE FFN, post-router) — BK=64 + XOR-swizzled LDS (verified
// round 17). Accumulation order identical to BK=32 version.
// ---------------------------------------------------------------------------
template<int EPI>
__global__ __launch_bounds__(256) void gemm_mfma(
    const ushort_t* __restrict__ A, const ushort_t* __restrict__ Bt,
    const float* __restrict__ bias,
    const int* __restrict__ token_at, const float* __restrict__ gate_val,
    void* __restrict__ Cout, int N, int K,
    long strA, long strB, long strBias, long strC)
{
    const int e = blockIdx.z;
    A    += (size_t)e * (size_t)strA;
    Bt   += (size_t)e * (size_t)strB;
    bias += (size_t)e * (size_t)strBias;

    __shared__ ushort_t As[128 * 64];   // 16 KiB
    __shared__ ushort_t Bs[128 * 64];   // 16 KiB

    const int t  = threadIdx.x;
    const int l  = t & 63;
    const int wv = t >> 6;
    const int wm = (wv & 1) * 64, wn = (wv >> 1) * 64;
    const int fr = l & 15, fk = (l >> 4) * 8;
    const int m0 = blockIdx.y * 128, n0 = blockIdx.x * 128;

    const int srow = t >> 3;
    const int schunk = (t & 7) ^ (srow & 7);
    const ushort_t* gA = A + (size_t)(m0 + srow) * K + schunk * 8;
    const ushort_t* gB = Bt + (size_t)(n0 + srow) * K + schunk * 8;
    ushort_t* lA = As + wv * 512;       // wave-uniform; HW adds lane*16B
    ushort_t* lB = Bs + wv * 512;

    const int aswz = (fr & 7) << 3;

    f32x4 acc[4][4] = {};

    for (int k0 = 0; k0 < K; k0 += 64) {
        __syncthreads();
        gload_lds16(gA + k0,                  lA);
        gload_lds16(gA + k0 + (size_t)32 * K, lA + 2048);
        gload_lds16(gA + k0 + (size_t)64 * K, lA + 4096);
        gload_lds16(gA + k0 + (size_t)96 * K, lA + 6144);
        gload_lds16(gB + k0,                  lB);
        gload_lds16(gB + k0 + (size_t)32 * K, lB + 2048);
        gload_lds16(gB + k0 + (size_t)64 * K, lB + 4096);
        gload_lds16(gB + k0 + (size_t)96 * K, lB + 6144);
        __syncthreads();
        #pragma unroll
        for (int ks = 0; ks < 2; ++ks) {
            bf16x8 af[4], bfr[4];
            #pragma unroll
            for (int i = 0; i < 4; ++i) {
                af[i] = *reinterpret_cast<const bf16x8*>(
                    &As[(wm + i*16 + fr) * 64 + ((32*ks + fk) ^ aswz)]);
                bfr[i] = *reinterpret_cast<const bf16x8*>(
                    &Bs[(wn + i*16 + fr) * 64 + ((32*ks + fk) ^ aswz)]);
            }
            #pragma unroll
            for (int mi = 0; mi < 4; ++mi) {
                #pragma unroll
                for (int ni = 0; ni < 4; ++ni)
                    acc[mi][ni] = __builtin_amdgcn_mfma_f32_16x16x32_bf16(
                        af[mi], bfr[ni], acc[mi][ni], 0, 0, 0);
            }
        }
    }

    const int l4 = (l >> 4) * 4;
    if (EPI == 0) {
        ushort_t* Cc = (ushort_t*)Cout + (size_t)e * (size_t)strC;
        #pragma unroll
        for (int ni = 0; ni < 4; ++ni) {
            const int cl = n0 + wn + ni*16 + fr;
            const float bb = bias[cl];
            #pragma unroll
            for (int mi = 0; mi < 4; ++mi) {
                #pragma unroll
                for (int i = 0; i < 4; ++i) {
                    const int rr = m0 + wm + mi*16 + l4 + i;
                    Cc[(size_t)rr * N + cl] = f2bf(gelu_exact(acc[mi][ni][i] + bb));
                }
            }
        }
    } else {
        float* Co = (float*)Cout;
        const int* ta = token_at + e * C_;
        #pragma unroll
        for (int mi = 0; mi < 4; ++mi) {
            #pragma unroll
            for (int i = 0; i < 4; ++i) {
                const int rr = m0 + wm + mi*16 + l4 + i;
                const int s = ta[rr];
                if (s >= 0) {
                    const float gvl = gate_val[s];
                    #pragma unroll
                    for (int ni = 0; ni < 4; ++ni) {
                        const int cl = n0 + wn + ni*16 + fr;
                        Co[(size_t)s * N + cl] += gvl * (acc[mi][ni][i] + bias[cl]);
                    }
                }
            }
        }
    }
}

// ---------------------------------------------------------------------------
extern "C" void kernel_launch(void* const* d_in, const int* in_sizes, int n_in,
                              void* d_out, int out_size, void* d_ws, size_t ws_size,
                              hipStream_t stream)
{
    const float* x    = (const float*)d_in[0];
    const float* ln1g = (const float*)d_in[1];
    const float* ln1b = (const float*)d_in[2];
    const float* Wqkv = (const float*)d_in[3];
    const float* bqkv = (const float*)d_in[4];
    const float* Wout = (const float*)d_in[5];
    const float* bout = (const float*)d_in[6];
    const float* ln2g = (const float*)d_in[7];
    const float* ln2b = (const float*)d_in[8];
    const float* wg   = (const float*)d_in[9];
    const float* w1   = (const float*)d_in[10];
    const float* b1   = (const float*)d_in[11];
    const float* w2   = (const float*)d_in[12];
    const float* b2   = (const float*)d_in[13];
    float* out = (float*)d_out;

    // Workspace (MiB offsets), lifetime-scheduled. Peak ~196 MiB.
    char* ws = (char*)d_ws;
    ushort_t* ahi   = (ushort_t*)ws;
    ushort_t* alo   = (ushort_t*)(ws + ((size_t)16  << 20));
    ushort_t* h2b   = (ushort_t*)ws;                           // router phase
    ushort_t* qkvh  = (ushort_t*)(ws + ((size_t)32  << 20));
    ushort_t* qkvl  = (ushort_t*)(ws + ((size_t)80  << 20));
    ushort_t* vth   = (ushort_t*)(ws + ((size_t)128 << 20));
    ushort_t* vtl   = (ushort_t*)(ws + ((size_t)144 << 20));
    ushort_t* ohi   = (ushort_t*)(ws + ((size_t)160 << 20));
    ushort_t* olo   = (ushort_t*)(ws + ((size_t)176 << 20));
    ushort_t* wqh   = (ushort_t*)(ws + ((size_t)128 << 20));   // ph1 only
    ushort_t* wql   = (ushort_t*)(ws + ((size_t)134 << 20));   // ph1 only
    ushort_t* woh   = (ushort_t*)(ws + ((size_t)192 << 20));
    ushort_t* wol   = (ushort_t*)(ws + ((size_t)194 << 20));
    ushort_t* w1t   = (ushort_t*)(ws + ((size_t)32  << 20));
    ushort_t* w2t   = (ushort_t*)(ws + ((size_t)32  << 20));
    ushort_t* dispb = (ushort_t*)(ws + ((size_t)96  << 20));
    ushort_t* h1b   = (ushort_t*)(ws + ((size_t)112 << 20));
    float*    buf_gtop = (float*)(ws + ((size_t)196 << 20));
    float*    buf_gv   = buf_gtop + S_;
    int*      buf_idx  = (int*)(buf_gv + S_);
    int*      buf_ta   = buf_idx + S_;

    // --- pre-router path (f32-grade via bf16x3 MFMA) ---
    split_kernel<<<(3*M_*M_/4 + 255)/256, 256, 0, stream>>>(Wqkv, wqh, wql, 3*M_*M_/4);
    split_kernel<<<(M_*M_/4 + 255)/256, 256, 0, stream>>>(Wout, woh, wol, M_*M_/4);
    ln_split_kernel<<<S_, 256, 0, stream>>>(x, ln1g, ln1b, ahi, alo);
    gemm_bf16x3<2><<<dim3(3*M_/128, S_/128, 1), 256, 0, stream>>>(
        ahi, alo, wqh, wql, bqkv, nullptr, qkvh, qkvl, 3*M_, M_);
    vtrans_kernel<<<dim3(T_/64, H_, B_), 256, 0, stream>>>(qkvh, qkvl, vth, vtl);
    attn_mfma_kernel<<<dim3(1024, 1, 1), 256, 0, stream>>>(qkvh, qkvl, vth, vtl, ohi, olo);
    gemm_bf16x3<1><<<dim3(M_/128, S_/128, 1), 256, 0, stream>>>(
        ohi, olo, woh, wol, bout, x, out, nullptr, M_, M_);

    // --- router (exact f32; fused LN2 + gate; h2 as bf16) ---
    ln_gate_kernel<<<S_, 256, 0, stream>>>(out, ln2g, ln2b, wg, h2b, buf_idx, buf_gtop);
    scan_kernel<<<1, 1024, 0, stream>>>(buf_idx, buf_gtop, buf_gv, buf_ta);
    dispatch_bf16_kernel<<<E_*C_, 256, 0, stream>>>(h2b, buf_ta, dispb);

    // --- MoE FFN (bf16 MFMA, post-router) ---
    transpose_bf16_kernel<<<dim3(F_/32, M_/32, E_), 256, 0, stream>>>(w1, w1t, M_, F_);
    gemm_mfma<0><<<dim3(F_/128, C_/128, E_), 256, 0, stream>>>(
        dispb, w1t, b1, nullptr, nullptr, h1b, F_, M_,
        (long)C_*M_, (long)F_*M_, (long)F_, (long)C_*F_);
    transpose_bf16_kernel<<<dim3(M_/32, F_/32, E_), 256, 0, stream>>>(w2, w2t, F_, M_);
    gemm_mfma<1><<<dim3(M_/128, C_/128, E_), 256, 0, stream>>>(
        h1b, w2t, b2, buf_ta, buf_gv, out, M_, F_,
        (long)C_*F_, (long)M_*F_, (long)M_, 0);
}